// Round 1
// baseline (7581.342 us; speedup 1.0000x reference)
//
#include <hip/hip_runtime.h>
#include <hip/hip_bf16.h>

#define B 8
#define S 512
#define MM 64
#define T 576          // S + MM
#define H 768
#define NH 12
#define DH 64
#define FF 3072
#define E 512
#define NL 2
#define K2 1536        // 2*H (key_w1 out)
#define E2 1024        // 2*E (val_w1 out)

// ---------------- order / argsort kernel ----------------
// stable argsort of (1 - mask): valid positions (mask=1) first in index order,
// then invalid positions in index order.
__global__ void order_kernel(const int* __restrict__ mask, int* __restrict__ ord,
                             int* __restrict__ Larr) {
    __shared__ int ps[S];
    int b = blockIdx.x;
    int t = threadIdx.x;
    int mv = (mask[b * S + t] != 0) ? 1 : 0;
    ps[t] = mv;
    __syncthreads();
    // Hillis-Steele inclusive scan over 512 elements
    for (int off = 1; off < S; off <<= 1) {
        int v = ps[t];
        int add = (t >= off) ? ps[t - off] : 0;
        __syncthreads();
        ps[t] = v + add;
        __syncthreads();
    }
    int L = ps[S - 1];
    int rank = mv ? (ps[t] - 1) : (L + (t - ps[t]));
    ord[b * S + rank] = t;
    if (t == 0) Larr[b] = L;
}

// ---------------- embedding + LN ----------------
__global__ void embed_kernel(const int* __restrict__ ids, const int* __restrict__ toktype,
                             const int* __restrict__ ord, const int* __restrict__ Larr,
                             const float* __restrict__ word_emb, const float* __restrict__ pos_emb,
                             const float* __restrict__ type_emb, const float* __restrict__ memory,
                             const float* __restrict__ lns, const float* __restrict__ lnb,
                             float* __restrict__ x, int* __restrict__ ttarr,
                             float* __restrict__ biasArr) {
    int t = blockIdx.x;
    int b = blockIdx.y;
    int Lb = Larr[b];
    int tid = threadIdx.x;
    int tt;
    const float* src;
    if (t < Lb) {
        int sp = ord[b * S + t];
        tt = toktype[b * S + sp];
        src = &word_emb[(size_t)ids[b * S + sp] * H];
    } else if (t < Lb + MM) {
        tt = 1;
        src = &memory[(size_t)(t - Lb) * H];
    } else {
        int spp = t - MM;
        if (spp < 0) spp = 0;
        if (spp > S - 1) spp = S - 1;
        int sp = ord[b * S + spp];
        tt = 1;
        src = &word_emb[(size_t)ids[b * S + sp] * H];
    }
    __shared__ float row[H];
    __shared__ float r1[256], r2[256];
    float lsum = 0.f, lsq = 0.f;
    for (int hh = tid; hh < H; hh += 256) {
        float v = src[hh] + pos_emb[(size_t)t * H + hh] + type_emb[(size_t)tt * H + hh];
        row[hh] = v;
        lsum += v;
        lsq += v * v;
    }
    r1[tid] = lsum; r2[tid] = lsq;
    __syncthreads();
    for (int s = 128; s > 0; s >>= 1) {
        if (tid < s) { r1[tid] += r1[tid + s]; r2[tid] += r2[tid + s]; }
        __syncthreads();
    }
    float mu = r1[0] / H;
    float var = r2[0] / H - mu * mu;
    float inv = rsqrtf(var + 1e-12f);
    for (int hh = tid; hh < H; hh += 256) {
        x[((size_t)b * T + t) * H + hh] = (row[hh] - mu) * inv * lns[hh] + lnb[hh];
    }
    if (tid == 0) {
        ttarr[b * T + t] = tt;
        biasArr[b * T + t] = (t < Lb + MM) ? 0.f : -10000.f;
    }
}

// ---------------- generic tiled fp32 GEMM + bias + activation ----------------
#define ACT_NONE 0
#define ACT_RELU 1
#define ACT_GELU 2
#define ACT_SIGMOID 3
#define ACT_TANH 4

template <int ACT>
__device__ inline float apply_act(float v) {
    if constexpr (ACT == ACT_RELU) return fmaxf(v, 0.f);
    else if constexpr (ACT == ACT_GELU) return 0.5f * v * (1.f + erff(v * 0.70710678118654752f));
    else if constexpr (ACT == ACT_SIGMOID) return 1.f / (1.f + expf(-v));
    else if constexpr (ACT == ACT_TANH) return tanhf(v);
    else return v;
}

// C[M,N] = act(A[M,K] @ W[K,N] + bias[N]); all row-major; M%64==0, N%64==0, K%16==0
template <int ACT>
__global__ void gemm_kernel(const float* __restrict__ A, const float* __restrict__ W,
                            const float* __restrict__ bias, float* __restrict__ C,
                            int Mdim, int Ndim, int Kdim) {
    __shared__ float As[16][65];
    __shared__ float Bs[16][65];
    int bn = blockIdx.x * 64;
    int bm = blockIdx.y * 64;
    int tx = threadIdx.x, ty = threadIdx.y;
    int tid = ty * 16 + tx;
    float acc[4][4] = {};
    for (int k0 = 0; k0 < Kdim; k0 += 16) {
        #pragma unroll
        for (int i = 0; i < 4; ++i) {
            int e = tid * 4 + i;
            int am = e >> 4, ak = e & 15;
            As[ak][am] = A[(size_t)(bm + am) * Kdim + k0 + ak];
        }
        #pragma unroll
        for (int i = 0; i < 4; ++i) {
            int e = tid + i * 256;
            int bk = e >> 6, bnn = e & 63;
            Bs[bk][bnn] = W[(size_t)(k0 + bk) * Ndim + bn + bnn];
        }
        __syncthreads();
        #pragma unroll
        for (int kk = 0; kk < 16; ++kk) {
            float a0[4], b0[4];
            #pragma unroll
            for (int i = 0; i < 4; ++i) a0[i] = As[kk][ty * 4 + i];
            #pragma unroll
            for (int j = 0; j < 4; ++j) b0[j] = Bs[kk][tx * 4 + j];
            #pragma unroll
            for (int i = 0; i < 4; ++i)
                #pragma unroll
                for (int j = 0; j < 4; ++j)
                    acc[i][j] = fmaf(a0[i], b0[j], acc[i][j]);
        }
        __syncthreads();
    }
    #pragma unroll
    for (int i = 0; i < 4; ++i) {
        int r = bm + ty * 4 + i;
        #pragma unroll
        for (int j = 0; j < 4; ++j) {
            int c = bn + tx * 4 + j;
            float v = acc[i][j] + (bias ? bias[c] : 0.f);
            C[(size_t)r * Ndim + c] = apply_act<ACT>(v);
        }
    }
}

// ---------------- attention (per b,h, 16-query tile) ----------------
__global__ void attn_kernel(const float* __restrict__ Q, const float* __restrict__ K,
                            const float* __restrict__ V, const float* __restrict__ biasArr,
                            float* __restrict__ ctx) {
    const int QT = 16;
    __shared__ float qs[QT][DH];
    __shared__ float sc[QT][T];
    __shared__ float red[256];
    int qt = blockIdx.x * QT;
    int h = blockIdx.y;
    int b = blockIdx.z;
    int tid = threadIdx.x;
    const size_t base = ((size_t)b * T) * H + (size_t)h * DH;

    for (int e = tid; e < QT * DH; e += 256) {
        int q = e >> 6, d = e & 63;
        qs[q][d] = Q[base + (size_t)(qt + q) * H + d];
    }
    __syncthreads();
    // scores
    for (int e = tid; e < QT * T; e += 256) {
        int q = e / T, kk = e % T;
        const float* kp = &K[base + (size_t)kk * H];
        float dot = 0.f;
        #pragma unroll
        for (int d = 0; d < DH; ++d) dot = fmaf(qs[q][d], kp[d], dot);
        sc[q][kk] = dot * 0.125f + biasArr[b * T + kk];
    }
    __syncthreads();
    // softmax per row
    for (int q = 0; q < QT; ++q) {
        float m = -1e30f;
        for (int kk = tid; kk < T; kk += 256) m = fmaxf(m, sc[q][kk]);
        red[tid] = m;
        __syncthreads();
        for (int s = 128; s > 0; s >>= 1) {
            if (tid < s) red[tid] = fmaxf(red[tid], red[tid + s]);
            __syncthreads();
        }
        m = red[0];
        __syncthreads();
        float sum = 0.f;
        for (int kk = tid; kk < T; kk += 256) {
            float e2 = expf(sc[q][kk] - m);
            sc[q][kk] = e2;
            sum += e2;
        }
        red[tid] = sum;
        __syncthreads();
        for (int s = 128; s > 0; s >>= 1) {
            if (tid < s) red[tid] += red[tid + s];
            __syncthreads();
        }
        float inv = 1.f / red[0];
        __syncthreads();
        for (int kk = tid; kk < T; kk += 256) sc[q][kk] *= inv;
    }
    __syncthreads();
    // ctx = P @ V
    for (int e = tid; e < QT * DH; e += 256) {
        int q = e >> 6, d = e & 63;
        float s = 0.f;
        for (int kk = 0; kk < T; ++kk) s = fmaf(sc[q][kk], V[base + (size_t)kk * H + d], s);
        ctx[base + (size_t)(qt + q) * H + d] = s;
    }
}

// ---------------- residual + LN (in-place on x) ----------------
__global__ void lnres_kernel(float* __restrict__ x, const float* __restrict__ delta,
                             const float* __restrict__ s, const float* __restrict__ bvec) {
    int r = blockIdx.x;
    int tid = threadIdx.x;
    __shared__ float row[H];
    __shared__ float r1[256], r2[256];
    float lsum = 0.f, lsq = 0.f;
    size_t off = (size_t)r * H;
    for (int hh = tid; hh < H; hh += 256) {
        float v = x[off + hh] + delta[off + hh];
        row[hh] = v;
        lsum += v;
        lsq += v * v;
    }
    r1[tid] = lsum; r2[tid] = lsq;
    __syncthreads();
    for (int ss = 128; ss > 0; ss >>= 1) {
        if (tid < ss) { r1[tid] += r1[tid + ss]; r2[tid] += r2[tid + ss]; }
        __syncthreads();
    }
    float mu = r1[0] / H;
    float var = r2[0] / H - mu * mu;
    float inv = rsqrtf(var + 1e-12f);
    for (int hh = tid; hh < H; hh += 256) x[off + hh] = (row[hh] - mu) * inv * s[hh] + bvec[hh];
}

// ---------------- masked softmax pooling ----------------
__global__ void pool_kernel(const float* __restrict__ weight, const float* __restrict__ value,
                            const int* __restrict__ ttarr, float* __restrict__ out) {
    int b = blockIdx.x;
    int e = blockIdx.y * 256 + threadIdx.x;
    float mx = -1e30f;
    for (int t = 0; t < T; ++t) {
        if (ttarr[b * T + t] == 1) continue;
        mx = fmaxf(mx, weight[((size_t)b * T + t) * E + e]);
    }
    float den = 0.f, num = 0.f;
    for (int t = 0; t < T; ++t) {
        if (ttarr[b * T + t] == 1) continue;
        float w = expf(weight[((size_t)b * T + t) * E + e] - mx);
        den += w;
        num = fmaf(w, value[((size_t)b * T + t) * E + e], num);
    }
    out[(size_t)b * E + e] = fmaxf(num / den, 0.f);
}

// ---------------- host-side launch ----------------
extern "C" void kernel_launch(void* const* d_in, const int* in_sizes, int n_in,
                              void* d_out, int out_size, void* d_ws, size_t ws_size,
                              hipStream_t stream) {
    const int*   input_ids  = (const int*)d_in[0];
    const int*   token_type = (const int*)d_in[1];
    const int*   attn_mask  = (const int*)d_in[2];
    const float* word_emb   = (const float*)d_in[3];
    const float* pos_emb    = (const float*)d_in[4];
    const float* type_emb   = (const float*)d_in[5];
    const float* emb_ln_s   = (const float*)d_in[6];
    const float* emb_ln_b   = (const float*)d_in[7];
    const float* memory     = (const float*)d_in[8];
    const float* q_w  = (const float*)d_in[9];
    const float* q_b  = (const float*)d_in[10];
    const float* k_w  = (const float*)d_in[11];
    const float* k_b  = (const float*)d_in[12];
    const float* v_w  = (const float*)d_in[13];
    const float* v_b  = (const float*)d_in[14];
    const float* o_w  = (const float*)d_in[15];
    const float* o_b  = (const float*)d_in[16];
    const float* ln1_s = (const float*)d_in[17];
    const float* ln1_b = (const float*)d_in[18];
    const float* f_w1  = (const float*)d_in[19];
    const float* f_b1  = (const float*)d_in[20];
    const float* f_w2  = (const float*)d_in[21];
    const float* f_b2  = (const float*)d_in[22];
    const float* ln2_s = (const float*)d_in[23];
    const float* ln2_b = (const float*)d_in[24];
    const float* key_w1 = (const float*)d_in[25];
    const float* key_b1 = (const float*)d_in[26];
    const float* key_w2 = (const float*)d_in[27];
    const float* key_b2 = (const float*)d_in[28];
    const float* val_w1 = (const float*)d_in[29];
    const float* val_b1 = (const float*)d_in[30];
    const float* val_w2 = (const float*)d_in[31];
    const float* val_b2 = (const float*)d_in[32];
    float* out = (float*)d_out;

    char* ws = (char*)d_ws;
    size_t off = 0;
    auto alloc = [&](size_t bytes) {
        void* p = ws + off;
        off += (bytes + 255) & ~(size_t)255;
        return p;
    };
    const size_t BT  = (size_t)B * T;
    const size_t BTH = BT * H;

    int*   ord     = (int*)alloc((size_t)B * S * 4);
    int*   Larr    = (int*)alloc((size_t)B * 4);
    int*   ttarr   = (int*)alloc(BT * 4);
    float* biasArr = (float*)alloc(BT * 4);
    float* x       = (float*)alloc(BTH * 4);
    float* Abuf    = (float*)alloc(BT * FF * 4);   // holds q|k|v|ctx, or ffn-h, or key1|val1
    float* Bbuf    = (float*)alloc(BTH * 4);       // proj / ffn-out / weight
    float* Cbuf    = (float*)alloc(BT * E * 4);    // value

    float* qb  = Abuf;
    float* kb  = Abuf + BTH;
    float* vb  = Abuf + 2 * BTH;
    float* ctx = Abuf + 3 * BTH;

    auto gemm = [&](const float* A, const float* W, const float* bias, float* C,
                    int Md, int Nd, int Kd, int actid) {
        dim3 grid(Nd / 64, Md / 64);
        dim3 blk(16, 16);
        switch (actid) {
            case ACT_NONE:    hipLaunchKernelGGL((gemm_kernel<ACT_NONE>),    grid, blk, 0, stream, A, W, bias, C, Md, Nd, Kd); break;
            case ACT_RELU:    hipLaunchKernelGGL((gemm_kernel<ACT_RELU>),    grid, blk, 0, stream, A, W, bias, C, Md, Nd, Kd); break;
            case ACT_GELU:    hipLaunchKernelGGL((gemm_kernel<ACT_GELU>),    grid, blk, 0, stream, A, W, bias, C, Md, Nd, Kd); break;
            case ACT_SIGMOID: hipLaunchKernelGGL((gemm_kernel<ACT_SIGMOID>), grid, blk, 0, stream, A, W, bias, C, Md, Nd, Kd); break;
            case ACT_TANH:    hipLaunchKernelGGL((gemm_kernel<ACT_TANH>),    grid, blk, 0, stream, A, W, bias, C, Md, Nd, Kd); break;
        }
    };

    const int Mrows = (int)BT;  // 4608

    hipLaunchKernelGGL(order_kernel, dim3(B), dim3(S), 0, stream, attn_mask, ord, Larr);
    hipLaunchKernelGGL(embed_kernel, dim3(T, B), dim3(256), 0, stream,
                       input_ids, token_type, ord, Larr, word_emb, pos_emb, type_emb,
                       memory, emb_ln_s, emb_ln_b, x, ttarr, biasArr);

    for (int l = 0; l < NL; ++l) {
        const float* qwl = q_w + (size_t)l * H * H;
        const float* kwl = k_w + (size_t)l * H * H;
        const float* vwl = v_w + (size_t)l * H * H;
        const float* owl = o_w + (size_t)l * H * H;
        gemm(x, qwl, q_b + (size_t)l * H, qb, Mrows, H, H, ACT_NONE);
        gemm(x, kwl, k_b + (size_t)l * H, kb, Mrows, H, H, ACT_NONE);
        gemm(x, vwl, v_b + (size_t)l * H, vb, Mrows, H, H, ACT_NONE);
        hipLaunchKernelGGL(attn_kernel, dim3(T / 16, NH, B), dim3(256), 0, stream,
                           qb, kb, vb, biasArr, ctx);
        gemm(ctx, owl, o_b + (size_t)l * H, Bbuf, Mrows, H, H, ACT_NONE);
        hipLaunchKernelGGL(lnres_kernel, dim3((int)BT), dim3(256), 0, stream,
                           x, Bbuf, ln1_s + (size_t)l * H, ln1_b + (size_t)l * H);
        gemm(x, f_w1 + (size_t)l * H * FF, f_b1 + (size_t)l * FF, Abuf, Mrows, FF, H, ACT_GELU);
        gemm(Abuf, f_w2 + (size_t)l * FF * H, f_b2 + (size_t)l * H, Bbuf, Mrows, H, FF, ACT_NONE);
        hipLaunchKernelGGL(lnres_kernel, dim3((int)BT), dim3(256), 0, stream,
                           x, Bbuf, ln2_s + (size_t)l * H, ln2_b + (size_t)l * H);
    }

    // pooling heads
    float* key1 = Abuf;                     // (BT, 1536)
    float* val1 = Abuf + BT * K2;           // (BT, 1024)
    float* wgt  = Bbuf;                     // (BT, 512)
    float* val  = Cbuf;                     // (BT, 512)
    gemm(x, key_w1, key_b1, key1, Mrows, K2, H, ACT_RELU);
    gemm(key1, key_w2, key_b2, wgt, Mrows, E, K2, ACT_SIGMOID);
    gemm(x, val_w1, val_b1, val1, Mrows, E2, H, ACT_RELU);
    gemm(val1, val_w2, val_b2, val, Mrows, E, E2, ACT_TANH);
    hipLaunchKernelGGL(pool_kernel, dim3(B, E / 256), dim3(256), 0, stream,
                       wgt, val, ttarr, out);
}

// Round 2
// 966.549 us; speedup vs baseline: 7.8437x; 7.8437x over previous
//
#include <hip/hip_runtime.h>
#include <hip/hip_bf16.h>

#define B 8
#define S 512
#define MM 64
#define T 576          // S + MM
#define H 768
#define NH 12
#define DH 64
#define FF 3072
#define E 512
#define NL 2

typedef __attribute__((ext_vector_type(8))) short bf16x8;
typedef __attribute__((ext_vector_type(4))) float f32x4;

__device__ inline unsigned short bf16_rne(float f) {
    unsigned u = __builtin_bit_cast(unsigned, f);
    unsigned r = u + 0x7FFFu + ((u >> 16) & 1u);
    return (unsigned short)(r >> 16);
}

__device__ inline f32x4 mfma16(bf16x8 a, bf16x8 b, f32x4 c) {
    return __builtin_amdgcn_mfma_f32_16x16x32_bf16(a, b, c, 0, 0, 0);
}

__device__ inline void load_lds16(const void* g, void* l) {
    __builtin_amdgcn_global_load_lds((const __attribute__((address_space(1))) void*)g,
                                     (__attribute__((address_space(3))) void*)l, 16, 0, 0);
}

// ---------------- order / argsort ----------------
__global__ void order_kernel(const int* __restrict__ mask, int* __restrict__ ord,
                             int* __restrict__ Larr) {
    __shared__ int ps[S];
    int b = blockIdx.x;
    int t = threadIdx.x;
    int mv = (mask[b * S + t] != 0) ? 1 : 0;
    ps[t] = mv;
    __syncthreads();
    for (int off = 1; off < S; off <<= 1) {
        int v = ps[t];
        int add = (t >= off) ? ps[t - off] : 0;
        __syncthreads();
        ps[t] = v + add;
        __syncthreads();
    }
    int L = ps[S - 1];
    int rank = mv ? (ps[t] - 1) : (L + (t - ps[t]));
    ord[b * S + rank] = t;
    if (t == 0) Larr[b] = L;
}

// ---------------- embedding + LN (writes f32 x and bf16 xb) ----------------
__global__ void embed_kernel(const int* __restrict__ ids, const int* __restrict__ toktype,
                             const int* __restrict__ ord, const int* __restrict__ Larr,
                             const float* __restrict__ word_emb, const float* __restrict__ pos_emb,
                             const float* __restrict__ type_emb, const float* __restrict__ memory,
                             const float* __restrict__ lns, const float* __restrict__ lnb,
                             float* __restrict__ x, unsigned short* __restrict__ xb,
                             int* __restrict__ ttarr) {
    int t = blockIdx.x;
    int b = blockIdx.y;
    int Lb = Larr[b];
    int tid = threadIdx.x;
    int tt;
    const float* src;
    if (t < Lb) {
        int sp = ord[b * S + t];
        tt = toktype[b * S + sp];
        src = &word_emb[(size_t)ids[b * S + sp] * H];
    } else if (t < Lb + MM) {
        tt = 1;
        src = &memory[(size_t)(t - Lb) * H];
    } else {
        int spp = t - MM;
        if (spp < 0) spp = 0;
        if (spp > S - 1) spp = S - 1;
        int sp = ord[b * S + spp];
        tt = 1;
        src = &word_emb[(size_t)ids[b * S + sp] * H];
    }
    __shared__ float row[H];
    __shared__ float r1[256], r2[256];
    float lsum = 0.f, lsq = 0.f;
    for (int hh = tid; hh < H; hh += 256) {
        float v = src[hh] + pos_emb[(size_t)t * H + hh] + type_emb[(size_t)tt * H + hh];
        row[hh] = v;
        lsum += v;
        lsq += v * v;
    }
    r1[tid] = lsum; r2[tid] = lsq;
    __syncthreads();
    for (int s = 128; s > 0; s >>= 1) {
        if (tid < s) { r1[tid] += r1[tid + s]; r2[tid] += r2[tid + s]; }
        __syncthreads();
    }
    float mu = r1[0] / H;
    float var = r2[0] / H - mu * mu;
    float inv = rsqrtf(var + 1e-12f);
    for (int hh = tid; hh < H; hh += 256) {
        float v = (row[hh] - mu) * inv * lns[hh] + lnb[hh];
        x[((size_t)b * T + t) * H + hh] = v;
        xb[((size_t)b * T + t) * H + hh] = bf16_rne(v);
    }
    if (tid == 0) ttarr[b * T + t] = tt;
}

// ---------------- activations ----------------
#define ACT_NONE 0
#define ACT_RELU 1
#define ACT_GELU 2
#define ACT_SIGMOID 3
#define ACT_TANH 4

template <int ACT>
__device__ inline float apply_act(float v) {
    if constexpr (ACT == ACT_RELU) return fmaxf(v, 0.f);
    else if constexpr (ACT == ACT_GELU) return 0.5f * v * (1.f + erff(v * 0.70710678118654752f));
    else if constexpr (ACT == ACT_SIGMOID) return 1.f / (1.f + expf(-v));
    else if constexpr (ACT == ACT_TANH) return tanhf(v);
    else return v;
}

// ---------------- weight transpose + bf16 convert: W[K][N] f32 -> Wt[N][K] bf16 ----------------
__global__ void transpose_w(const float* __restrict__ W, unsigned short* __restrict__ Wt,
                            int Kd, int Nd) {
    __shared__ float tile[32][33];
    int k0 = blockIdx.x * 32, n0 = blockIdx.y * 32;
    int tx = threadIdx.x & 31, ty = threadIdx.x >> 5;  // 32 x 8
    #pragma unroll
    for (int r = 0; r < 4; ++r) {
        int kk = ty + r * 8;
        tile[kk][tx] = W[(size_t)(k0 + kk) * Nd + n0 + tx];
    }
    __syncthreads();
    #pragma unroll
    for (int r = 0; r < 4; ++r) {
        int nn = ty + r * 8;
        Wt[(size_t)(n0 + nn) * Kd + k0 + tx] = bf16_rne(tile[tx][nn]);
    }
}

// ---------------- MFMA GEMM: C[M,N] = act(A[M,K] @ Wt[N,K]^T + bias) ----------------
// A bf16 row-major [M][K], Bt bf16 row-major [N][K]. 128x128 tile, BK=32, 4 waves.
template <int ACT, bool F32OUT, bool BF16OUT, bool VTOUT>
__global__ __launch_bounds__(256) void mfma_gemm(
    const unsigned short* __restrict__ A, const unsigned short* __restrict__ Bt,
    const float* __restrict__ bias, float* __restrict__ Cf,
    unsigned short* __restrict__ Cb, unsigned short* __restrict__ VtOut,
    int Mdim, int Ndim, int Kdim) {
    __shared__ unsigned short As[128 * 32];
    __shared__ unsigned short Bs[128 * 32];
    const int bn = blockIdx.x * 128, bm = blockIdx.y * 128;
    const int tid = threadIdx.x;
    const int w = tid >> 6, lane = tid & 63;
    const int lr = lane & 15, g = lane >> 4;
    const int wr = w >> 1, wc = w & 1;
    f32x4 acc[4][4] = {};
    const int srow = w * 32 + (lane >> 2);
    const int kc = (lane & 3) * 8;
    const unsigned short* ga0 = A + (size_t)(bm + srow) * Kdim + kc;
    const unsigned short* ga1 = A + (size_t)(bm + srow + 16) * Kdim + kc;
    const unsigned short* gb0 = Bt + (size_t)(bn + srow) * Kdim + kc;
    const unsigned short* gb1 = Bt + (size_t)(bn + srow + 16) * Kdim + kc;
    unsigned short* asb0 = &As[(w * 32) * 32];
    unsigned short* asb1 = &As[(w * 32 + 16) * 32];
    unsigned short* bsb0 = &Bs[(w * 32) * 32];
    unsigned short* bsb1 = &Bs[(w * 32 + 16) * 32];
    for (int k0 = 0; k0 < Kdim; k0 += 32) {
        load_lds16(ga0 + k0, asb0);
        load_lds16(ga1 + k0, asb1);
        load_lds16(gb0 + k0, bsb0);
        load_lds16(gb1 + k0, bsb1);
        __syncthreads();
        bf16x8 af[4], bfr[4];
        #pragma unroll
        for (int i = 0; i < 4; ++i)
            af[i] = *(const bf16x8*)&As[(wr * 64 + i * 16 + lr) * 32 + g * 8];
        #pragma unroll
        for (int j = 0; j < 4; ++j)
            bfr[j] = *(const bf16x8*)&Bs[(wc * 64 + j * 16 + lr) * 32 + g * 8];
        #pragma unroll
        for (int i = 0; i < 4; ++i)
            #pragma unroll
            for (int j = 0; j < 4; ++j)
                acc[i][j] = mfma16(af[i], bfr[j], acc[i][j]);
        __syncthreads();
    }
    #pragma unroll
    for (int i = 0; i < 4; ++i) {
        const int row0 = bm + wr * 64 + i * 16 + 4 * g;
        #pragma unroll
        for (int j = 0; j < 4; ++j) {
            const int col = bn + wc * 64 + j * 16 + lr;
            const float bv = bias ? bias[col] : 0.f;
            float vv[4];
            #pragma unroll
            for (int r = 0; r < 4; ++r) vv[r] = apply_act<ACT>(acc[i][j][r] + bv);
            if constexpr (F32OUT) {
                #pragma unroll
                for (int r = 0; r < 4; ++r) Cf[(size_t)(row0 + r) * Ndim + col] = vv[r];
            }
            if constexpr (BF16OUT) {
                #pragma unroll
                for (int r = 0; r < 4; ++r) Cb[(size_t)(row0 + r) * Ndim + col] = bf16_rne(vv[r]);
            }
            if constexpr (VTOUT) {
                // Vt[b][h][d][t] bf16; rows row0..row0+3 are consecutive t in the same b
                int bb = row0 / T, t0 = row0 % T;
                int hh2 = col >> 6, dd = col & 63;
                unsigned lo = (unsigned)bf16_rne(vv[0]) | ((unsigned)bf16_rne(vv[1]) << 16);
                unsigned hi = (unsigned)bf16_rne(vv[2]) | ((unsigned)bf16_rne(vv[3]) << 16);
                size_t idx = (((size_t)bb * NH + hh2) * DH + dd) * T + t0;
                *(uint2*)&VtOut[idx] = make_uint2(lo, hi);
            }
        }
    }
}

// ---------------- MFMA flash attention ----------------
// QK: [B*T][1536] bf16 (cols 0..767 = Q, 768..1535 = K), Vt: [B][NH][DH][T] bf16.
// 1 wave per 16 q-rows; swapped QK^T (mfma(K,Q) -> lane holds S^T[key][q]).
__global__ __launch_bounds__(64) void attn_mfma(
    const unsigned short* __restrict__ QK, const unsigned short* __restrict__ Vt,
    const int* __restrict__ Larr, unsigned short* __restrict__ ctxb) {
    const int q0 = blockIdx.x * 16;
    const int h = blockIdx.y, b = blockIdx.z;
    const int lane = threadIdx.x;
    const int lr = lane & 15, g = lane >> 4;
    const int LbMM = Larr[b] + MM;
    __shared__ unsigned short P[16][72];
    const unsigned short* qrow = QK + (size_t)(b * T + q0 + lr) * 1536 + h * 64;
    bf16x8 qf0 = *(const bf16x8*)(qrow + 8 * g);
    bf16x8 qf1 = *(const bf16x8*)(qrow + 32 + 8 * g);
    f32x4 ctx[4] = {};
    float m_run = -1e30f, l_run = 0.f;
    const size_t vbase = ((size_t)b * NH + h) * DH;
    for (int kt = 0; kt < T; kt += 64) {
        f32x4 sf[4];
        #pragma unroll
        for (int i = 0; i < 4; ++i) {
            const unsigned short* krow =
                QK + (size_t)(b * T + kt + 16 * i + lr) * 1536 + 768 + h * 64;
            bf16x8 kf0 = *(const bf16x8*)(krow + 8 * g);
            bf16x8 kf1 = *(const bf16x8*)(krow + 32 + 8 * g);
            f32x4 s = {};
            s = mfma16(kf0, qf0, s);
            s = mfma16(kf1, qf1, s);
            sf[i] = s;
        }
        float tmax = -1e30f;
        #pragma unroll
        for (int i = 0; i < 4; ++i)
            #pragma unroll
            for (int r = 0; r < 4; ++r) {
                int key = kt + 16 * i + 4 * g + r;
                float v = sf[i][r] * 0.125f + (key < LbMM ? 0.f : -10000.f);
                sf[i][r] = v;
                tmax = fmaxf(tmax, v);
            }
        tmax = fmaxf(tmax, __shfl_xor(tmax, 16));
        tmax = fmaxf(tmax, __shfl_xor(tmax, 32));
        float m_new = fmaxf(m_run, tmax);
        float scale = expf(m_run - m_new);
        m_run = m_new;
        float psum = 0.f;
        #pragma unroll
        for (int i = 0; i < 4; ++i)
            #pragma unroll
            for (int r = 0; r < 4; ++r) {
                float p = expf(sf[i][r] - m_new);
                sf[i][r] = p;
                psum += p;
            }
        l_run = l_run * scale + psum;
        float f0 = __shfl(scale, 4 * g + 0);
        float f1 = __shfl(scale, 4 * g + 1);
        float f2 = __shfl(scale, 4 * g + 2);
        float f3 = __shfl(scale, 4 * g + 3);
        #pragma unroll
        for (int j = 0; j < 4; ++j) {
            ctx[j][0] *= f0; ctx[j][1] *= f1; ctx[j][2] *= f2; ctx[j][3] *= f3;
        }
        #pragma unroll
        for (int i = 0; i < 4; ++i) {
            unsigned lo = (unsigned)bf16_rne(sf[i][0]) | ((unsigned)bf16_rne(sf[i][1]) << 16);
            unsigned hi = (unsigned)bf16_rne(sf[i][2]) | ((unsigned)bf16_rne(sf[i][3]) << 16);
            *(unsigned*)&P[lr][16 * i + 4 * g] = lo;
            *(unsigned*)&P[lr][16 * i + 4 * g + 2] = hi;
        }
        __syncthreads();  // single wave: forces lgkmcnt drain between P writes and reads
        #pragma unroll
        for (int s2 = 0; s2 < 2; ++s2) {
            bf16x8 pa = *(const bf16x8*)&P[lr][32 * s2 + 8 * g];
            #pragma unroll
            for (int j = 0; j < 4; ++j) {
                const unsigned short* vrow =
                    Vt + (vbase + 16 * j + lr) * T + kt + 32 * s2 + 8 * g;
                bf16x8 vf = *(const bf16x8*)vrow;
                ctx[j] = mfma16(pa, vf, ctx[j]);
            }
        }
        __syncthreads();
    }
    l_run += __shfl_xor(l_run, 16);
    l_run += __shfl_xor(l_run, 32);
    float inv = 1.f / l_run;
    float i0 = __shfl(inv, 4 * g + 0);
    float i1 = __shfl(inv, 4 * g + 1);
    float i2 = __shfl(inv, 4 * g + 2);
    float i3 = __shfl(inv, 4 * g + 3);
    float sc[4] = {i0, i1, i2, i3};
    #pragma unroll
    for (int j = 0; j < 4; ++j)
        #pragma unroll
        for (int r = 0; r < 4; ++r)
            ctxb[(size_t)(b * T + q0 + 4 * g + r) * H + h * 64 + 16 * j + lr] =
                bf16_rne(ctx[j][r] * sc[r]);
}

// ---------------- residual + LN (writes f32 x in place and bf16 xb) ----------------
__global__ void lnres_kernel(float* __restrict__ x, const float* __restrict__ delta,
                             const float* __restrict__ s, const float* __restrict__ bvec,
                             unsigned short* __restrict__ xb) {
    int r = blockIdx.x;
    int tid = threadIdx.x;
    __shared__ float row[H];
    __shared__ float r1[256], r2[256];
    float lsum = 0.f, lsq = 0.f;
    size_t off = (size_t)r * H;
    for (int hh = tid; hh < H; hh += 256) {
        float v = x[off + hh] + delta[off + hh];
        row[hh] = v;
        lsum += v;
        lsq += v * v;
    }
    r1[tid] = lsum; r2[tid] = lsq;
    __syncthreads();
    for (int ss = 128; ss > 0; ss >>= 1) {
        if (tid < ss) { r1[tid] += r1[tid + ss]; r2[tid] += r2[tid + ss]; }
        __syncthreads();
    }
    float mu = r1[0] / H;
    float var = r2[0] / H - mu * mu;
    float inv = rsqrtf(var + 1e-12f);
    for (int hh = tid; hh < H; hh += 256) {
        float v = (row[hh] - mu) * inv * s[hh] + bvec[hh];
        x[off + hh] = v;
        xb[off + hh] = bf16_rne(v);
    }
}

// ---------------- masked softmax pooling ----------------
__global__ void pool_kernel(const float* __restrict__ weight, const float* __restrict__ value,
                            const int* __restrict__ ttarr, float* __restrict__ out) {
    int b = blockIdx.x;
    int e = blockIdx.y * 256 + threadIdx.x;
    float mx = -1e30f;
    for (int t = 0; t < T; ++t) {
        if (ttarr[b * T + t] == 1) continue;
        mx = fmaxf(mx, weight[((size_t)b * T + t) * E + e]);
    }
    float den = 0.f, num = 0.f;
    for (int t = 0; t < T; ++t) {
        if (ttarr[b * T + t] == 1) continue;
        float w = expf(weight[((size_t)b * T + t) * E + e] - mx);
        den += w;
        num = fmaf(w, value[((size_t)b * T + t) * E + e], num);
    }
    out[(size_t)b * E + e] = fmaxf(num / den, 0.f);
}

// ---------------- host-side launch ----------------
extern "C" void kernel_launch(void* const* d_in, const int* in_sizes, int n_in,
                              void* d_out, int out_size, void* d_ws, size_t ws_size,
                              hipStream_t stream) {
    const int*   input_ids  = (const int*)d_in[0];
    const int*   token_type = (const int*)d_in[1];
    const int*   attn_mask  = (const int*)d_in[2];
    const float* word_emb   = (const float*)d_in[3];
    const float* pos_emb    = (const float*)d_in[4];
    const float* type_emb   = (const float*)d_in[5];
    const float* emb_ln_s   = (const float*)d_in[6];
    const float* emb_ln_b   = (const float*)d_in[7];
    const float* memory     = (const float*)d_in[8];
    const float* q_w  = (const float*)d_in[9];
    const float* q_b  = (const float*)d_in[10];
    const float* k_w  = (const float*)d_in[11];
    const float* k_b  = (const float*)d_in[12];
    const float* v_w  = (const float*)d_in[13];
    const float* v_b  = (const float*)d_in[14];
    const float* o_w  = (const float*)d_in[15];
    const float* o_b  = (const float*)d_in[16];
    const float* ln1_s = (const float*)d_in[17];
    const float* ln1_b = (const float*)d_in[18];
    const float* f_w1  = (const float*)d_in[19];
    const float* f_b1  = (const float*)d_in[20];
    const float* f_w2  = (const float*)d_in[21];
    const float* f_b2  = (const float*)d_in[22];
    const float* ln2_s = (const float*)d_in[23];
    const float* ln2_b = (const float*)d_in[24];
    const float* key_w1 = (const float*)d_in[25];
    const float* key_b1 = (const float*)d_in[26];
    const float* key_w2 = (const float*)d_in[27];
    const float* key_b2 = (const float*)d_in[28];
    const float* val_w1 = (const float*)d_in[29];
    const float* val_b1 = (const float*)d_in[30];
    const float* val_w2 = (const float*)d_in[31];
    const float* val_b2 = (const float*)d_in[32];
    float* out = (float*)d_out;

    char* ws = (char*)d_ws;
    size_t off = 0;
    auto alloc = [&](size_t bytes) {
        void* p = ws + off;
        off += (bytes + 255) & ~(size_t)255;
        return p;
    };
    const size_t BT  = (size_t)B * T;      // 4608
    const size_t BTH = BT * H;             // 3538944

    int*   ord   = (int*)alloc((size_t)B * S * 4);
    int*   Larr  = (int*)alloc(64);
    int*   ttarr = (int*)alloc(BT * 4);
    float* x     = (float*)alloc(BTH * 4);
    unsigned short* xb   = (unsigned short*)alloc(BTH * 2);
    unsigned short* reg1 = (unsigned short*)alloc(BT * FF * 2);   // 28.3 MB, multi-use
    float* Bbuf  = (float*)alloc(BTH * 4);
    unsigned short* wt = (unsigned short*)alloc((size_t)7077888 * 2);  // transposed weights
    float* bqk = (float*)alloc(1536 * 4);

    unsigned short* qkb  = reg1;                       // [BT][1536]
    unsigned short* Vtb  = reg1 + BT * 1536;           // [B][NH][DH][T]
    unsigned short* ctxb = reg1 + BT * 1536 + BTH;     // [BT][H]
    unsigned short* hb   = reg1;                       // [BT][FF] (FFN phase)
    unsigned short* key1b = reg1;                      // [BT][1536] (head phase)
    unsigned short* val1b = reg1 + BT * 1536;          // [BT][1024]
    float* wgt  = Bbuf;                                // [BT][512] f32
    float* valf = x;                                   // [BT][512] f32 (x dead by then)

    // transposed weight sub-buffers (per-layer reuse)
    unsigned short* wt_qk = wt;                        // [1536][768]
    unsigned short* wt_v  = wt + (size_t)1536 * 768;   // [768][768]
    unsigned short* wt_o  = wt_v + (size_t)768 * 768;  // [768][768]
    unsigned short* wt_f1 = wt_o + (size_t)768 * 768;  // [3072][768]
    unsigned short* wt_f2 = wt_f1 + (size_t)3072 * 768;// [768][3072]
    // head phase reuse
    unsigned short* wt_k1 = wt;                        // [1536][768]
    unsigned short* wt_k2 = wt + (size_t)1536 * 768;   // [512][1536]
    unsigned short* wt_v1 = wt_k2 + (size_t)512 * 1536;// [1024][768]
    unsigned short* wt_v2 = wt_v1 + (size_t)1024 * 768;// [512][1024]

    const int Mrows = (int)BT;  // 4608

    hipLaunchKernelGGL(order_kernel, dim3(B), dim3(S), 0, stream, attn_mask, ord, Larr);
    hipLaunchKernelGGL(embed_kernel, dim3(T, B), dim3(256), 0, stream,
                       input_ids, token_type, ord, Larr, word_emb, pos_emb, type_emb,
                       memory, emb_ln_s, emb_ln_b, x, xb, ttarr);

    for (int l = 0; l < NL; ++l) {
        const size_t HH = (size_t)H * H;
        hipLaunchKernelGGL(transpose_w, dim3(H / 32, H / 32), dim3(256), 0, stream,
                           q_w + l * HH, wt_qk, H, H);
        hipLaunchKernelGGL(transpose_w, dim3(H / 32, H / 32), dim3(256), 0, stream,
                           k_w + l * HH, wt_qk + (size_t)768 * 768, H, H);
        hipLaunchKernelGGL(transpose_w, dim3(H / 32, H / 32), dim3(256), 0, stream,
                           v_w + l * HH, wt_v, H, H);
        hipLaunchKernelGGL(transpose_w, dim3(H / 32, H / 32), dim3(256), 0, stream,
                           o_w + l * HH, wt_o, H, H);
        hipLaunchKernelGGL(transpose_w, dim3(H / 32, FF / 32), dim3(256), 0, stream,
                           f_w1 + (size_t)l * H * FF, wt_f1, H, FF);
        hipLaunchKernelGGL(transpose_w, dim3(FF / 32, H / 32), dim3(256), 0, stream,
                           f_w2 + (size_t)l * FF * H, wt_f2, FF, H);
        hipMemcpyAsync(bqk, q_b + (size_t)l * H, H * 4, hipMemcpyDeviceToDevice, stream);
        hipMemcpyAsync(bqk + H, k_b + (size_t)l * H, H * 4, hipMemcpyDeviceToDevice, stream);

        mfma_gemm<ACT_NONE, false, true, false><<<dim3(12, 36), 256, 0, stream>>>(
            xb, wt_qk, bqk, nullptr, qkb, nullptr, Mrows, 1536, H);
        mfma_gemm<ACT_NONE, false, false, true><<<dim3(6, 36), 256, 0, stream>>>(
            xb, wt_v, v_b + (size_t)l * H, nullptr, nullptr, Vtb, Mrows, H, H);
        hipLaunchKernelGGL(attn_mfma, dim3(T / 16, NH, B), dim3(64), 0, stream,
                           qkb, Vtb, Larr, ctxb);
        mfma_gemm<ACT_NONE, true, false, false><<<dim3(6, 36), 256, 0, stream>>>(
            ctxb, wt_o, o_b + (size_t)l * H, Bbuf, nullptr, nullptr, Mrows, H, H);
        hipLaunchKernelGGL(lnres_kernel, dim3((int)BT), dim3(256), 0, stream,
                           x, Bbuf, ln1_s + (size_t)l * H, ln1_b + (size_t)l * H, xb);
        mfma_gemm<ACT_GELU, false, true, false><<<dim3(24, 36), 256, 0, stream>>>(
            xb, wt_f1, f_b1 + (size_t)l * FF, nullptr, hb, nullptr, Mrows, FF, H);
        mfma_gemm<ACT_NONE, true, false, false><<<dim3(6, 36), 256, 0, stream>>>(
            hb, wt_f2, f_b2 + (size_t)l * H, Bbuf, nullptr, nullptr, Mrows, H, FF);
        hipLaunchKernelGGL(lnres_kernel, dim3((int)BT), dim3(256), 0, stream,
                           x, Bbuf, ln2_s + (size_t)l * H, ln2_b + (size_t)l * H, xb);
    }

    // pooling heads
    hipLaunchKernelGGL(transpose_w, dim3(768 / 32, 1536 / 32), dim3(256), 0, stream,
                       key_w1, wt_k1, 768, 1536);
    hipLaunchKernelGGL(transpose_w, dim3(1536 / 32, 512 / 32), dim3(256), 0, stream,
                       key_w2, wt_k2, 1536, 512);
    hipLaunchKernelGGL(transpose_w, dim3(768 / 32, 1024 / 32), dim3(256), 0, stream,
                       val_w1, wt_v1, 768, 1024);
    hipLaunchKernelGGL(transpose_w, dim3(1024 / 32, 512 / 32), dim3(256), 0, stream,
                       val_w2, wt_v2, 1024, 512);

    mfma_gemm<ACT_RELU, false, true, false><<<dim3(12, 36), 256, 0, stream>>>(
        xb, wt_k1, key_b1, nullptr, key1b, nullptr, Mrows, 1536, H);
    mfma_gemm<ACT_SIGMOID, true, false, false><<<dim3(4, 36), 256, 0, stream>>>(
        key1b, wt_k2, key_b2, wgt, nullptr, nullptr, Mrows, 512, 1536);
    mfma_gemm<ACT_RELU, false, true, false><<<dim3(8, 36), 256, 0, stream>>>(
        xb, wt_v1, val_b1, nullptr, val1b, nullptr, Mrows, 1024, H);
    mfma_gemm<ACT_TANH, true, false, false><<<dim3(4, 36), 256, 0, stream>>>(
        val1b, wt_v2, val_b2, valf, nullptr, nullptr, Mrows, 512, 1024);
    hipLaunchKernelGGL(pool_kernel, dim3(B, E / 256), dim3(256), 0, stream,
                       wgt, valf, ttarr, out);
}

// Round 3
// 794.732 us; speedup vs baseline: 9.5395x; 1.2162x over previous
//
#include <hip/hip_runtime.h>
#include <hip/hip_bf16.h>

#define B 8
#define S 512
#define MM 64
#define T 576          // S + MM
#define H 768
#define NH 12
#define DH 64
#define FF 3072
#define E 512
#define NL 2

typedef __attribute__((ext_vector_type(8))) short bf16x8;
typedef __attribute__((ext_vector_type(4))) float f32x4;

__device__ inline unsigned short bf16_rne(float f) {
    unsigned u = __builtin_bit_cast(unsigned, f);
    unsigned r = u + 0x7FFFu + ((u >> 16) & 1u);
    return (unsigned short)(r >> 16);
}

__device__ inline f32x4 mfma16(bf16x8 a, bf16x8 b, f32x4 c) {
    return __builtin_amdgcn_mfma_f32_16x16x32_bf16(a, b, c, 0, 0, 0);
}

__device__ inline void load_lds16(const void* g, void* l) {
    __builtin_amdgcn_global_load_lds((const __attribute__((address_space(1))) void*)g,
                                     (__attribute__((address_space(3))) void*)l, 16, 0, 0);
}

// ---------------- order / argsort ----------------
__global__ void order_kernel(const int* __restrict__ mask, int* __restrict__ ord,
                             int* __restrict__ Larr) {
    __shared__ int ps[S];
    int b = blockIdx.x;
    int t = threadIdx.x;
    int mv = (mask[b * S + t] != 0) ? 1 : 0;
    ps[t] = mv;
    __syncthreads();
    for (int off = 1; off < S; off <<= 1) {
        int v = ps[t];
        int add = (t >= off) ? ps[t - off] : 0;
        __syncthreads();
        ps[t] = v + add;
        __syncthreads();
    }
    int L = ps[S - 1];
    int rank = mv ? (ps[t] - 1) : (L + (t - ps[t]));
    ord[b * S + rank] = t;
    if (t == 0) Larr[b] = L;
}

// ---------------- embedding + LN (writes f32 x and bf16 xb) ----------------
__global__ void embed_kernel(const int* __restrict__ ids, const int* __restrict__ toktype,
                             const int* __restrict__ ord, const int* __restrict__ Larr,
                             const float* __restrict__ word_emb, const float* __restrict__ pos_emb,
                             const float* __restrict__ type_emb, const float* __restrict__ memory,
                             const float* __restrict__ lns, const float* __restrict__ lnb,
                             float* __restrict__ x, unsigned short* __restrict__ xb,
                             int* __restrict__ ttarr) {
    int t = blockIdx.x;
    int b = blockIdx.y;
    int Lb = Larr[b];
    int tid = threadIdx.x;
    int tt;
    const float* src;
    if (t < Lb) {
        int sp = ord[b * S + t];
        tt = toktype[b * S + sp];
        src = &word_emb[(size_t)ids[b * S + sp] * H];
    } else if (t < Lb + MM) {
        tt = 1;
        src = &memory[(size_t)(t - Lb) * H];
    } else {
        int spp = t - MM;
        if (spp < 0) spp = 0;
        if (spp > S - 1) spp = S - 1;
        int sp = ord[b * S + spp];
        tt = 1;
        src = &word_emb[(size_t)ids[b * S + sp] * H];
    }
    __shared__ float row[H];
    __shared__ float r1[256], r2[256];
    float lsum = 0.f, lsq = 0.f;
    for (int hh = tid; hh < H; hh += 256) {
        float v = src[hh] + pos_emb[(size_t)t * H + hh] + type_emb[(size_t)tt * H + hh];
        row[hh] = v;
        lsum += v;
        lsq += v * v;
    }
    r1[tid] = lsum; r2[tid] = lsq;
    __syncthreads();
    for (int s = 128; s > 0; s >>= 1) {
        if (tid < s) { r1[tid] += r1[tid + s]; r2[tid] += r2[tid + s]; }
        __syncthreads();
    }
    float mu = r1[0] / H;
    float var = r2[0] / H - mu * mu;
    float inv = rsqrtf(var + 1e-12f);
    for (int hh = tid; hh < H; hh += 256) {
        float v = (row[hh] - mu) * inv * lns[hh] + lnb[hh];
        x[((size_t)b * T + t) * H + hh] = v;
        xb[((size_t)b * T + t) * H + hh] = bf16_rne(v);
    }
    if (tid == 0) ttarr[b * T + t] = tt;
}

// ---------------- activations ----------------
#define ACT_NONE 0
#define ACT_RELU 1
#define ACT_GELU 2
#define ACT_SIGMOID 3
#define ACT_TANH 4

template <int ACT>
__device__ inline float apply_act(float v) {
    if constexpr (ACT == ACT_RELU) return fmaxf(v, 0.f);
    else if constexpr (ACT == ACT_GELU) return 0.5f * v * (1.f + erff(v * 0.70710678118654752f));
    else if constexpr (ACT == ACT_SIGMOID) return 1.f / (1.f + expf(-v));
    else if constexpr (ACT == ACT_TANH) return tanhf(v);
    else return v;
}

// ---------------- fused weight transpose set: W[K][N] f32 -> Wt[N][K] bf16 ----------------
struct TDesc { const float* src; unsigned dstoff; int Kd; int Nd; int tile0; };
struct TTab { TDesc d[6]; int n; };

__global__ __launch_bounds__(256) void transpose_all(TTab tab, unsigned short* __restrict__ dstbase) {
    int tile = blockIdx.x;
    int mi = 0;
    #pragma unroll
    for (int i = 1; i < 6; ++i)
        if (i < tab.n && tab.d[i].tile0 <= tile) mi = i;
    TDesc d = tab.d[mi];
    int rel = tile - d.tile0;
    int tilesK = d.Kd >> 5;
    int kt = rel % tilesK, nt = rel / tilesK;
    __shared__ float ts[32][33];
    int k0 = kt * 32, n0 = nt * 32;
    int tx = threadIdx.x & 31, ty = threadIdx.x >> 5;  // 32 x 8
    #pragma unroll
    for (int r = 0; r < 4; ++r) {
        int kk = ty + r * 8;
        ts[kk][tx] = d.src[(size_t)(k0 + kk) * d.Nd + n0 + tx];
    }
    __syncthreads();
    unsigned short* Wt = dstbase + d.dstoff;
    #pragma unroll
    for (int r = 0; r < 4; ++r) {
        int nn = ty + r * 8;
        Wt[(size_t)(n0 + nn) * d.Kd + k0 + tx] = bf16_rne(ts[tx][nn]);
    }
}

// ---------------- MFMA GEMM: C[M,N] = act(A[M,K] @ Wt[N,K]^T + bias) ----------------
template <int ACT, bool F32OUT, bool BF16OUT, bool VTOUT>
__global__ __launch_bounds__(256) void mfma_gemm(
    const unsigned short* __restrict__ A, const unsigned short* __restrict__ Bt,
    const float* __restrict__ bias, const float* __restrict__ bias2, int bsplit,
    float* __restrict__ Cf, unsigned short* __restrict__ Cb, unsigned short* __restrict__ VtOut,
    int Mdim, int Ndim, int Kdim) {
    __shared__ unsigned short As[128 * 32];
    __shared__ unsigned short Bs[128 * 32];
    const int bn = blockIdx.x * 128, bm = blockIdx.y * 128;
    const int tid = threadIdx.x;
    const int w = tid >> 6, lane = tid & 63;
    const int lr = lane & 15, g = lane >> 4;
    const int wr = w >> 1, wc = w & 1;
    f32x4 acc[4][4] = {};
    const int srow = w * 32 + (lane >> 2);
    const int kc = (lane & 3) * 8;
    const unsigned short* ga0 = A + (size_t)(bm + srow) * Kdim + kc;
    const unsigned short* ga1 = A + (size_t)(bm + srow + 16) * Kdim + kc;
    const unsigned short* gb0 = Bt + (size_t)(bn + srow) * Kdim + kc;
    const unsigned short* gb1 = Bt + (size_t)(bn + srow + 16) * Kdim + kc;
    unsigned short* asb0 = &As[(w * 32) * 32];
    unsigned short* asb1 = &As[(w * 32 + 16) * 32];
    unsigned short* bsb0 = &Bs[(w * 32) * 32];
    unsigned short* bsb1 = &Bs[(w * 32 + 16) * 32];
    for (int k0 = 0; k0 < Kdim; k0 += 32) {
        load_lds16(ga0 + k0, asb0);
        load_lds16(ga1 + k0, asb1);
        load_lds16(gb0 + k0, bsb0);
        load_lds16(gb1 + k0, bsb1);
        __syncthreads();
        bf16x8 af[4], bfr[4];
        #pragma unroll
        for (int i = 0; i < 4; ++i)
            af[i] = *(const bf16x8*)&As[(wr * 64 + i * 16 + lr) * 32 + g * 8];
        #pragma unroll
        for (int j = 0; j < 4; ++j)
            bfr[j] = *(const bf16x8*)&Bs[(wc * 64 + j * 16 + lr) * 32 + g * 8];
        #pragma unroll
        for (int i = 0; i < 4; ++i)
            #pragma unroll
            for (int j = 0; j < 4; ++j)
                acc[i][j] = mfma16(af[i], bfr[j], acc[i][j]);
        __syncthreads();
    }
    #pragma unroll
    for (int i = 0; i < 4; ++i) {
        const int row0 = bm + wr * 64 + i * 16 + 4 * g;
        #pragma unroll
        for (int j = 0; j < 4; ++j) {
            const int col = bn + wc * 64 + j * 16 + lr;
            float bv = 0.f;
            if (bias) bv = (col < bsplit) ? bias[col] : bias2[col - bsplit];
            float vv[4];
            #pragma unroll
            for (int r = 0; r < 4; ++r) vv[r] = apply_act<ACT>(acc[i][j][r] + bv);
            if constexpr (F32OUT) {
                #pragma unroll
                for (int r = 0; r < 4; ++r) Cf[(size_t)(row0 + r) * Ndim + col] = vv[r];
            }
            if constexpr (BF16OUT) {
                #pragma unroll
                for (int r = 0; r < 4; ++r) Cb[(size_t)(row0 + r) * Ndim + col] = bf16_rne(vv[r]);
            }
            if constexpr (VTOUT) {
                int bb = row0 / T, t0 = row0 % T;
                int hh2 = col >> 6, dd = col & 63;
                unsigned lo = (unsigned)bf16_rne(vv[0]) | ((unsigned)bf16_rne(vv[1]) << 16);
                unsigned hi = (unsigned)bf16_rne(vv[2]) | ((unsigned)bf16_rne(vv[3]) << 16);
                size_t idx = (((size_t)bb * NH + hh2) * DH + dd) * T + t0;
                *(uint2*)&VtOut[idx] = make_uint2(lo, hi);
            }
        }
    }
}

// ---------------- MFMA flash attention ----------------
__global__ __launch_bounds__(64) void attn_mfma(
    const unsigned short* __restrict__ QK, const unsigned short* __restrict__ Vt,
    const int* __restrict__ Larr, unsigned short* __restrict__ ctxb) {
    const int q0 = blockIdx.x * 16;
    const int h = blockIdx.y, b = blockIdx.z;
    const int lane = threadIdx.x;
    const int lr = lane & 15, g = lane >> 4;
    const int LbMM = Larr[b] + MM;
    __shared__ unsigned short P[16][72];
    const unsigned short* qrow = QK + (size_t)(b * T + q0 + lr) * 1536 + h * 64;
    bf16x8 qf0 = *(const bf16x8*)(qrow + 8 * g);
    bf16x8 qf1 = *(const bf16x8*)(qrow + 32 + 8 * g);
    f32x4 ctx[4] = {};
    float m_run = -1e30f, l_run = 0.f;
    const size_t vbase = ((size_t)b * NH + h) * DH;
    for (int kt = 0; kt < T; kt += 64) {
        f32x4 sf[4];
        #pragma unroll
        for (int i = 0; i < 4; ++i) {
            const unsigned short* krow =
                QK + (size_t)(b * T + kt + 16 * i + lr) * 1536 + 768 + h * 64;
            bf16x8 kf0 = *(const bf16x8*)(krow + 8 * g);
            bf16x8 kf1 = *(const bf16x8*)(krow + 32 + 8 * g);
            f32x4 s = {};
            s = mfma16(kf0, qf0, s);
            s = mfma16(kf1, qf1, s);
            sf[i] = s;
        }
        float tmax = -1e30f;
        #pragma unroll
        for (int i = 0; i < 4; ++i)
            #pragma unroll
            for (int r = 0; r < 4; ++r) {
                int key = kt + 16 * i + 4 * g + r;
                float v = sf[i][r] * 0.125f + (key < LbMM ? 0.f : -10000.f);
                sf[i][r] = v;
                tmax = fmaxf(tmax, v);
            }
        tmax = fmaxf(tmax, __shfl_xor(tmax, 16));
        tmax = fmaxf(tmax, __shfl_xor(tmax, 32));
        float m_new = fmaxf(m_run, tmax);
        float scale = expf(m_run - m_new);
        m_run = m_new;
        float psum = 0.f;
        #pragma unroll
        for (int i = 0; i < 4; ++i)
            #pragma unroll
            for (int r = 0; r < 4; ++r) {
                float p = expf(sf[i][r] - m_new);
                sf[i][r] = p;
                psum += p;
            }
        l_run = l_run * scale + psum;
        float f0 = __shfl(scale, 4 * g + 0);
        float f1 = __shfl(scale, 4 * g + 1);
        float f2 = __shfl(scale, 4 * g + 2);
        float f3 = __shfl(scale, 4 * g + 3);
        #pragma unroll
        for (int j = 0; j < 4; ++j) {
            ctx[j][0] *= f0; ctx[j][1] *= f1; ctx[j][2] *= f2; ctx[j][3] *= f3;
        }
        #pragma unroll
        for (int i = 0; i < 4; ++i) {
            unsigned lo = (unsigned)bf16_rne(sf[i][0]) | ((unsigned)bf16_rne(sf[i][1]) << 16);
            unsigned hi = (unsigned)bf16_rne(sf[i][2]) | ((unsigned)bf16_rne(sf[i][3]) << 16);
            *(unsigned*)&P[lr][16 * i + 4 * g] = lo;
            *(unsigned*)&P[lr][16 * i + 4 * g + 2] = hi;
        }
        __syncthreads();
        #pragma unroll
        for (int s2 = 0; s2 < 2; ++s2) {
            bf16x8 pa = *(const bf16x8*)&P[lr][32 * s2 + 8 * g];
            #pragma unroll
            for (int j = 0; j < 4; ++j) {
                const unsigned short* vrow =
                    Vt + (vbase + 16 * j + lr) * T + kt + 32 * s2 + 8 * g;
                bf16x8 vf = *(const bf16x8*)vrow;
                ctx[j] = mfma16(pa, vf, ctx[j]);
            }
        }
        __syncthreads();
    }
    l_run += __shfl_xor(l_run, 16);
    l_run += __shfl_xor(l_run, 32);
    float inv = 1.f / l_run;
    float i0 = __shfl(inv, 4 * g + 0);
    float i1 = __shfl(inv, 4 * g + 1);
    float i2 = __shfl(inv, 4 * g + 2);
    float i3 = __shfl(inv, 4 * g + 3);
    float sc[4] = {i0, i1, i2, i3};
    #pragma unroll
    for (int j = 0; j < 4; ++j)
        #pragma unroll
        for (int r = 0; r < 4; ++r)
            ctxb[(size_t)(b * T + q0 + 4 * g + r) * H + h * 64 + 16 * j + lr] =
                bf16_rne(ctx[j][r] * sc[r]);
}

// ---------------- residual + LN ----------------
__global__ void lnres_kernel(float* __restrict__ x, const float* __restrict__ delta,
                             const float* __restrict__ s, const float* __restrict__ bvec,
                             unsigned short* __restrict__ xb) {
    int r = blockIdx.x;
    int tid = threadIdx.x;
    __shared__ float row[H];
    __shared__ float r1[256], r2[256];
    float lsum = 0.f, lsq = 0.f;
    size_t off = (size_t)r * H;
    for (int hh = tid; hh < H; hh += 256) {
        float v = x[off + hh] + delta[off + hh];
        row[hh] = v;
        lsum += v;
        lsq += v * v;
    }
    r1[tid] = lsum; r2[tid] = lsq;
    __syncthreads();
    for (int ss = 128; ss > 0; ss >>= 1) {
        if (tid < ss) { r1[tid] += r1[tid + ss]; r2[tid] += r2[tid + ss]; }
        __syncthreads();
    }
    float mu = r1[0] / H;
    float var = r2[0] / H - mu * mu;
    float inv = rsqrtf(var + 1e-12f);
    for (int hh = tid; hh < H; hh += 256) {
        float v = (row[hh] - mu) * inv * s[hh] + bvec[hh];
        x[off + hh] = v;
        xb[off + hh] = bf16_rne(v);
    }
}

// ---------------- masked softmax pooling (t-parallel) ----------------
__global__ __launch_bounds__(256) void pool_kernel(
    const float* __restrict__ weight, const float* __restrict__ value,
    const int* __restrict__ ttarr, float* __restrict__ out) {
    int b = blockIdx.x;
    int le = threadIdx.x & 31;
    int e = blockIdx.y * 32 + le;
    int tg = threadIdx.x >> 5;  // 0..7
    __shared__ int ttl[T];
    __shared__ float red[8][33];
    for (int t = threadIdx.x; t < T; t += 256) ttl[t] = ttarr[b * T + t];
    __syncthreads();
    float mx = -1e30f;
    for (int t = tg; t < T; t += 8) {
        if (ttl[t] == 1) continue;
        mx = fmaxf(mx, weight[((size_t)b * T + t) * E + e]);
    }
    red[tg][le] = mx;
    __syncthreads();
    #pragma unroll
    for (int i = 0; i < 8; ++i) mx = fmaxf(mx, red[i][le]);
    float den = 0.f, num = 0.f;
    for (int t = tg; t < T; t += 8) {
        if (ttl[t] == 1) continue;
        float w = expf(weight[((size_t)b * T + t) * E + e] - mx);
        den += w;
        num = fmaf(w, value[((size_t)b * T + t) * E + e], num);
    }
    __syncthreads();
    red[tg][le] = den;
    __syncthreads();
    float dtot = 0.f;
    #pragma unroll
    for (int i = 0; i < 8; ++i) dtot += red[i][le];
    __syncthreads();
    red[tg][le] = num;
    __syncthreads();
    float ntot = 0.f;
    #pragma unroll
    for (int i = 0; i < 8; ++i) ntot += red[i][le];
    if (tg == 0) out[(size_t)b * E + e] = fmaxf(ntot / dtot, 0.f);
}

// ---------------- host-side launch ----------------
extern "C" void kernel_launch(void* const* d_in, const int* in_sizes, int n_in,
                              void* d_out, int out_size, void* d_ws, size_t ws_size,
                              hipStream_t stream) {
    const int*   input_ids  = (const int*)d_in[0];
    const int*   token_type = (const int*)d_in[1];
    const int*   attn_mask  = (const int*)d_in[2];
    const float* word_emb   = (const float*)d_in[3];
    const float* pos_emb    = (const float*)d_in[4];
    const float* type_emb   = (const float*)d_in[5];
    const float* emb_ln_s   = (const float*)d_in[6];
    const float* emb_ln_b   = (const float*)d_in[7];
    const float* memory     = (const float*)d_in[8];
    const float* q_w  = (const float*)d_in[9];
    const float* q_b  = (const float*)d_in[10];
    const float* k_w  = (const float*)d_in[11];
    const float* k_b  = (const float*)d_in[12];
    const float* v_w  = (const float*)d_in[13];
    const float* v_b  = (const float*)d_in[14];
    const float* o_w  = (const float*)d_in[15];
    const float* o_b  = (const float*)d_in[16];
    const float* ln1_s = (const float*)d_in[17];
    const float* ln1_b = (const float*)d_in[18];
    const float* f_w1  = (const float*)d_in[19];
    const float* f_b1  = (const float*)d_in[20];
    const float* f_w2  = (const float*)d_in[21];
    const float* f_b2  = (const float*)d_in[22];
    const float* ln2_s = (const float*)d_in[23];
    const float* ln2_b = (const float*)d_in[24];
    const float* key_w1 = (const float*)d_in[25];
    const float* key_b1 = (const float*)d_in[26];
    const float* key_w2 = (const float*)d_in[27];
    const float* key_b2 = (const float*)d_in[28];
    const float* val_w1 = (const float*)d_in[29];
    const float* val_b1 = (const float*)d_in[30];
    const float* val_w2 = (const float*)d_in[31];
    const float* val_b2 = (const float*)d_in[32];
    float* out = (float*)d_out;

    char* ws = (char*)d_ws;
    size_t off = 0;
    auto alloc = [&](size_t bytes) {
        void* p = ws + off;
        off += (bytes + 255) & ~(size_t)255;
        return p;
    };
    const size_t BT  = (size_t)B * T;      // 4608
    const size_t BTH = BT * H;             // 3538944

    int*   ord   = (int*)alloc((size_t)B * S * 4);
    int*   Larr  = (int*)alloc(64);
    int*   ttarr = (int*)alloc(BT * 4);
    float* x     = (float*)alloc(BTH * 4);
    unsigned short* xb   = (unsigned short*)alloc(BTH * 2);
    unsigned short* reg1 = (unsigned short*)alloc(BT * FF * 2);
    float* Bbuf  = (float*)alloc(BTH * 4);
    unsigned short* wt = (unsigned short*)alloc((size_t)7077888 * 2);

    unsigned short* qkb  = reg1;                       // [BT][1536]
    unsigned short* Vtb  = reg1 + BT * 1536;           // [B][NH][DH][T]
    unsigned short* ctxb = reg1 + BT * 1536 + BTH;     // [BT][H]
    unsigned short* hb   = reg1;                       // [BT][FF] (FFN phase)
    unsigned short* key1b = reg1;                      // [BT][1536] (head phase)
    unsigned short* val1b = reg1 + BT * 1536;          // [BT][1024]
    float* wgt  = Bbuf;                                // [BT][512] f32
    float* valf = x;                                   // [BT][512] f32 (x dead by then)

    unsigned short* wt_qk = wt;                        // [1536][768]
    unsigned short* wt_v  = wt + (size_t)1536 * 768;   // [768][768]
    unsigned short* wt_o  = wt_v + (size_t)768 * 768;  // [768][768]
    unsigned short* wt_f1 = wt_o + (size_t)768 * 768;  // [3072][768]
    unsigned short* wt_f2 = wt_f1 + (size_t)3072 * 768;// [768][3072]
    unsigned short* wt_k1 = wt;                        // [1536][768]
    unsigned short* wt_k2 = wt + (size_t)1536 * 768;   // [512][1536]
    unsigned short* wt_v1 = wt_k2 + (size_t)512 * 1536;// [1024][768]
    unsigned short* wt_v2 = wt_v1 + (size_t)1024 * 768;// [512][1024]

    const int Mrows = (int)BT;  // 4608
    const size_t HH = (size_t)H * H;

    hipLaunchKernelGGL(order_kernel, dim3(B), dim3(S), 0, stream, attn_mask, ord, Larr);
    hipLaunchKernelGGL(embed_kernel, dim3(T, B), dim3(256), 0, stream,
                       input_ids, token_type, ord, Larr, word_emb, pos_emb, type_emb,
                       memory, emb_ln_s, emb_ln_b, x, xb, ttarr);

    for (int l = 0; l < NL; ++l) {
        // fused per-layer weight transpose (6 matrices, one launch)
        TTab tab;
        tab.n = 6;
        tab.d[0] = { q_w + l * HH,                 0u,                      H,  H,  0    };
        tab.d[1] = { k_w + l * HH,                 (unsigned)(768 * 768),   H,  H,  576  };
        tab.d[2] = { v_w + l * HH,                 (unsigned)(1536 * 768),  H,  H,  1152 };
        tab.d[3] = { o_w + l * HH,                 (unsigned)(2304 * 768),  H,  H,  1728 };
        tab.d[4] = { f_w1 + (size_t)l * H * FF,    (unsigned)(3072 * 768),  H,  FF, 2304 };
        tab.d[5] = { f_w2 + (size_t)l * FF * H,    (unsigned)(3072 * 768 + 3072 * 768), FF, H, 4608 };
        hipLaunchKernelGGL(transpose_all, dim3(6912), dim3(256), 0, stream, tab, wt);

        mfma_gemm<ACT_NONE, false, true, false><<<dim3(12, 36), 256, 0, stream>>>(
            xb, wt_qk, q_b + (size_t)l * H, k_b + (size_t)l * H, 768,
            nullptr, qkb, nullptr, Mrows, 1536, H);
        mfma_gemm<ACT_NONE, false, false, true><<<dim3(6, 36), 256, 0, stream>>>(
            xb, wt_v, v_b + (size_t)l * H, nullptr, 1 << 30,
            nullptr, nullptr, Vtb, Mrows, H, H);
        hipLaunchKernelGGL(attn_mfma, dim3(T / 16, NH, B), dim3(64), 0, stream,
                           qkb, Vtb, Larr, ctxb);
        mfma_gemm<ACT_NONE, true, false, false><<<dim3(6, 36), 256, 0, stream>>>(
            ctxb, wt_o, o_b + (size_t)l * H, nullptr, 1 << 30,
            Bbuf, nullptr, nullptr, Mrows, H, H);
        hipLaunchKernelGGL(lnres_kernel, dim3((int)BT), dim3(256), 0, stream,
                           x, Bbuf, ln1_s + (size_t)l * H, ln1_b + (size_t)l * H, xb);
        mfma_gemm<ACT_GELU, false, true, false><<<dim3(24, 36), 256, 0, stream>>>(
            xb, wt_f1, f_b1 + (size_t)l * FF, nullptr, 1 << 30,
            nullptr, hb, nullptr, Mrows, FF, H);
        mfma_gemm<ACT_NONE, true, false, false><<<dim3(6, 36), 256, 0, stream>>>(
            hb, wt_f2, f_b2 + (size_t)l * H, nullptr, 1 << 30,
            Bbuf, nullptr, nullptr, Mrows, H, FF);
        hipLaunchKernelGGL(lnres_kernel, dim3((int)BT), dim3(256), 0, stream,
                           x, Bbuf, ln2_s + (size_t)l * H, ln2_b + (size_t)l * H, xb);
    }

    // pooling heads: fused transpose (4 matrices, one launch)
    {
        TTab tab;
        tab.n = 4;
        tab.d[0] = { key_w1, 0u,                              H,    2 * H, 0    };
        tab.d[1] = { key_w2, (unsigned)(1536 * 768),          2 * H, E,    1152 };
        tab.d[2] = { val_w1, (unsigned)(1536 * 768 + 512 * 1536), H, 2 * E, 1920 };
        tab.d[3] = { val_w2, (unsigned)(1536 * 768 + 512 * 1536 + 1024 * 768), 2 * E, E, 2688 };
        hipLaunchKernelGGL(transpose_all, dim3(3200), dim3(256), 0, stream, tab, wt);
    }

    mfma_gemm<ACT_RELU, false, true, false><<<dim3(12, 36), 256, 0, stream>>>(
        xb, wt_k1, key_b1, nullptr, 1 << 30, nullptr, key1b, nullptr, Mrows, 1536, H);
    mfma_gemm<ACT_SIGMOID, true, false, false><<<dim3(4, 36), 256, 0, stream>>>(
        key1b, wt_k2, key_b2, nullptr, 1 << 30, wgt, nullptr, nullptr, Mrows, 512, 1536);
    mfma_gemm<ACT_RELU, false, true, false><<<dim3(8, 36), 256, 0, stream>>>(
        xb, wt_v1, val_b1, nullptr, 1 << 30, nullptr, val1b, nullptr, Mrows, 1024, H);
    mfma_gemm<ACT_TANH, true, false, false><<<dim3(4, 36), 256, 0, stream>>>(
        val1b, wt_v2, val_b2, nullptr, 1 << 30, valf, nullptr, nullptr, Mrows, 512, 1024);
    hipLaunchKernelGGL(pool_kernel, dim3(B, E / 32), dim3(256), 0, stream,
                       wgt, valf, ttarr, out);
}

// Round 4
// 676.970 us; speedup vs baseline: 11.1989x; 1.1740x over previous
//
#include <hip/hip_runtime.h>
#include <hip/hip_bf16.h>

#define B 8
#define S 512
#define MM 64
#define T 576          // S + MM
#define H 768
#define NH 12
#define DH 64
#define FF 3072
#define E 512
#define NL 2

typedef __attribute__((ext_vector_type(8))) short bf16x8;
typedef __attribute__((ext_vector_type(4))) float f32x4;

__device__ inline unsigned short bf16_rne(float f) {
    unsigned u = __builtin_bit_cast(unsigned, f);
    unsigned r = u + 0x7FFFu + ((u >> 16) & 1u);
    return (unsigned short)(r >> 16);
}

__device__ inline f32x4 mfma16(bf16x8 a, bf16x8 b, f32x4 c) {
    return __builtin_amdgcn_mfma_f32_16x16x32_bf16(a, b, c, 0, 0, 0);
}

__device__ inline void load_lds16(const void* g, void* l) {
    __builtin_amdgcn_global_load_lds((const __attribute__((address_space(1))) void*)g,
                                     (__attribute__((address_space(3))) void*)l, 16, 0, 0);
}

// ---------------- order / argsort ----------------
__global__ void order_kernel(const int* __restrict__ mask, int* __restrict__ ord,
                             int* __restrict__ Larr) {
    __shared__ int ps[S];
    int b = blockIdx.x;
    int t = threadIdx.x;
    int mv = (mask[b * S + t] != 0) ? 1 : 0;
    ps[t] = mv;
    __syncthreads();
    for (int off = 1; off < S; off <<= 1) {
        int v = ps[t];
        int add = (t >= off) ? ps[t - off] : 0;
        __syncthreads();
        ps[t] = v + add;
        __syncthreads();
    }
    int L = ps[S - 1];
    int rank = mv ? (ps[t] - 1) : (L + (t - ps[t]));
    ord[b * S + rank] = t;
    if (t == 0) Larr[b] = L;
}

// ---------------- embedding + LN (writes f32 x and bf16 xb) ----------------
__global__ void embed_kernel(const int* __restrict__ ids, const int* __restrict__ toktype,
                             const int* __restrict__ ord, const int* __restrict__ Larr,
                             const float* __restrict__ word_emb, const float* __restrict__ pos_emb,
                             const float* __restrict__ type_emb, const float* __restrict__ memory,
                             const float* __restrict__ lns, const float* __restrict__ lnb,
                             float* __restrict__ x, unsigned short* __restrict__ xb,
                             int* __restrict__ ttarr) {
    int t = blockIdx.x;
    int b = blockIdx.y;
    int Lb = Larr[b];
    int tid = threadIdx.x;
    int tt;
    const float* src;
    if (t < Lb) {
        int sp = ord[b * S + t];
        tt = toktype[b * S + sp];
        src = &word_emb[(size_t)ids[b * S + sp] * H];
    } else if (t < Lb + MM) {
        tt = 1;
        src = &memory[(size_t)(t - Lb) * H];
    } else {
        int spp = t - MM;
        if (spp < 0) spp = 0;
        if (spp > S - 1) spp = S - 1;
        int sp = ord[b * S + spp];
        tt = 1;
        src = &word_emb[(size_t)ids[b * S + sp] * H];
    }
    __shared__ float row[H];
    __shared__ float r1[256], r2[256];
    float lsum = 0.f, lsq = 0.f;
    for (int hh = tid; hh < H; hh += 256) {
        float v = src[hh] + pos_emb[(size_t)t * H + hh] + type_emb[(size_t)tt * H + hh];
        row[hh] = v;
        lsum += v;
        lsq += v * v;
    }
    r1[tid] = lsum; r2[tid] = lsq;
    __syncthreads();
    for (int s = 128; s > 0; s >>= 1) {
        if (tid < s) { r1[tid] += r1[tid + s]; r2[tid] += r2[tid + s]; }
        __syncthreads();
    }
    float mu = r1[0] / H;
    float var = r2[0] / H - mu * mu;
    float inv = rsqrtf(var + 1e-12f);
    for (int hh = tid; hh < H; hh += 256) {
        float v = (row[hh] - mu) * inv * lns[hh] + lnb[hh];
        x[((size_t)b * T + t) * H + hh] = v;
        xb[((size_t)b * T + t) * H + hh] = bf16_rne(v);
    }
    if (tid == 0) ttarr[b * T + t] = tt;
}

// ---------------- activations ----------------
#define ACT_NONE 0
#define ACT_RELU 1
#define ACT_GELU 2
#define ACT_SIGMOID 3
#define ACT_TANH 4

template <int ACT>
__device__ inline float apply_act(float v) {
    if constexpr (ACT == ACT_RELU) return fmaxf(v, 0.f);
    else if constexpr (ACT == ACT_GELU) return 0.5f * v * (1.f + erff(v * 0.70710678118654752f));
    else if constexpr (ACT == ACT_SIGMOID) return 1.f / (1.f + expf(-v));
    else if constexpr (ACT == ACT_TANH) return tanhf(v);
    else return v;
}

// ---------------- fused weight transpose set: W[K][N] f32 -> Wt[N][K] bf16 ----------------
struct TDesc { const float* src; unsigned dstoff; int Kd; int Nd; int tile0; };
struct TTab { TDesc d[6]; int n; };

__global__ __launch_bounds__(256) void transpose_all(TTab tab, unsigned short* __restrict__ dstbase) {
    int tile = blockIdx.x;
    int mi = 0;
    #pragma unroll
    for (int i = 1; i < 6; ++i)
        if (i < tab.n && tab.d[i].tile0 <= tile) mi = i;
    TDesc d = tab.d[mi];
    int rel = tile - d.tile0;
    int tilesK = d.Kd >> 5;
    int kt = rel % tilesK, nt = rel / tilesK;
    __shared__ float ts[32][33];
    int k0 = kt * 32, n0 = nt * 32;
    int tx = threadIdx.x & 31, ty = threadIdx.x >> 5;  // 32 x 8
    #pragma unroll
    for (int r = 0; r < 4; ++r) {
        int kk = ty + r * 8;
        ts[kk][tx] = d.src[(size_t)(k0 + kk) * d.Nd + n0 + tx];
    }
    __syncthreads();
    unsigned short* Wt = dstbase + d.dstoff;
    #pragma unroll
    for (int r = 0; r < 4; ++r) {
        int nn = ty + r * 8;
        Wt[(size_t)(n0 + nn) * d.Kd + k0 + tx] = bf16_rne(ts[tx][nn]);
    }
}

// ---------------- MFMA GEMM ----------------
// C[M,N] = act(A[M,K] @ Wt[N,K]^T + bias).  128x128 tile, BK=32, 4 waves,
// double-buffered LDS with counted vmcnt (T3-minimum), XOR slot swizzle (T2-partial),
// bijective XCD block swizzle (T1), setprio around MFMA (T5).
#define EPI_F32   0
#define EPI_BF16  1
#define EPI_QKV   2
#define EPI_SPLIT2 3

template <int ACT, int EPI>
__global__ __launch_bounds__(256) void mfma_gemm(
    const unsigned short* __restrict__ A, const unsigned short* __restrict__ Bt,
    const float* __restrict__ b0, const float* __restrict__ b1, const float* __restrict__ b2,
    int sp1, int sp2,
    float* __restrict__ Cf, unsigned short* __restrict__ Cb, unsigned short* __restrict__ Cb2,
    unsigned short* __restrict__ Vt, int n2w,
    int Mdim, int Ndim, int Kdim) {
    __shared__ unsigned short As[2][128 * 32];
    __shared__ unsigned short Bs[2][128 * 32];

    // bijective XCD swizzle (m204)
    const int gx = gridDim.x;
    const int nwg = gx * gridDim.y;
    int orig = blockIdx.y * gx + blockIdx.x;
    int q = nwg >> 3, r8 = nwg & 7;
    int xcd = orig & 7, idx = orig >> 3;
    int swz = (xcd < r8 ? xcd * (q + 1) : r8 * (q + 1) + (xcd - r8) * q) + idx;
    const int bn = (swz % gx) * 128, bm = (swz / gx) * 128;

    const int tid = threadIdx.x;
    const int w = tid >> 6, lane = tid & 63;
    const int lr = lane & 15, g = lane >> 4;
    const int wr = w >> 1, wc = w & 1;
    f32x4 acc[4][4] = {};

    // staging addresses: lane covers row (lane>>2), 16B slot (lane&3), slot pre-XOR'd by row&3
    const int srow = w * 32 + (lane >> 2);
    const int kc = (((lane & 3) ^ ((lane >> 2) & 3)) * 8);
    const unsigned short* ga0 = A + (size_t)(bm + srow) * Kdim + kc;
    const unsigned short* ga1 = A + (size_t)(bm + srow + 16) * Kdim + kc;
    const unsigned short* gb0 = Bt + (size_t)(bn + srow) * Kdim + kc;
    const unsigned short* gb1 = Bt + (size_t)(bn + srow + 16) * Kdim + kc;
    const int d0 = (w * 32) * 32, d1 = (w * 32 + 16) * 32;

    const int sw = (g ^ (lr & 3)) * 8;  // swizzled read slot

    auto stage = [&](int pp, int k0) {
        load_lds16(ga0 + k0, &As[pp][d0]);
        load_lds16(ga1 + k0, &As[pp][d1]);
        load_lds16(gb0 + k0, &Bs[pp][d0]);
        load_lds16(gb1 + k0, &Bs[pp][d1]);
    };
    auto compute = [&](int pp) {
        bf16x8 af[4], bfr[4];
        #pragma unroll
        for (int i = 0; i < 4; ++i)
            af[i] = *(const bf16x8*)&As[pp][(wr * 64 + i * 16 + lr) * 32 + sw];
        #pragma unroll
        for (int j = 0; j < 4; ++j)
            bfr[j] = *(const bf16x8*)&Bs[pp][(wc * 64 + j * 16 + lr) * 32 + sw];
        __builtin_amdgcn_s_setprio(1);
        #pragma unroll
        for (int i = 0; i < 4; ++i)
            #pragma unroll
            for (int j = 0; j < 4; ++j)
                acc[i][j] = mfma16(af[i], bfr[j], acc[i][j]);
        __builtin_amdgcn_s_setprio(0);
    };

    stage(0, 0);
    int p = 0;
    for (int k0 = 0; k0 < Kdim - 32; k0 += 32) {
        stage(p ^ 1, k0 + 32);
        asm volatile("s_waitcnt vmcnt(4)" ::: "memory");
        __builtin_amdgcn_s_barrier();
        __builtin_amdgcn_sched_barrier(0);
        compute(p);
        __builtin_amdgcn_sched_barrier(0);
        __builtin_amdgcn_s_barrier();
        __builtin_amdgcn_sched_barrier(0);
        p ^= 1;
    }
    asm volatile("s_waitcnt vmcnt(0)" ::: "memory");
    __builtin_amdgcn_s_barrier();
    __builtin_amdgcn_sched_barrier(0);
    compute(p);

    #pragma unroll
    for (int i = 0; i < 4; ++i) {
        const int row0 = bm + wr * 64 + i * 16 + 4 * g;
        #pragma unroll
        for (int j = 0; j < 4; ++j) {
            const int col = bn + wc * 64 + j * 16 + lr;
            float bv = (col < sp1) ? b0[col] : (col < sp2 ? b1[col - sp1] : b2[col - sp2]);
            float vv[4];
            #pragma unroll
            for (int r = 0; r < 4; ++r) vv[r] = apply_act<ACT>(acc[i][j][r] + bv);
            if constexpr (EPI == EPI_F32) {
                #pragma unroll
                for (int r = 0; r < 4; ++r) Cf[(size_t)(row0 + r) * Ndim + col] = vv[r];
            } else if constexpr (EPI == EPI_BF16) {
                #pragma unroll
                for (int r = 0; r < 4; ++r) Cb[(size_t)(row0 + r) * Ndim + col] = bf16_rne(vv[r]);
            } else if constexpr (EPI == EPI_QKV) {
                if (col < 1536) {
                    #pragma unroll
                    for (int r = 0; r < 4; ++r) Cb[(size_t)(row0 + r) * 1536 + col] = bf16_rne(vv[r]);
                } else {
                    int c2 = col - 1536;
                    int bb = row0 / T, t0 = row0 % T;
                    int hh2 = c2 >> 6, dd = c2 & 63;
                    unsigned lo = (unsigned)bf16_rne(vv[0]) | ((unsigned)bf16_rne(vv[1]) << 16);
                    unsigned hi = (unsigned)bf16_rne(vv[2]) | ((unsigned)bf16_rne(vv[3]) << 16);
                    size_t idxv = (((size_t)bb * NH + hh2) * DH + dd) * T + t0;
                    *(uint2*)&Vt[idxv] = make_uint2(lo, hi);
                }
            } else {  // EPI_SPLIT2
                if (col < sp1) {
                    #pragma unroll
                    for (int r = 0; r < 4; ++r) Cb[(size_t)(row0 + r) * sp1 + col] = bf16_rne(vv[r]);
                } else {
                    #pragma unroll
                    for (int r = 0; r < 4; ++r)
                        Cb2[(size_t)(row0 + r) * n2w + (col - sp1)] = bf16_rne(vv[r]);
                }
            }
        }
    }
}

// ---------------- MFMA flash attention ----------------
__global__ __launch_bounds__(64) void attn_mfma(
    const unsigned short* __restrict__ QK, const unsigned short* __restrict__ Vt,
    const int* __restrict__ Larr, unsigned short* __restrict__ ctxb) {
    const int q0 = blockIdx.x * 16;
    const int h = blockIdx.y, b = blockIdx.z;
    const int lane = threadIdx.x;
    const int lr = lane & 15, g = lane >> 4;
    const int LbMM = Larr[b] + MM;
    __shared__ unsigned short P[16][72];
    const unsigned short* qrow = QK + (size_t)(b * T + q0 + lr) * 1536 + h * 64;
    bf16x8 qf0 = *(const bf16x8*)(qrow + 8 * g);
    bf16x8 qf1 = *(const bf16x8*)(qrow + 32 + 8 * g);
    f32x4 ctx[4] = {};
    float m_run = -1e30f, l_run = 0.f;
    const size_t vbase = ((size_t)b * NH + h) * DH;
    for (int kt = 0; kt < T; kt += 64) {
        f32x4 sf[4];
        #pragma unroll
        for (int i = 0; i < 4; ++i) {
            const unsigned short* krow =
                QK + (size_t)(b * T + kt + 16 * i + lr) * 1536 + 768 + h * 64;
            bf16x8 kf0 = *(const bf16x8*)(krow + 8 * g);
            bf16x8 kf1 = *(const bf16x8*)(krow + 32 + 8 * g);
            f32x4 s = {};
            s = mfma16(kf0, qf0, s);
            s = mfma16(kf1, qf1, s);
            sf[i] = s;
        }
        float tmax = -1e30f;
        #pragma unroll
        for (int i = 0; i < 4; ++i)
            #pragma unroll
            for (int r = 0; r < 4; ++r) {
                int key = kt + 16 * i + 4 * g + r;
                float v = sf[i][r] * 0.125f + (key < LbMM ? 0.f : -10000.f);
                sf[i][r] = v;
                tmax = fmaxf(tmax, v);
            }
        tmax = fmaxf(tmax, __shfl_xor(tmax, 16));
        tmax = fmaxf(tmax, __shfl_xor(tmax, 32));
        float m_new = fmaxf(m_run, tmax);
        float scale = expf(m_run - m_new);
        m_run = m_new;
        float psum = 0.f;
        #pragma unroll
        for (int i = 0; i < 4; ++i)
            #pragma unroll
            for (int r = 0; r < 4; ++r) {
                float pv = expf(sf[i][r] - m_new);
                sf[i][r] = pv;
                psum += pv;
            }
        l_run = l_run * scale + psum;
        float f0 = __shfl(scale, 4 * g + 0);
        float f1 = __shfl(scale, 4 * g + 1);
        float f2 = __shfl(scale, 4 * g + 2);
        float f3 = __shfl(scale, 4 * g + 3);
        #pragma unroll
        for (int j = 0; j < 4; ++j) {
            ctx[j][0] *= f0; ctx[j][1] *= f1; ctx[j][2] *= f2; ctx[j][3] *= f3;
        }
        #pragma unroll
        for (int i = 0; i < 4; ++i) {
            unsigned lo = (unsigned)bf16_rne(sf[i][0]) | ((unsigned)bf16_rne(sf[i][1]) << 16);
            unsigned hi = (unsigned)bf16_rne(sf[i][2]) | ((unsigned)bf16_rne(sf[i][3]) << 16);
            *(unsigned*)&P[lr][16 * i + 4 * g] = lo;
            *(unsigned*)&P[lr][16 * i + 4 * g + 2] = hi;
        }
        __syncthreads();
        #pragma unroll
        for (int s2 = 0; s2 < 2; ++s2) {
            bf16x8 pa = *(const bf16x8*)&P[lr][32 * s2 + 8 * g];
            #pragma unroll
            for (int j = 0; j < 4; ++j) {
                const unsigned short* vrow =
                    Vt + (vbase + 16 * j + lr) * T + kt + 32 * s2 + 8 * g;
                bf16x8 vf = *(const bf16x8*)vrow;
                ctx[j] = mfma16(pa, vf, ctx[j]);
            }
        }
        __syncthreads();
    }
    l_run += __shfl_xor(l_run, 16);
    l_run += __shfl_xor(l_run, 32);
    float inv = 1.f / l_run;
    float i0 = __shfl(inv, 4 * g + 0);
    float i1 = __shfl(inv, 4 * g + 1);
    float i2 = __shfl(inv, 4 * g + 2);
    float i3 = __shfl(inv, 4 * g + 3);
    float sc[4] = {i0, i1, i2, i3};
    #pragma unroll
    for (int j = 0; j < 4; ++j)
        #pragma unroll
        for (int r = 0; r < 4; ++r)
            ctxb[(size_t)(b * T + q0 + 4 * g + r) * H + h * 64 + 16 * j + lr] =
                bf16_rne(ctx[j][r] * sc[r]);
}

// ---------------- residual + LN ----------------
__global__ void lnres_kernel(float* __restrict__ x, const float* __restrict__ delta,
                             const float* __restrict__ s, const float* __restrict__ bvec,
                             unsigned short* __restrict__ xb) {
    int r = blockIdx.x;
    int tid = threadIdx.x;
    __shared__ float row[H];
    __shared__ float r1[256], r2[256];
    float lsum = 0.f, lsq = 0.f;
    size_t off = (size_t)r * H;
    for (int hh = tid; hh < H; hh += 256) {
        float v = x[off + hh] + delta[off + hh];
        row[hh] = v;
        lsum += v;
        lsq += v * v;
    }
    r1[tid] = lsum; r2[tid] = lsq;
    __syncthreads();
    for (int ss = 128; ss > 0; ss >>= 1) {
        if (tid < ss) { r1[tid] += r1[tid + ss]; r2[tid] += r2[tid + ss]; }
        __syncthreads();
    }
    float mu = r1[0] / H;
    float var = r2[0] / H - mu * mu;
    float inv = rsqrtf(var + 1e-12f);
    for (int hh = tid; hh < H; hh += 256) {
        float v = (row[hh] - mu) * inv * s[hh] + bvec[hh];
        x[off + hh] = v;
        xb[off + hh] = bf16_rne(v);
    }
}

// ---------------- masked softmax pooling (t-parallel) ----------------
__global__ __launch_bounds__(256) void pool_kernel(
    const float* __restrict__ weight, const float* __restrict__ value,
    const int* __restrict__ ttarr, float* __restrict__ out) {
    int b = blockIdx.x;
    int le = threadIdx.x & 31;
    int e = blockIdx.y * 32 + le;
    int tg = threadIdx.x >> 5;  // 0..7
    __shared__ int ttl[T];
    __shared__ float red[8][33];
    for (int t = threadIdx.x; t < T; t += 256) ttl[t] = ttarr[b * T + t];
    __syncthreads();
    float mx = -1e30f;
    for (int t = tg; t < T; t += 8) {
        if (ttl[t] == 1) continue;
        mx = fmaxf(mx, weight[((size_t)b * T + t) * E + e]);
    }
    red[tg][le] = mx;
    __syncthreads();
    #pragma unroll
    for (int i = 0; i < 8; ++i) mx = fmaxf(mx, red[i][le]);
    float den = 0.f, num = 0.f;
    for (int t = tg; t < T; t += 8) {
        if (ttl[t] == 1) continue;
        float w = expf(weight[((size_t)b * T + t) * E + e] - mx);
        den += w;
        num = fmaf(w, value[((size_t)b * T + t) * E + e], num);
    }
    __syncthreads();
    red[tg][le] = den;
    __syncthreads();
    float dtot = 0.f;
    #pragma unroll
    for (int i = 0; i < 8; ++i) dtot += red[i][le];
    __syncthreads();
    red[tg][le] = num;
    __syncthreads();
    float ntot = 0.f;
    #pragma unroll
    for (int i = 0; i < 8; ++i) ntot += red[i][le];
    if (tg == 0) out[(size_t)b * E + e] = fmaxf(ntot / dtot, 0.f);
}

// ---------------- host-side launch ----------------
extern "C" void kernel_launch(void* const* d_in, const int* in_sizes, int n_in,
                              void* d_out, int out_size, void* d_ws, size_t ws_size,
                              hipStream_t stream) {
    const int*   input_ids  = (const int*)d_in[0];
    const int*   token_type = (const int*)d_in[1];
    const int*   attn_mask  = (const int*)d_in[2];
    const float* word_emb   = (const float*)d_in[3];
    const float* pos_emb    = (const float*)d_in[4];
    const float* type_emb   = (const float*)d_in[5];
    const float* emb_ln_s   = (const float*)d_in[6];
    const float* emb_ln_b   = (const float*)d_in[7];
    const float* memory     = (const float*)d_in[8];
    const float* q_w  = (const float*)d_in[9];
    const float* q_b  = (const float*)d_in[10];
    const float* k_w  = (const float*)d_in[11];
    const float* k_b  = (const float*)d_in[12];
    const float* v_w  = (const float*)d_in[13];
    const float* v_b  = (const float*)d_in[14];
    const float* o_w  = (const float*)d_in[15];
    const float* o_b  = (const float*)d_in[16];
    const float* ln1_s = (const float*)d_in[17];
    const float* ln1_b = (const float*)d_in[18];
    const float* f_w1  = (const float*)d_in[19];
    const float* f_b1  = (const float*)d_in[20];
    const float* f_w2  = (const float*)d_in[21];
    const float* f_b2  = (const float*)d_in[22];
    const float* ln2_s = (const float*)d_in[23];
    const float* ln2_b = (const float*)d_in[24];
    const float* key_w1 = (const float*)d_in[25];
    const float* key_b1 = (const float*)d_in[26];
    const float* key_w2 = (const float*)d_in[27];
    const float* key_b2 = (const float*)d_in[28];
    const float* val_w1 = (const float*)d_in[29];
    const float* val_b1 = (const float*)d_in[30];
    const float* val_w2 = (const float*)d_in[31];
    const float* val_b2 = (const float*)d_in[32];
    float* out = (float*)d_out;

    char* ws = (char*)d_ws;
    size_t off = 0;
    auto alloc = [&](size_t bytes) {
        void* p = ws + off;
        off += (bytes + 255) & ~(size_t)255;
        return p;
    };
    const size_t BT  = (size_t)B * T;      // 4608
    const size_t BTH = BT * H;             // 3538944

    int*   ord   = (int*)alloc((size_t)B * S * 4);
    int*   Larr  = (int*)alloc(64);
    int*   ttarr = (int*)alloc(BT * 4);
    float* x     = (float*)alloc(BTH * 4);
    unsigned short* xb   = (unsigned short*)alloc(BTH * 2);
    unsigned short* reg1 = (unsigned short*)alloc(BT * FF * 2);
    float* Bbuf  = (float*)alloc(BTH * 4);
    unsigned short* wt = (unsigned short*)alloc((size_t)7077888 * 2);

    unsigned short* qkb  = reg1;                       // [BT][1536]
    unsigned short* Vtb  = reg1 + BT * 1536;           // [B][NH][DH][T]
    unsigned short* ctxb = reg1 + BT * 1536 + BTH;     // [BT][H]
    unsigned short* hb   = reg1;                       // [BT][FF] (FFN phase)
    unsigned short* key1b = reg1;                      // [BT][1536] (head phase)
    unsigned short* val1b = reg1 + BT * 1536;          // [BT][1024]
    float* wgt  = Bbuf;                                // [BT][512] f32
    float* valf = x;                                   // [BT][512] f32 (x dead by then)

    unsigned short* wt_qkv = wt;                       // [2304][768] (q|k|v)
    unsigned short* wt_o  = wt + (size_t)2304 * 768;   // [768][768]
    unsigned short* wt_f1 = wt_o + (size_t)768 * 768;  // [3072][768]
    unsigned short* wt_f2 = wt_f1 + (size_t)3072 * 768;// [768][3072]
    unsigned short* wt_kv1 = wt;                       // [2560][768] (key1|val1)
    unsigned short* wt_k2 = wt + (size_t)2560 * 768;   // [512][1536]
    unsigned short* wt_v2 = wt_k2 + (size_t)512 * 1536;// [512][1024]

    const int Mrows = (int)BT;  // 4608
    const size_t HH = (size_t)H * H;
    const int BIG = 1 << 30;

    hipLaunchKernelGGL(order_kernel, dim3(B), dim3(S), 0, stream, attn_mask, ord, Larr);
    hipLaunchKernelGGL(embed_kernel, dim3(T, B), dim3(256), 0, stream,
                       input_ids, token_type, ord, Larr, word_emb, pos_emb, type_emb,
                       memory, emb_ln_s, emb_ln_b, x, xb, ttarr);

    for (int l = 0; l < NL; ++l) {
        TTab tab;
        tab.n = 6;
        tab.d[0] = { q_w + l * HH,              0u,                              H,  H,  0    };
        tab.d[1] = { k_w + l * HH,              (unsigned)(768 * 768),           H,  H,  576  };
        tab.d[2] = { v_w + l * HH,              (unsigned)(1536 * 768),          H,  H,  1152 };
        tab.d[3] = { o_w + l * HH,              (unsigned)(2304 * 768),          H,  H,  1728 };
        tab.d[4] = { f_w1 + (size_t)l * H * FF, (unsigned)(3072 * 768),          H,  FF, 2304 };
        tab.d[5] = { f_w2 + (size_t)l * FF * H, (unsigned)(6144 * 768),          FF, H,  4608 };
        hipLaunchKernelGGL(transpose_all, dim3(6912), dim3(256), 0, stream, tab, wt);

        // fused QKV GEMM: N=2304, tri-bias, qkb + Vt epilogue
        mfma_gemm<ACT_NONE, EPI_QKV><<<dim3(18, 36), 256, 0, stream>>>(
            xb, wt_qkv, q_b + (size_t)l * H, k_b + (size_t)l * H, v_b + (size_t)l * H,
            768, 1536, nullptr, qkb, nullptr, Vtb, 0, Mrows, 2304, H);
        hipLaunchKernelGGL(attn_mfma, dim3(T / 16, NH, B), dim3(64), 0, stream,
                           qkb, Vtb, Larr, ctxb);
        mfma_gemm<ACT_NONE, EPI_F32><<<dim3(6, 36), 256, 0, stream>>>(
            ctxb, wt_o, o_b + (size_t)l * H, nullptr, nullptr, BIG, BIG,
            Bbuf, nullptr, nullptr, nullptr, 0, Mrows, H, H);
        hipLaunchKernelGGL(lnres_kernel, dim3((int)BT), dim3(256), 0, stream,
                           x, Bbuf, ln1_s + (size_t)l * H, ln1_b + (size_t)l * H, xb);
        mfma_gemm<ACT_GELU, EPI_BF16><<<dim3(24, 36), 256, 0, stream>>>(
            xb, wt_f1, f_b1 + (size_t)l * FF, nullptr, nullptr, BIG, BIG,
            nullptr, hb, nullptr, nullptr, 0, Mrows, FF, H);
        mfma_gemm<ACT_NONE, EPI_F32><<<dim3(6, 36), 256, 0, stream>>>(
            hb, wt_f2, f_b2 + (size_t)l * H, nullptr, nullptr, BIG, BIG,
            Bbuf, nullptr, nullptr, nullptr, 0, Mrows, H, FF);
        hipLaunchKernelGGL(lnres_kernel, dim3((int)BT), dim3(256), 0, stream,
                           x, Bbuf, ln2_s + (size_t)l * H, ln2_b + (size_t)l * H, xb);
    }

    // pooling heads: fused transpose (4 matrices, one launch)
    {
        TTab tab;
        tab.n = 4;
        tab.d[0] = { key_w1, 0u,                               H,     2 * H, 0    };
        tab.d[1] = { val_w1, (unsigned)(1536 * 768),           H,     2 * E, 1152 };
        tab.d[2] = { key_w2, (unsigned)(2560 * 768),           2 * H, E,     1920 };
        tab.d[3] = { val_w2, (unsigned)(2560 * 768 + 512 * 1536), 2 * E, E,  2688 };
        tab.d[4] = { nullptr, 0u, 32, 32, 1 << 28 };
        tab.d[5] = { nullptr, 0u, 32, 32, 1 << 28 };
        hipLaunchKernelGGL(transpose_all, dim3(3200), dim3(256), 0, stream, tab, wt);
    }

    // fused key1|val1 GEMM: N=2560, split epilogue
    mfma_gemm<ACT_RELU, EPI_SPLIT2><<<dim3(20, 36), 256, 0, stream>>>(
        xb, wt_kv1, key_b1, val_b1, nullptr, 1536, BIG,
        nullptr, key1b, val1b, nullptr, 1024, Mrows, 2560, H);
    mfma_gemm<ACT_SIGMOID, EPI_F32><<<dim3(4, 36), 256, 0, stream>>>(
        key1b, wt_k2, key_b2, nullptr, nullptr, BIG, BIG,
        wgt, nullptr, nullptr, nullptr, 0, Mrows, 512, 1536);
    mfma_gemm<ACT_TANH, EPI_F32><<<dim3(4, 36), 256, 0, stream>>>(
        val1b, wt_v2, val_b2, nullptr, nullptr, BIG, BIG,
        valf, nullptr, nullptr, nullptr, 0, Mrows, 512, 1024);
    hipLaunchKernelGGL(pool_kernel, dim3(B, E / 32), dim3(256), 0, stream,
                       wgt, valf, ttarr, out);
}

// Round 5
// 646.567 us; speedup vs baseline: 11.7255x; 1.0470x over previous
//
#include <hip/hip_runtime.h>
#include <hip/hip_bf16.h>

#define B 8
#define S 512
#define MM 64
#define T 576          // S + MM
#define H 768
#define NH 12
#define DH 64
#define FF 3072
#define E 512
#define NL 2

typedef __attribute__((ext_vector_type(8))) short bf16x8;
typedef __attribute__((ext_vector_type(4))) float f32x4;

__device__ inline unsigned short bf16_rne(float f) {
    unsigned u = __builtin_bit_cast(unsigned, f);
    unsigned r = u + 0x7FFFu + ((u >> 16) & 1u);
    return (unsigned short)(r >> 16);
}

__device__ inline f32x4 mfma16(bf16x8 a, bf16x8 b, f32x4 c) {
    return __builtin_amdgcn_mfma_f32_16x16x32_bf16(a, b, c, 0, 0, 0);
}

__device__ inline void load_lds16(const void* g, void* l) {
    __builtin_amdgcn_global_load_lds((const __attribute__((address_space(1))) void*)g,
                                     (__attribute__((address_space(3))) void*)l, 16, 0, 0);
}

// ---------------- order / argsort ----------------
__global__ void order_kernel(const int* __restrict__ mask, int* __restrict__ ord,
                             int* __restrict__ Larr) {
    __shared__ int ps[S];
    int b = blockIdx.x;
    int t = threadIdx.x;
    int mv = (mask[b * S + t] != 0) ? 1 : 0;
    ps[t] = mv;
    __syncthreads();
    for (int off = 1; off < S; off <<= 1) {
        int v = ps[t];
        int add = (t >= off) ? ps[t - off] : 0;
        __syncthreads();
        ps[t] = v + add;
        __syncthreads();
    }
    int L = ps[S - 1];
    int rank = mv ? (ps[t] - 1) : (L + (t - ps[t]));
    ord[b * S + rank] = t;
    if (t == 0) Larr[b] = L;
}

// ---------------- embedding + LN (writes f32 x and bf16 xb) ----------------
__global__ void embed_kernel(const int* __restrict__ ids, const int* __restrict__ toktype,
                             const int* __restrict__ ord, const int* __restrict__ Larr,
                             const float* __restrict__ word_emb, const float* __restrict__ pos_emb,
                             const float* __restrict__ type_emb, const float* __restrict__ memory,
                             const float* __restrict__ lns, const float* __restrict__ lnb,
                             float* __restrict__ x, unsigned short* __restrict__ xb,
                             int* __restrict__ ttarr) {
    int t = blockIdx.x;
    int b = blockIdx.y;
    int Lb = Larr[b];
    int tid = threadIdx.x;
    int tt;
    const float* src;
    if (t < Lb) {
        int sp = ord[b * S + t];
        tt = toktype[b * S + sp];
        src = &word_emb[(size_t)ids[b * S + sp] * H];
    } else if (t < Lb + MM) {
        tt = 1;
        src = &memory[(size_t)(t - Lb) * H];
    } else {
        int spp = t - MM;
        if (spp < 0) spp = 0;
        if (spp > S - 1) spp = S - 1;
        int sp = ord[b * S + spp];
        tt = 1;
        src = &word_emb[(size_t)ids[b * S + sp] * H];
    }
    __shared__ float row[H];
    __shared__ float r1[256], r2[256];
    float lsum = 0.f, lsq = 0.f;
    for (int hh = tid; hh < H; hh += 256) {
        float v = src[hh] + pos_emb[(size_t)t * H + hh] + type_emb[(size_t)tt * H + hh];
        row[hh] = v;
        lsum += v;
        lsq += v * v;
    }
    r1[tid] = lsum; r2[tid] = lsq;
    __syncthreads();
    for (int s = 128; s > 0; s >>= 1) {
        if (tid < s) { r1[tid] += r1[tid + s]; r2[tid] += r2[tid + s]; }
        __syncthreads();
    }
    float mu = r1[0] / H;
    float var = r2[0] / H - mu * mu;
    float inv = rsqrtf(var + 1e-12f);
    for (int hh = tid; hh < H; hh += 256) {
        float v = (row[hh] - mu) * inv * lns[hh] + lnb[hh];
        x[((size_t)b * T + t) * H + hh] = v;
        xb[((size_t)b * T + t) * H + hh] = bf16_rne(v);
    }
    if (tid == 0) ttarr[b * T + t] = tt;
}

// ---------------- activations ----------------
#define ACT_NONE 0
#define ACT_RELU 1
#define ACT_GELU 2
#define ACT_SIGMOID 3
#define ACT_TANH 4

template <int ACT>
__device__ inline float apply_act(float v) {
    if constexpr (ACT == ACT_RELU) return fmaxf(v, 0.f);
    else if constexpr (ACT == ACT_GELU) return 0.5f * v * (1.f + erff(v * 0.70710678118654752f));
    else if constexpr (ACT == ACT_SIGMOID) return 1.f / (1.f + expf(-v));
    else if constexpr (ACT == ACT_TANH) return tanhf(v);
    else return v;
}

// ---------------- fused weight transpose set: W[K][N] f32 -> Wt[N][K] bf16 ----------------
struct TDesc { const float* src; unsigned dstoff; int Kd; int Nd; int tile0; };
struct TTab { TDesc d[6]; int n; };

__global__ __launch_bounds__(256) void transpose_all(TTab tab, unsigned short* __restrict__ dstbase) {
    int tile = blockIdx.x;
    int mi = 0;
    #pragma unroll
    for (int i = 1; i < 6; ++i)
        if (i < tab.n && tab.d[i].tile0 <= tile) mi = i;
    TDesc d = tab.d[mi];
    int rel = tile - d.tile0;
    int tilesK = d.Kd >> 5;
    int kt = rel % tilesK, nt = rel / tilesK;
    __shared__ float ts[32][33];
    int k0 = kt * 32, n0 = nt * 32;
    int tx = threadIdx.x & 31, ty = threadIdx.x >> 5;  // 32 x 8
    #pragma unroll
    for (int r = 0; r < 4; ++r) {
        int kk = ty + r * 8;
        ts[kk][tx] = d.src[(size_t)(k0 + kk) * d.Nd + n0 + tx];
    }
    __syncthreads();
    unsigned short* Wt = dstbase + d.dstoff;
    #pragma unroll
    for (int r = 0; r < 4; ++r) {
        int nn = ty + r * 8;
        Wt[(size_t)(n0 + nn) * d.Kd + k0 + tx] = bf16_rne(ts[tx][nn]);
    }
}

// ---------------- MFMA GEMM ----------------
#define EPI_F32   0
#define EPI_BF16  1
#define EPI_QKV   2
#define EPI_SPLIT2 3

template <int ACT, int EPI>
__global__ __launch_bounds__(256) void mfma_gemm(
    const unsigned short* __restrict__ A, const unsigned short* __restrict__ Bt,
    const float* __restrict__ b0, const float* __restrict__ b1, const float* __restrict__ b2,
    int sp1, int sp2,
    float* __restrict__ Cf, unsigned short* __restrict__ Cb, unsigned short* __restrict__ Cb2,
    unsigned short* __restrict__ Vt, int n2w,
    int Mdim, int Ndim, int Kdim) {
    __shared__ unsigned short As[2][128 * 32];
    __shared__ unsigned short Bs[2][128 * 32];

    // bijective XCD swizzle (m204)
    const int gx = gridDim.x;
    const int nwg = gx * gridDim.y;
    int orig = blockIdx.y * gx + blockIdx.x;
    int q = nwg >> 3, r8 = nwg & 7;
    int xcd = orig & 7, idx = orig >> 3;
    int swz = (xcd < r8 ? xcd * (q + 1) : r8 * (q + 1) + (xcd - r8) * q) + idx;
    const int bn = (swz % gx) * 128, bm = (swz / gx) * 128;

    const int tid = threadIdx.x;
    const int w = tid >> 6, lane = tid & 63;
    const int lr = lane & 15, g = lane >> 4;
    const int wr = w >> 1, wc = w & 1;
    f32x4 acc[4][4] = {};

    const int srow = w * 32 + (lane >> 2);
    const int kc = (((lane & 3) ^ ((lane >> 2) & 3)) * 8);
    const unsigned short* ga0 = A + (size_t)(bm + srow) * Kdim + kc;
    const unsigned short* ga1 = A + (size_t)(bm + srow + 16) * Kdim + kc;
    const unsigned short* gb0 = Bt + (size_t)(bn + srow) * Kdim + kc;
    const unsigned short* gb1 = Bt + (size_t)(bn + srow + 16) * Kdim + kc;
    const int d0 = (w * 32) * 32, d1 = (w * 32 + 16) * 32;

    const int sw = (g ^ (lr & 3)) * 8;  // swizzled read slot

    auto stage = [&](int pp, int k0) {
        load_lds16(ga0 + k0, &As[pp][d0]);
        load_lds16(ga1 + k0, &As[pp][d1]);
        load_lds16(gb0 + k0, &Bs[pp][d0]);
        load_lds16(gb1 + k0, &Bs[pp][d1]);
    };
    auto compute = [&](int pp) {
        bf16x8 af[4], bfr[4];
        #pragma unroll
        for (int i = 0; i < 4; ++i)
            af[i] = *(const bf16x8*)&As[pp][(wr * 64 + i * 16 + lr) * 32 + sw];
        #pragma unroll
        for (int j = 0; j < 4; ++j)
            bfr[j] = *(const bf16x8*)&Bs[pp][(wc * 64 + j * 16 + lr) * 32 + sw];
        __builtin_amdgcn_s_setprio(1);
        #pragma unroll
        for (int i = 0; i < 4; ++i)
            #pragma unroll
            for (int j = 0; j < 4; ++j)
                acc[i][j] = mfma16(af[i], bfr[j], acc[i][j]);
        __builtin_amdgcn_s_setprio(0);
    };

    stage(0, 0);
    int p = 0;
    for (int k0 = 0; k0 < Kdim - 32; k0 += 32) {
        stage(p ^ 1, k0 + 32);
        asm volatile("s_waitcnt vmcnt(4)" ::: "memory");
        __builtin_amdgcn_s_barrier();
        __builtin_amdgcn_sched_barrier(0);
        compute(p);
        __builtin_amdgcn_sched_barrier(0);
        __builtin_amdgcn_s_barrier();
        __builtin_amdgcn_sched_barrier(0);
        p ^= 1;
    }
    asm volatile("s_waitcnt vmcnt(0)" ::: "memory");
    __builtin_amdgcn_s_barrier();
    __builtin_amdgcn_sched_barrier(0);
    compute(p);

    #pragma unroll
    for (int i = 0; i < 4; ++i) {
        const int row0 = bm + wr * 64 + i * 16 + 4 * g;
        #pragma unroll
        for (int j = 0; j < 4; ++j) {
            const int col = bn + wc * 64 + j * 16 + lr;
            float bv = (col < sp1) ? b0[col] : (col < sp2 ? b1[col - sp1] : b2[col - sp2]);
            float vv[4];
            #pragma unroll
            for (int r = 0; r < 4; ++r) vv[r] = apply_act<ACT>(acc[i][j][r] + bv);
            if constexpr (EPI == EPI_F32) {
                #pragma unroll
                for (int r = 0; r < 4; ++r) Cf[(size_t)(row0 + r) * Ndim + col] = vv[r];
            } else if constexpr (EPI == EPI_BF16) {
                #pragma unroll
                for (int r = 0; r < 4; ++r) Cb[(size_t)(row0 + r) * Ndim + col] = bf16_rne(vv[r]);
            } else if constexpr (EPI == EPI_QKV) {
                if (col < 1536) {
                    #pragma unroll
                    for (int r = 0; r < 4; ++r) Cb[(size_t)(row0 + r) * 1536 + col] = bf16_rne(vv[r]);
                } else {
                    int c2 = col - 1536;
                    int bb = row0 / T, t0 = row0 % T;
                    int hh2 = c2 >> 6, dd = c2 & 63;
                    unsigned lo = (unsigned)bf16_rne(vv[0]) | ((unsigned)bf16_rne(vv[1]) << 16);
                    unsigned hi = (unsigned)bf16_rne(vv[2]) | ((unsigned)bf16_rne(vv[3]) << 16);
                    size_t idxv = (((size_t)bb * NH + hh2) * DH + dd) * T + t0;
                    *(uint2*)&Vt[idxv] = make_uint2(lo, hi);
                }
            } else {  // EPI_SPLIT2
                if (col < sp1) {
                    #pragma unroll
                    for (int r = 0; r < 4; ++r) Cb[(size_t)(row0 + r) * sp1 + col] = bf16_rne(vv[r]);
                } else {
                    #pragma unroll
                    for (int r = 0; r < 4; ++r)
                        Cb2[(size_t)(row0 + r) * n2w + (col - sp1)] = bf16_rne(vv[r]);
                }
            }
        }
    }
}

// ---------------- MFMA flash attention ----------------
// 4 waves/block, 64 q-rows/block; XCD-co-located heads: 1-D grid n=864,
// xcd = n&7 (dispatch round-robin), 12 (b,h) pairs per XCD -> K/V L2-resident.
// Fully-masked key tiles are skipped exactly (exp underflows to 0 in f32).
// Softmax in exp2 domain.
#define C2 0.180336880111116670f      // 0.125 * log2(e)
#define MB2 14426.950408889634f       // 10000 * log2(e)

__global__ __launch_bounds__(256) void attn_mfma(
    const unsigned short* __restrict__ QK, const unsigned short* __restrict__ Vt,
    const int* __restrict__ Larr, unsigned short* __restrict__ ctxb) {
    const int n = blockIdx.x;
    const int xcd = n & 7, k = n >> 3;
    const int p = xcd * 12 + k / 9, qt = k % 9;
    const int b = p / NH, h = p % NH;
    const int w = threadIdx.x >> 6, lane = threadIdx.x & 63;
    const int q0 = qt * 64 + w * 16;
    const int lr = lane & 15, g = lane >> 4;
    const int LbMM = Larr[b] + MM;
    const int ktend = min(T, (LbMM + 63) & ~63);  // skip fully-masked tiles (exact)
    __shared__ unsigned short P[4][16][72];
    const unsigned short* qrow = QK + (size_t)(b * T + q0 + lr) * 1536 + h * 64;
    bf16x8 qf0 = *(const bf16x8*)(qrow + 8 * g);
    bf16x8 qf1 = *(const bf16x8*)(qrow + 32 + 8 * g);
    f32x4 ctx[4] = {};
    float m_run = -1e30f, l_run = 0.f;
    const size_t vbase = ((size_t)b * NH + h) * DH;
    for (int kt = 0; kt < ktend; kt += 64) {
        f32x4 sf[4];
        #pragma unroll
        for (int i = 0; i < 4; ++i) {
            const unsigned short* krow =
                QK + (size_t)(b * T + kt + 16 * i + lr) * 1536 + 768 + h * 64;
            bf16x8 kf0 = *(const bf16x8*)(krow + 8 * g);
            bf16x8 kf1 = *(const bf16x8*)(krow + 32 + 8 * g);
            f32x4 s = {};
            s = mfma16(kf0, qf0, s);
            s = mfma16(kf1, qf1, s);
            sf[i] = s;
        }
        float tmax = -1e30f;
        #pragma unroll
        for (int i = 0; i < 4; ++i)
            #pragma unroll
            for (int r = 0; r < 4; ++r) {
                int key = kt + 16 * i + 4 * g + r;
                float v = sf[i][r] * C2 + (key < LbMM ? 0.f : -MB2);  // log2 domain
                sf[i][r] = v;
                tmax = fmaxf(tmax, v);
            }
        tmax = fmaxf(tmax, __shfl_xor(tmax, 16));
        tmax = fmaxf(tmax, __shfl_xor(tmax, 32));
        float m_new = fmaxf(m_run, tmax);
        float scale = exp2f(m_run - m_new);
        m_run = m_new;
        float psum = 0.f;
        #pragma unroll
        for (int i = 0; i < 4; ++i)
            #pragma unroll
            for (int r = 0; r < 4; ++r) {
                float pv = exp2f(sf[i][r] - m_new);
                sf[i][r] = pv;
                psum += pv;
            }
        l_run = l_run * scale + psum;
        float f0 = __shfl(scale, 4 * g + 0);
        float f1 = __shfl(scale, 4 * g + 1);
        float f2 = __shfl(scale, 4 * g + 2);
        float f3 = __shfl(scale, 4 * g + 3);
        #pragma unroll
        for (int j = 0; j < 4; ++j) {
            ctx[j][0] *= f0; ctx[j][1] *= f1; ctx[j][2] *= f2; ctx[j][3] *= f3;
        }
        #pragma unroll
        for (int i = 0; i < 4; ++i) {
            unsigned lo = (unsigned)bf16_rne(sf[i][0]) | ((unsigned)bf16_rne(sf[i][1]) << 16);
            unsigned hi = (unsigned)bf16_rne(sf[i][2]) | ((unsigned)bf16_rne(sf[i][3]) << 16);
            *(unsigned*)&P[w][lr][16 * i + 4 * g] = lo;
            *(unsigned*)&P[w][lr][16 * i + 4 * g + 2] = hi;
        }
        asm volatile("s_waitcnt lgkmcnt(0)" ::: "memory");   // per-wave P turnaround
        __builtin_amdgcn_sched_barrier(0);
        #pragma unroll
        for (int s2 = 0; s2 < 2; ++s2) {
            bf16x8 pa = *(const bf16x8*)&P[w][lr][32 * s2 + 8 * g];
            #pragma unroll
            for (int j = 0; j < 4; ++j) {
                const unsigned short* vrow =
                    Vt + (vbase + 16 * j + lr) * T + kt + 32 * s2 + 8 * g;
                bf16x8 vf = *(const bf16x8*)vrow;
                ctx[j] = mfma16(pa, vf, ctx[j]);
            }
        }
        asm volatile("s_waitcnt lgkmcnt(0)" ::: "memory");   // WAR: reads done before next writes
        __builtin_amdgcn_sched_barrier(0);
    }
    l_run += __shfl_xor(l_run, 16);
    l_run += __shfl_xor(l_run, 32);
    float inv = 1.f / l_run;
    float i0 = __shfl(inv, 4 * g + 0);
    float i1 = __shfl(inv, 4 * g + 1);
    float i2 = __shfl(inv, 4 * g + 2);
    float i3 = __shfl(inv, 4 * g + 3);
    float sc[4] = {i0, i1, i2, i3};
    #pragma unroll
    for (int j = 0; j < 4; ++j)
        #pragma unroll
        for (int r = 0; r < 4; ++r)
            ctxb[(size_t)(b * T + q0 + 4 * g + r) * H + h * 64 + 16 * j + lr] =
                bf16_rne(ctx[j][r] * sc[r]);
}

// ---------------- residual + LN ----------------
__global__ void lnres_kernel(float* __restrict__ x, const float* __restrict__ delta,
                             const float* __restrict__ s, const float* __restrict__ bvec,
                             unsigned short* __restrict__ xb) {
    int r = blockIdx.x;
    int tid = threadIdx.x;
    __shared__ float row[H];
    __shared__ float r1[256], r2[256];
    float lsum = 0.f, lsq = 0.f;
    size_t off = (size_t)r * H;
    for (int hh = tid; hh < H; hh += 256) {
        float v = x[off + hh] + delta[off + hh];
        row[hh] = v;
        lsum += v;
        lsq += v * v;
    }
    r1[tid] = lsum; r2[tid] = lsq;
    __syncthreads();
    for (int ss = 128; ss > 0; ss >>= 1) {
        if (tid < ss) { r1[tid] += r1[tid + ss]; r2[tid] += r2[tid + ss]; }
        __syncthreads();
    }
    float mu = r1[0] / H;
    float var = r2[0] / H - mu * mu;
    float inv = rsqrtf(var + 1e-12f);
    for (int hh = tid; hh < H; hh += 256) {
        float v = (row[hh] - mu) * inv * s[hh] + bvec[hh];
        x[off + hh] = v;
        xb[off + hh] = bf16_rne(v);
    }
}

// ---------------- masked softmax pooling (t-parallel) ----------------
__global__ __launch_bounds__(256) void pool_kernel(
    const float* __restrict__ weight, const float* __restrict__ value,
    const int* __restrict__ ttarr, float* __restrict__ out) {
    int b = blockIdx.x;
    int le = threadIdx.x & 31;
    int e = blockIdx.y * 32 + le;
    int tg = threadIdx.x >> 5;  // 0..7
    __shared__ int ttl[T];
    __shared__ float red[8][33];
    for (int t = threadIdx.x; t < T; t += 256) ttl[t] = ttarr[b * T + t];
    __syncthreads();
    float mx = -1e30f;
    for (int t = tg; t < T; t += 8) {
        if (ttl[t] == 1) continue;
        mx = fmaxf(mx, weight[((size_t)b * T + t) * E + e]);
    }
    red[tg][le] = mx;
    __syncthreads();
    #pragma unroll
    for (int i = 0; i < 8; ++i) mx = fmaxf(mx, red[i][le]);
    float den = 0.f, num = 0.f;
    for (int t = tg; t < T; t += 8) {
        if (ttl[t] == 1) continue;
        float w = expf(weight[((size_t)b * T + t) * E + e] - mx);
        den += w;
        num = fmaf(w, value[((size_t)b * T + t) * E + e], num);
    }
    __syncthreads();
    red[tg][le] = den;
    __syncthreads();
    float dtot = 0.f;
    #pragma unroll
    for (int i = 0; i < 8; ++i) dtot += red[i][le];
    __syncthreads();
    red[tg][le] = num;
    __syncthreads();
    float ntot = 0.f;
    #pragma unroll
    for (int i = 0; i < 8; ++i) ntot += red[i][le];
    if (tg == 0) out[(size_t)b * E + e] = fmaxf(ntot / dtot, 0.f);
}

// ---------------- host-side launch ----------------
extern "C" void kernel_launch(void* const* d_in, const int* in_sizes, int n_in,
                              void* d_out, int out_size, void* d_ws, size_t ws_size,
                              hipStream_t stream) {
    const int*   input_ids  = (const int*)d_in[0];
    const int*   token_type = (const int*)d_in[1];
    const int*   attn_mask  = (const int*)d_in[2];
    const float* word_emb   = (const float*)d_in[3];
    const float* pos_emb    = (const float*)d_in[4];
    const float* type_emb   = (const float*)d_in[5];
    const float* emb_ln_s   = (const float*)d_in[6];
    const float* emb_ln_b   = (const float*)d_in[7];
    const float* memory     = (const float*)d_in[8];
    const float* q_w  = (const float*)d_in[9];
    const float* q_b  = (const float*)d_in[10];
    const float* k_w  = (const float*)d_in[11];
    const float* k_b  = (const float*)d_in[12];
    const float* v_w  = (const float*)d_in[13];
    const float* v_b  = (const float*)d_in[14];
    const float* o_w  = (const float*)d_in[15];
    const float* o_b  = (const float*)d_in[16];
    const float* ln1_s = (const float*)d_in[17];
    const float* ln1_b = (const float*)d_in[18];
    const float* f_w1  = (const float*)d_in[19];
    const float* f_b1  = (const float*)d_in[20];
    const float* f_w2  = (const float*)d_in[21];
    const float* f_b2  = (const float*)d_in[22];
    const float* ln2_s = (const float*)d_in[23];
    const float* ln2_b = (const float*)d_in[24];
    const float* key_w1 = (const float*)d_in[25];
    const float* key_b1 = (const float*)d_in[26];
    const float* key_w2 = (const float*)d_in[27];
    const float* key_b2 = (const float*)d_in[28];
    const float* val_w1 = (const float*)d_in[29];
    const float* val_b1 = (const float*)d_in[30];
    const float* val_w2 = (const float*)d_in[31];
    const float* val_b2 = (const float*)d_in[32];
    float* out = (float*)d_out;

    char* ws = (char*)d_ws;
    size_t off = 0;
    auto alloc = [&](size_t bytes) {
        void* p = ws + off;
        off += (bytes + 255) & ~(size_t)255;
        return p;
    };
    const size_t BT  = (size_t)B * T;      // 4608
    const size_t BTH = BT * H;             // 3538944

    int*   ord   = (int*)alloc((size_t)B * S * 4);
    int*   Larr  = (int*)alloc(64);
    int*   ttarr = (int*)alloc(BT * 4);
    float* x     = (float*)alloc(BTH * 4);
    unsigned short* xb   = (unsigned short*)alloc(BTH * 2);
    unsigned short* reg1 = (unsigned short*)alloc(BT * FF * 2);
    float* Bbuf  = (float*)alloc(BTH * 4);
    unsigned short* wt = (unsigned short*)alloc((size_t)7077888 * 2);

    unsigned short* qkb  = reg1;                       // [BT][1536]
    unsigned short* Vtb  = reg1 + BT * 1536;           // [B][NH][DH][T]
    unsigned short* ctxb = reg1 + BT * 1536 + BTH;     // [BT][H]
    unsigned short* hb   = reg1;                       // [BT][FF] (FFN phase)
    unsigned short* key1b = reg1;                      // [BT][1536] (head phase)
    unsigned short* val1b = reg1 + BT * 1536;          // [BT][1024]
    float* wgt  = Bbuf;                                // [BT][512] f32
    float* valf = x;                                   // [BT][512] f32 (x dead by then)

    unsigned short* wt_qkv = wt;                       // [2304][768] (q|k|v)
    unsigned short* wt_o  = wt + (size_t)2304 * 768;   // [768][768]
    unsigned short* wt_f1 = wt_o + (size_t)768 * 768;  // [3072][768]
    unsigned short* wt_f2 = wt_f1 + (size_t)3072 * 768;// [768][3072]
    unsigned short* wt_kv1 = wt;                       // [2560][768] (key1|val1)
    unsigned short* wt_k2 = wt + (size_t)2560 * 768;   // [512][1536]
    unsigned short* wt_v2 = wt_k2 + (size_t)512 * 1536;// [512][1024]

    const int Mrows = (int)BT;  // 4608
    const size_t HH = (size_t)H * H;
    const int BIG = 1 << 30;

    hipLaunchKernelGGL(order_kernel, dim3(B), dim3(S), 0, stream, attn_mask, ord, Larr);
    hipLaunchKernelGGL(embed_kernel, dim3(T, B), dim3(256), 0, stream,
                       input_ids, token_type, ord, Larr, word_emb, pos_emb, type_emb,
                       memory, emb_ln_s, emb_ln_b, x, xb, ttarr);

    for (int l = 0; l < NL; ++l) {
        TTab tab;
        tab.n = 6;
        tab.d[0] = { q_w + l * HH,              0u,                              H,  H,  0    };
        tab.d[1] = { k_w + l * HH,              (unsigned)(768 * 768),           H,  H,  576  };
        tab.d[2] = { v_w + l * HH,              (unsigned)(1536 * 768),          H,  H,  1152 };
        tab.d[3] = { o_w + l * HH,              (unsigned)(2304 * 768),          H,  H,  1728 };
        tab.d[4] = { f_w1 + (size_t)l * H * FF, (unsigned)(3072 * 768),          H,  FF, 2304 };
        tab.d[5] = { f_w2 + (size_t)l * FF * H, (unsigned)(6144 * 768),          FF, H,  4608 };
        hipLaunchKernelGGL(transpose_all, dim3(6912), dim3(256), 0, stream, tab, wt);

        mfma_gemm<ACT_NONE, EPI_QKV><<<dim3(18, 36), 256, 0, stream>>>(
            xb, wt_qkv, q_b + (size_t)l * H, k_b + (size_t)l * H, v_b + (size_t)l * H,
            768, 1536, nullptr, qkb, nullptr, Vtb, 0, Mrows, 2304, H);
        hipLaunchKernelGGL(attn_mfma, dim3(864), dim3(256), 0, stream,
                           qkb, Vtb, Larr, ctxb);
        mfma_gemm<ACT_NONE, EPI_F32><<<dim3(6, 36), 256, 0, stream>>>(
            ctxb, wt_o, o_b + (size_t)l * H, nullptr, nullptr, BIG, BIG,
            Bbuf, nullptr, nullptr, nullptr, 0, Mrows, H, H);
        hipLaunchKernelGGL(lnres_kernel, dim3((int)BT), dim3(256), 0, stream,
                           x, Bbuf, ln1_s + (size_t)l * H, ln1_b + (size_t)l * H, xb);
        mfma_gemm<ACT_GELU, EPI_BF16><<<dim3(24, 36), 256, 0, stream>>>(
            xb, wt_f1, f_b1 + (size_t)l * FF, nullptr, nullptr, BIG, BIG,
            nullptr, hb, nullptr, nullptr, 0, Mrows, FF, H);
        mfma_gemm<ACT_NONE, EPI_F32><<<dim3(6, 36), 256, 0, stream>>>(
            hb, wt_f2, f_b2 + (size_t)l * H, nullptr, nullptr, BIG, BIG,
            Bbuf, nullptr, nullptr, nullptr, 0, Mrows, H, FF);
        hipLaunchKernelGGL(lnres_kernel, dim3((int)BT), dim3(256), 0, stream,
                           x, Bbuf, ln2_s + (size_t)l * H, ln2_b + (size_t)l * H, xb);
    }

    // pooling heads: fused transpose (4 matrices, one launch)
    {
        TTab tab;
        tab.n = 4;
        tab.d[0] = { key_w1, 0u,                               H,     2 * H, 0    };
        tab.d[1] = { val_w1, (unsigned)(1536 * 768),           H,     2 * E, 1152 };
        tab.d[2] = { key_w2, (unsigned)(2560 * 768),           2 * H, E,     1920 };
        tab.d[3] = { val_w2, (unsigned)(2560 * 768 + 512 * 1536), 2 * E, E,  2688 };
        tab.d[4] = { nullptr, 0u, 32, 32, 1 << 28 };
        tab.d[5] = { nullptr, 0u, 32, 32, 1 << 28 };
        hipLaunchKernelGGL(transpose_all, dim3(3200), dim3(256), 0, stream, tab, wt);
    }

    mfma_gemm<ACT_RELU, EPI_SPLIT2><<<dim3(20, 36), 256, 0, stream>>>(
        xb, wt_kv1, key_b1, val_b1, nullptr, 1536, BIG,
        nullptr, key1b, val1b, nullptr, 1024, Mrows, 2560, H);
    mfma_gemm<ACT_SIGMOID, EPI_F32><<<dim3(4, 36), 256, 0, stream>>>(
        key1b, wt_k2, key_b2, nullptr, nullptr, BIG, BIG,
        wgt, nullptr, nullptr, nullptr, 0, Mrows, 512, 1536);
    mfma_gemm<ACT_TANH, EPI_F32><<<dim3(4, 36), 256, 0, stream>>>(
        val1b, wt_v2, val_b2, nullptr, nullptr, BIG, BIG,
        valf, nullptr, nullptr, nullptr, 0, Mrows, 512, 1024);
    hipLaunchKernelGGL(pool_kernel, dim3(B, E / 32), dim3(256), 0, stream,
                       wgt, valf, ttarr, out);
}

// Round 6
// 585.203 us; speedup vs baseline: 12.9551x; 1.1049x over previous
//
#include <hip/hip_runtime.h>
#include <hip/hip_bf16.h>

#define B 8
#define S 512
#define MM 64
#define T 576          // S + MM
#define H 768
#define NH 12
#define DH 64
#define FF 3072
#define E 512
#define NL 2

typedef __attribute__((ext_vector_type(8))) short bf16x8;
typedef __attribute__((ext_vector_type(4))) float f32x4;

__device__ inline unsigned short bf16_rne(float f) {
    unsigned u = __builtin_bit_cast(unsigned, f);
    unsigned r = u + 0x7FFFu + ((u >> 16) & 1u);
    return (unsigned short)(r >> 16);
}

__device__ inline f32x4 mfma16(bf16x8 a, bf16x8 b, f32x4 c) {
    return __builtin_amdgcn_mfma_f32_16x16x32_bf16(a, b, c, 0, 0, 0);
}

__device__ inline void load_lds16(const void* g, void* l) {
    __builtin_amdgcn_global_load_lds((const __attribute__((address_space(1))) void*)g,
                                     (__attribute__((address_space(3))) void*)l, 16, 0, 0);
}

// ---------------- order / argsort ----------------
__global__ void order_kernel(const int* __restrict__ mask, int* __restrict__ ord,
                             int* __restrict__ Larr) {
    __shared__ int ps[S];
    int b = blockIdx.x;
    int t = threadIdx.x;
    int mv = (mask[b * S + t] != 0) ? 1 : 0;
    ps[t] = mv;
    __syncthreads();
    for (int off = 1; off < S; off <<= 1) {
        int v = ps[t];
        int add = (t >= off) ? ps[t - off] : 0;
        __syncthreads();
        ps[t] = v + add;
        __syncthreads();
    }
    int L = ps[S - 1];
    int rank = mv ? (ps[t] - 1) : (L + (t - ps[t]));
    ord[b * S + rank] = t;
    if (t == 0) Larr[b] = L;
}

// ---------------- embedding + LN (writes f32 x and bf16 xb) ----------------
__global__ void embed_kernel(const int* __restrict__ ids, const int* __restrict__ toktype,
                             const int* __restrict__ ord, const int* __restrict__ Larr,
                             const float* __restrict__ word_emb, const float* __restrict__ pos_emb,
                             const float* __restrict__ type_emb, const float* __restrict__ memory,
                             const float* __restrict__ lns, const float* __restrict__ lnb,
                             float* __restrict__ x, unsigned short* __restrict__ xb,
                             int* __restrict__ ttarr) {
    int t = blockIdx.x;
    int b = blockIdx.y;
    int Lb = Larr[b];
    int tid = threadIdx.x;
    int tt;
    const float* src;
    if (t < Lb) {
        int sp = ord[b * S + t];
        tt = toktype[b * S + sp];
        src = &word_emb[(size_t)ids[b * S + sp] * H];
    } else if (t < Lb + MM) {
        tt = 1;
        src = &memory[(size_t)(t - Lb) * H];
    } else {
        int spp = t - MM;
        if (spp < 0) spp = 0;
        if (spp > S - 1) spp = S - 1;
        int sp = ord[b * S + spp];
        tt = 1;
        src = &word_emb[(size_t)ids[b * S + sp] * H];
    }
    __shared__ float row[H];
    __shared__ float r1[256], r2[256];
    float lsum = 0.f, lsq = 0.f;
    for (int hh = tid; hh < H; hh += 256) {
        float v = src[hh] + pos_emb[(size_t)t * H + hh] + type_emb[(size_t)tt * H + hh];
        row[hh] = v;
        lsum += v;
        lsq += v * v;
    }
    r1[tid] = lsum; r2[tid] = lsq;
    __syncthreads();
    for (int s = 128; s > 0; s >>= 1) {
        if (tid < s) { r1[tid] += r1[tid + s]; r2[tid] += r2[tid + s]; }
        __syncthreads();
    }
    float mu = r1[0] / H;
    float var = r2[0] / H - mu * mu;
    float inv = rsqrtf(var + 1e-12f);
    for (int hh = tid; hh < H; hh += 256) {
        float v = (row[hh] - mu) * inv * lns[hh] + lnb[hh];
        x[((size_t)b * T + t) * H + hh] = v;
        xb[((size_t)b * T + t) * H + hh] = bf16_rne(v);
    }
    if (tid == 0) ttarr[b * T + t] = tt;
}

// ---------------- activations ----------------
#define ACT_NONE 0
#define ACT_RELU 1
#define ACT_GELU 2
#define ACT_SIGMOID 3
#define ACT_TANH 4

template <int ACT>
__device__ inline float apply_act(float v) {
    if constexpr (ACT == ACT_RELU) return fmaxf(v, 0.f);
    else if constexpr (ACT == ACT_GELU) return 0.5f * v * (1.f + erff(v * 0.70710678118654752f));
    else if constexpr (ACT == ACT_SIGMOID) return 1.f / (1.f + expf(-v));
    else if constexpr (ACT == ACT_TANH) return tanhf(v);
    else return v;
}

// ---------------- fused weight transpose set: W[K][N] f32 -> Wt[N][K] bf16 ----------------
struct TDesc { const float* src; unsigned dstoff; int Kd; int Nd; int tile0; };
struct TTab { TDesc d[6]; int n; };

__global__ __launch_bounds__(256) void transpose_all(TTab tab, unsigned short* __restrict__ dstbase) {
    int tile = blockIdx.x;
    int mi = 0;
    #pragma unroll
    for (int i = 1; i < 6; ++i)
        if (i < tab.n && tab.d[i].tile0 <= tile) mi = i;
    TDesc d = tab.d[mi];
    int rel = tile - d.tile0;
    int tilesK = d.Kd >> 5;
    int kt = rel % tilesK, nt = rel / tilesK;
    __shared__ float ts[32][33];
    int k0 = kt * 32, n0 = nt * 32;
    int tx = threadIdx.x & 31, ty = threadIdx.x >> 5;  // 32 x 8
    #pragma unroll
    for (int r = 0; r < 4; ++r) {
        int kk = ty + r * 8;
        ts[kk][tx] = d.src[(size_t)(k0 + kk) * d.Nd + n0 + tx];
    }
    __syncthreads();
    unsigned short* Wt = dstbase + d.dstoff;
    #pragma unroll
    for (int r = 0; r < 4; ++r) {
        int nn = ty + r * 8;
        Wt[(size_t)(n0 + nn) * d.Kd + k0 + tx] = bf16_rne(ts[tx][nn]);
    }
}

// ---------------- MFMA GEMM ----------------
// C[M,N] = act(A[M,K] @ Wt[N,K]^T + bias).  128x128 tile, BK=32, 4 waves,
// 3-deep LDS pipeline with counted vmcnt, XOR slot swizzle, bijective XCD
// swizzle, setprio around MFMA.  NSPLIT=2: blockIdx.z halves K; z0->Cf(+bias),
// z1->Cf2 (no bias, ACT must be NONE); consumer sums partials.
#define EPI_F32   0
#define EPI_BF16  1
#define EPI_QKV   2
#define EPI_SPLIT2 3

template <int ACT, int EPI, int NSPLIT>
__global__ __launch_bounds__(256) void mfma_gemm(
    const unsigned short* __restrict__ A, const unsigned short* __restrict__ Bt,
    const float* __restrict__ b0, const float* __restrict__ b1, const float* __restrict__ b2,
    int sp1, int sp2,
    float* __restrict__ Cf, float* __restrict__ Cf2,
    unsigned short* __restrict__ Cb, unsigned short* __restrict__ Cb2,
    unsigned short* __restrict__ Vt, int n2w,
    int Mdim, int Ndim, int Kdim) {
    __shared__ unsigned short As[3][128 * 32];
    __shared__ unsigned short Bs[3][128 * 32];

    // bijective XCD swizzle (m204) over the x-y grid
    const int gx = gridDim.x;
    const int nwg = gx * gridDim.y;
    int orig = blockIdx.y * gx + blockIdx.x;
    int q = nwg >> 3, r8 = nwg & 7;
    int xcd = orig & 7, idx = orig >> 3;
    int swz = (xcd < r8 ? xcd * (q + 1) : r8 * (q + 1) + (xcd - r8) * q) + idx;
    const int bn = (swz % gx) * 128, bm = (swz / gx) * 128;

    const int z = (NSPLIT > 1) ? blockIdx.z : 0;
    const int Klocal = Kdim / NSPLIT;
    const int koff = z * Klocal;

    const int tid = threadIdx.x;
    const int w = tid >> 6, lane = tid & 63;
    const int lr = lane & 15, g = lane >> 4;
    const int wr = w >> 1, wc = w & 1;
    f32x4 acc[4][4] = {};

    const int srow = w * 32 + (lane >> 2);
    const int kc = (((lane & 3) ^ ((lane >> 2) & 3)) * 8);
    const unsigned short* ga0 = A + (size_t)(bm + srow) * Kdim + kc;
    const unsigned short* ga1 = A + (size_t)(bm + srow + 16) * Kdim + kc;
    const unsigned short* gb0 = Bt + (size_t)(bn + srow) * Kdim + kc;
    const unsigned short* gb1 = Bt + (size_t)(bn + srow + 16) * Kdim + kc;
    const int d0 = (w * 32) * 32, d1 = (w * 32 + 16) * 32;

    const int sw = (g ^ (lr & 3)) * 8;  // swizzled read slot

    auto stage = [&](int pp, int k0) {
        load_lds16(ga0 + k0, &As[pp][d0]);
        load_lds16(ga1 + k0, &As[pp][d1]);
        load_lds16(gb0 + k0, &Bs[pp][d0]);
        load_lds16(gb1 + k0, &Bs[pp][d1]);
    };
    auto compute = [&](int pp) {
        bf16x8 af[4], bfr[4];
        #pragma unroll
        for (int i = 0; i < 4; ++i)
            af[i] = *(const bf16x8*)&As[pp][(wr * 64 + i * 16 + lr) * 32 + sw];
        #pragma unroll
        for (int j = 0; j < 4; ++j)
            bfr[j] = *(const bf16x8*)&Bs[pp][(wc * 64 + j * 16 + lr) * 32 + sw];
        __builtin_amdgcn_s_setprio(1);
        #pragma unroll
        for (int i = 0; i < 4; ++i)
            #pragma unroll
            for (int j = 0; j < 4; ++j)
                acc[i][j] = mfma16(af[i], bfr[j], acc[i][j]);
        __builtin_amdgcn_s_setprio(0);
    };

    const int nk = Klocal >> 5;
    stage(0, koff);
    if (nk > 1) stage(1, koff + 32);
    int p = 0;
    for (int s = 0; s < nk; ++s) {
        if (s + 2 < nk) {
            int pn = p + 2; if (pn >= 3) pn -= 3;
            stage(pn, koff + (s + 2) * 32);
            asm volatile("s_waitcnt vmcnt(8)" ::: "memory");
        } else if (s + 1 < nk) {
            asm volatile("s_waitcnt vmcnt(4)" ::: "memory");
        } else {
            asm volatile("s_waitcnt vmcnt(0)" ::: "memory");
        }
        __builtin_amdgcn_s_barrier();
        __builtin_amdgcn_sched_barrier(0);
        compute(p);
        __builtin_amdgcn_sched_barrier(0);
        __builtin_amdgcn_s_barrier();
        __builtin_amdgcn_sched_barrier(0);
        p = (p == 2) ? 0 : p + 1;
    }

    float* Cdst = (NSPLIT > 1 && z == 1) ? Cf2 : Cf;
    #pragma unroll
    for (int i = 0; i < 4; ++i) {
        const int row0 = bm + wr * 64 + i * 16 + 4 * g;
        #pragma unroll
        for (int j = 0; j < 4; ++j) {
            const int col = bn + wc * 64 + j * 16 + lr;
            float bv = (NSPLIT > 1 && z == 1) ? 0.f
                     : ((col < sp1) ? b0[col] : (col < sp2 ? b1[col - sp1] : b2[col - sp2]));
            float vv[4];
            #pragma unroll
            for (int r = 0; r < 4; ++r) vv[r] = apply_act<ACT>(acc[i][j][r] + bv);
            if constexpr (EPI == EPI_F32) {
                #pragma unroll
                for (int r = 0; r < 4; ++r) Cdst[(size_t)(row0 + r) * Ndim + col] = vv[r];
            } else if constexpr (EPI == EPI_BF16) {
                #pragma unroll
                for (int r = 0; r < 4; ++r) Cb[(size_t)(row0 + r) * Ndim + col] = bf16_rne(vv[r]);
            } else if constexpr (EPI == EPI_QKV) {
                if (col < 1536) {
                    #pragma unroll
                    for (int r = 0; r < 4; ++r) Cb[(size_t)(row0 + r) * 1536 + col] = bf16_rne(vv[r]);
                } else {
                    int c2 = col - 1536;
                    int bb = row0 / T, t0 = row0 % T;
                    int hh2 = c2 >> 6, dd = c2 & 63;
                    unsigned lo = (unsigned)bf16_rne(vv[0]) | ((unsigned)bf16_rne(vv[1]) << 16);
                    unsigned hi = (unsigned)bf16_rne(vv[2]) | ((unsigned)bf16_rne(vv[3]) << 16);
                    size_t idxv = (((size_t)bb * NH + hh2) * DH + dd) * T + t0;
                    *(uint2*)&Vt[idxv] = make_uint2(lo, hi);
                }
            } else {  // EPI_SPLIT2
                if (col < sp1) {
                    #pragma unroll
                    for (int r = 0; r < 4; ++r) Cb[(size_t)(row0 + r) * sp1 + col] = bf16_rne(vv[r]);
                } else {
                    #pragma unroll
                    for (int r = 0; r < 4; ++r)
                        Cb2[(size_t)(row0 + r) * n2w + (col - sp1)] = bf16_rne(vv[r]);
                }
            }
        }
    }
}

// ---------------- MFMA flash attention ----------------
#define C2 0.180336880111116670f      // 0.125 * log2(e)
#define MB2 14426.950408889634f       // 10000 * log2(e)

__global__ __launch_bounds__(256) void attn_mfma(
    const unsigned short* __restrict__ QK, const unsigned short* __restrict__ Vt,
    const int* __restrict__ Larr, unsigned short* __restrict__ ctxb) {
    const int n = blockIdx.x;
    const int xcd = n & 7, k = n >> 3;
    const int p = xcd * 12 + k / 9, qt = k % 9;
    const int b = p / NH, h = p % NH;
    const int w = threadIdx.x >> 6, lane = threadIdx.x & 63;
    const int q0 = qt * 64 + w * 16;
    const int lr = lane & 15, g = lane >> 4;
    const int LbMM = Larr[b] + MM;
    const int ktend = min(T, (LbMM + 63) & ~63);
    __shared__ unsigned short P[4][16][72];
    const unsigned short* qrow = QK + (size_t)(b * T + q0 + lr) * 1536 + h * 64;
    bf16x8 qf0 = *(const bf16x8*)(qrow + 8 * g);
    bf16x8 qf1 = *(const bf16x8*)(qrow + 32 + 8 * g);
    f32x4 ctx[4] = {};
    float m_run = -1e30f, l_run = 0.f;
    const size_t vbase = ((size_t)b * NH + h) * DH;
    for (int kt = 0; kt < ktend; kt += 64) {
        f32x4 sf[4];
        #pragma unroll
        for (int i = 0; i < 4; ++i) {
            const unsigned short* krow =
                QK + (size_t)(b * T + kt + 16 * i + lr) * 1536 + 768 + h * 64;
            bf16x8 kf0 = *(const bf16x8*)(krow + 8 * g);
            bf16x8 kf1 = *(const bf16x8*)(krow + 32 + 8 * g);
            f32x4 s = {};
            s = mfma16(kf0, qf0, s);
            s = mfma16(kf1, qf1, s);
            sf[i] = s;
        }
        float tmax = -1e30f;
        #pragma unroll
        for (int i = 0; i < 4; ++i)
            #pragma unroll
            for (int r = 0; r < 4; ++r) {
                int key = kt + 16 * i + 4 * g + r;
                float v = sf[i][r] * C2 + (key < LbMM ? 0.f : -MB2);
                sf[i][r] = v;
                tmax = fmaxf(tmax, v);
            }
        tmax = fmaxf(tmax, __shfl_xor(tmax, 16));
        tmax = fmaxf(tmax, __shfl_xor(tmax, 32));
        float m_new = fmaxf(m_run, tmax);
        float scale = exp2f(m_run - m_new);
        m_run = m_new;
        float psum = 0.f;
        #pragma unroll
        for (int i = 0; i < 4; ++i)
            #pragma unroll
            for (int r = 0; r < 4; ++r) {
                float pv = exp2f(sf[i][r] - m_new);
                sf[i][r] = pv;
                psum += pv;
            }
        l_run = l_run * scale + psum;
        float f0 = __shfl(scale, 4 * g + 0);
        float f1 = __shfl(scale, 4 * g + 1);
        float f2 = __shfl(scale, 4 * g + 2);
        float f3 = __shfl(scale, 4 * g + 3);
        #pragma unroll
        for (int j = 0; j < 4; ++j) {
            ctx[j][0] *= f0; ctx[j][1] *= f1; ctx[j][2] *= f2; ctx[j][3] *= f3;
        }
        #pragma unroll
        for (int i = 0; i < 4; ++i) {
            unsigned lo = (unsigned)bf16_rne(sf[i][0]) | ((unsigned)bf16_rne(sf[i][1]) << 16);
            unsigned hi = (unsigned)bf16_rne(sf[i][2]) | ((unsigned)bf16_rne(sf[i][3]) << 16);
            *(unsigned*)&P[w][lr][16 * i + 4 * g] = lo;
            *(unsigned*)&P[w][lr][16 * i + 4 * g + 2] = hi;
        }
        asm volatile("s_waitcnt lgkmcnt(0)" ::: "memory");
        __builtin_amdgcn_sched_barrier(0);
        #pragma unroll
        for (int s2 = 0; s2 < 2; ++s2) {
            bf16x8 pa = *(const bf16x8*)&P[w][lr][32 * s2 + 8 * g];
            #pragma unroll
            for (int j = 0; j < 4; ++j) {
                const unsigned short* vrow =
                    Vt + (vbase + 16 * j + lr) * T + kt + 32 * s2 + 8 * g;
                bf16x8 vf = *(const bf16x8*)vrow;
                ctx[j] = mfma16(pa, vf, ctx[j]);
            }
        }
        asm volatile("s_waitcnt lgkmcnt(0)" ::: "memory");
        __builtin_amdgcn_sched_barrier(0);
    }
    l_run += __shfl_xor(l_run, 16);
    l_run += __shfl_xor(l_run, 32);
    float inv = 1.f / l_run;
    float i0 = __shfl(inv, 4 * g + 0);
    float i1 = __shfl(inv, 4 * g + 1);
    float i2 = __shfl(inv, 4 * g + 2);
    float i3 = __shfl(inv, 4 * g + 3);
    float sc[4] = {i0, i1, i2, i3};
    #pragma unroll
    for (int j = 0; j < 4; ++j)
        #pragma unroll
        for (int r = 0; r < 4; ++r)
            ctxb[(size_t)(b * T + q0 + 4 * g + r) * H + h * 64 + 16 * j + lr] =
                bf16_rne(ctx[j][r] * sc[r]);
}

// ---------------- residual + LN (delta = d1 + d2) ----------------
__global__ void lnres_kernel(float* __restrict__ x, const float* __restrict__ d1,
                             const float* __restrict__ d2,
                             const float* __restrict__ s, const float* __restrict__ bvec,
                             unsigned short* __restrict__ xb) {
    int r = blockIdx.x;
    int tid = threadIdx.x;
    __shared__ float row[H];
    __shared__ float r1[256], r2[256];
    float lsum = 0.f, lsq = 0.f;
    size_t off = (size_t)r * H;
    for (int hh = tid; hh < H; hh += 256) {
        float v = x[off + hh] + d1[off + hh] + d2[off + hh];
        row[hh] = v;
        lsum += v;
        lsq += v * v;
    }
    r1[tid] = lsum; r2[tid] = lsq;
    __syncthreads();
    for (int ss = 128; ss > 0; ss >>= 1) {
        if (tid < ss) { r1[tid] += r1[tid + ss]; r2[tid] += r2[tid + ss]; }
        __syncthreads();
    }
    float mu = r1[0] / H;
    float var = r2[0] / H - mu * mu;
    float inv = rsqrtf(var + 1e-12f);
    for (int hh = tid; hh < H; hh += 256) {
        float v = (row[hh] - mu) * inv * s[hh] + bvec[hh];
        x[off + hh] = v;
        xb[off + hh] = bf16_rne(v);
    }
}

// ---------------- masked softmax pooling (sigmoid applied here; w = sigma(w0+w1)) ----------------
__global__ __launch_bounds__(256) void pool_kernel(
    const float* __restrict__ w0, const float* __restrict__ w1,
    const float* __restrict__ value,
    const int* __restrict__ ttarr, float* __restrict__ out) {
    int b = blockIdx.x;
    int le = threadIdx.x & 31;
    int e = blockIdx.y * 32 + le;
    int tg = threadIdx.x >> 5;  // 0..7
    __shared__ int ttl[T];
    __shared__ float red[8][33];
    for (int t = threadIdx.x; t < T; t += 256) ttl[t] = ttarr[b * T + t];
    __syncthreads();
    float mx = -1e30f;
    for (int t = tg; t < T; t += 8) {
        if (ttl[t] == 1) continue;
        size_t idx = ((size_t)b * T + t) * E + e;
        float w = 1.f / (1.f + expf(-(w0[idx] + w1[idx])));
        mx = fmaxf(mx, w);
    }
    red[tg][le] = mx;
    __syncthreads();
    #pragma unroll
    for (int i = 0; i < 8; ++i) mx = fmaxf(mx, red[i][le]);
    float den = 0.f, num = 0.f;
    for (int t = tg; t < T; t += 8) {
        if (ttl[t] == 1) continue;
        size_t idx = ((size_t)b * T + t) * E + e;
        float w = 1.f / (1.f + expf(-(w0[idx] + w1[idx])));
        float ew = expf(w - mx);
        den += ew;
        num = fmaf(ew, value[idx], num);
    }
    __syncthreads();
    red[tg][le] = den;
    __syncthreads();
    float dtot = 0.f;
    #pragma unroll
    for (int i = 0; i < 8; ++i) dtot += red[i][le];
    __syncthreads();
    red[tg][le] = num;
    __syncthreads();
    float ntot = 0.f;
    #pragma unroll
    for (int i = 0; i < 8; ++i) ntot += red[i][le];
    if (tg == 0) out[(size_t)b * E + e] = fmaxf(ntot / dtot, 0.f);
}

// ---------------- host-side launch ----------------
extern "C" void kernel_launch(void* const* d_in, const int* in_sizes, int n_in,
                              void* d_out, int out_size, void* d_ws, size_t ws_size,
                              hipStream_t stream) {
    const int*   input_ids  = (const int*)d_in[0];
    const int*   token_type = (const int*)d_in[1];
    const int*   attn_mask  = (const int*)d_in[2];
    const float* word_emb   = (const float*)d_in[3];
    const float* pos_emb    = (const float*)d_in[4];
    const float* type_emb   = (const float*)d_in[5];
    const float* emb_ln_s   = (const float*)d_in[6];
    const float* emb_ln_b   = (const float*)d_in[7];
    const float* memory     = (const float*)d_in[8];
    const float* q_w  = (const float*)d_in[9];
    const float* q_b  = (const float*)d_in[10];
    const float* k_w  = (const float*)d_in[11];
    const float* k_b  = (const float*)d_in[12];
    const float* v_w  = (const float*)d_in[13];
    const float* v_b  = (const float*)d_in[14];
    const float* o_w  = (const float*)d_in[15];
    const float* o_b  = (const float*)d_in[16];
    const float* ln1_s = (const float*)d_in[17];
    const float* ln1_b = (const float*)d_in[18];
    const float* f_w1  = (const float*)d_in[19];
    const float* f_b1  = (const float*)d_in[20];
    const float* f_w2  = (const float*)d_in[21];
    const float* f_b2  = (const float*)d_in[22];
    const float* ln2_s = (const float*)d_in[23];
    const float* ln2_b = (const float*)d_in[24];
    const float* key_w1 = (const float*)d_in[25];
    const float* key_b1 = (const float*)d_in[26];
    const float* key_w2 = (const float*)d_in[27];
    const float* key_b2 = (const float*)d_in[28];
    const float* val_w1 = (const float*)d_in[29];
    const float* val_b1 = (const float*)d_in[30];
    const float* val_w2 = (const float*)d_in[31];
    const float* val_b2 = (const float*)d_in[32];
    float* out = (float*)d_out;

    char* ws = (char*)d_ws;
    size_t off = 0;
    auto alloc = [&](size_t bytes) {
        void* p = ws + off;
        off += (bytes + 255) & ~(size_t)255;
        return p;
    };
    const size_t BT  = (size_t)B * T;      // 4608
    const size_t BTH = BT * H;             // 3538944

    int*   ord   = (int*)alloc((size_t)B * S * 4);
    int*   Larr  = (int*)alloc(64);
    int*   ttarr = (int*)alloc(BT * 4);
    float* x     = (float*)alloc(BTH * 4);
    unsigned short* xb   = (unsigned short*)alloc(BTH * 2);
    unsigned short* reg1 = (unsigned short*)alloc(BT * FF * 2);
    float* Bbuf  = (float*)alloc(BTH * 4);     // split-K partial z0
    float* part1 = (float*)alloc(BTH * 4);     // split-K partial z1
    unsigned short* wt = (unsigned short*)alloc((size_t)7077888 * 2);

    unsigned short* qkb  = reg1;                       // [BT][1536]
    unsigned short* Vtb  = reg1 + BT * 1536;           // [B][NH][DH][T]
    unsigned short* ctxb = reg1 + BT * 1536 + BTH;     // [BT][H]
    unsigned short* hb   = reg1;                       // [BT][FF] (FFN phase)
    unsigned short* key1b = reg1;                      // [BT][1536] (head phase)
    unsigned short* val1b = reg1 + BT * 1536;          // [BT][1024]
    float* valf = x;                                   // [BT][512] f32 (x dead by then)

    unsigned short* wt_qkv = wt;                       // [2304][768] (q|k|v)
    unsigned short* wt_o  = wt + (size_t)2304 * 768;   // [768][768]
    unsigned short* wt_f1 = wt_o + (size_t)768 * 768;  // [3072][768]
    unsigned short* wt_f2 = wt_f1 + (size_t)3072 * 768;// [768][3072]
    unsigned short* wt_kv1 = wt;                       // [2560][768] (key1|val1)
    unsigned short* wt_k2 = wt + (size_t)2560 * 768;   // [512][1536]
    unsigned short* wt_v2 = wt_k2 + (size_t)512 * 1536;// [512][1024]

    const int Mrows = (int)BT;  // 4608
    const size_t HH = (size_t)H * H;
    const int BIG = 1 << 30;

    hipLaunchKernelGGL(order_kernel, dim3(B), dim3(S), 0, stream, attn_mask, ord, Larr);
    hipLaunchKernelGGL(embed_kernel, dim3(T, B), dim3(256), 0, stream,
                       input_ids, token_type, ord, Larr, word_emb, pos_emb, type_emb,
                       memory, emb_ln_s, emb_ln_b, x, xb, ttarr);

    for (int l = 0; l < NL; ++l) {
        TTab tab;
        tab.n = 6;
        tab.d[0] = { q_w + l * HH,              0u,                              H,  H,  0    };
        tab.d[1] = { k_w + l * HH,              (unsigned)(768 * 768),           H,  H,  576  };
        tab.d[2] = { v_w + l * HH,              (unsigned)(1536 * 768),          H,  H,  1152 };
        tab.d[3] = { o_w + l * HH,              (unsigned)(2304 * 768),          H,  H,  1728 };
        tab.d[4] = { f_w1 + (size_t)l * H * FF, (unsigned)(3072 * 768),          H,  FF, 2304 };
        tab.d[5] = { f_w2 + (size_t)l * FF * H, (unsigned)(6144 * 768),          FF, H,  4608 };
        hipLaunchKernelGGL(transpose_all, dim3(6912), dim3(256), 0, stream, tab, wt);

        mfma_gemm<ACT_NONE, EPI_QKV, 1><<<dim3(18, 36), 256, 0, stream>>>(
            xb, wt_qkv, q_b + (size_t)l * H, k_b + (size_t)l * H, v_b + (size_t)l * H,
            768, 1536, nullptr, nullptr, qkb, nullptr, Vtb, 0, Mrows, 2304, H);
        hipLaunchKernelGGL(attn_mfma, dim3(864), dim3(256), 0, stream,
                           qkb, Vtb, Larr, ctxb);
        mfma_gemm<ACT_NONE, EPI_F32, 2><<<dim3(6, 36, 2), 256, 0, stream>>>(
            ctxb, wt_o, o_b + (size_t)l * H, nullptr, nullptr, BIG, BIG,
            Bbuf, part1, nullptr, nullptr, nullptr, 0, Mrows, H, H);
        hipLaunchKernelGGL(lnres_kernel, dim3((int)BT), dim3(256), 0, stream,
                           x, Bbuf, part1, ln1_s + (size_t)l * H, ln1_b + (size_t)l * H, xb);
        mfma_gemm<ACT_GELU, EPI_BF16, 1><<<dim3(24, 36), 256, 0, stream>>>(
            xb, wt_f1, f_b1 + (size_t)l * FF, nullptr, nullptr, BIG, BIG,
            nullptr, nullptr, hb, nullptr, nullptr, 0, Mrows, FF, H);
        mfma_gemm<ACT_NONE, EPI_F32, 2><<<dim3(6, 36, 2), 256, 0, stream>>>(
            hb, wt_f2, f_b2 + (size_t)l * H, nullptr, nullptr, BIG, BIG,
            Bbuf, part1, nullptr, nullptr, nullptr, 0, Mrows, H, FF);
        hipLaunchKernelGGL(lnres_kernel, dim3((int)BT), dim3(256), 0, stream,
                           x, Bbuf, part1, ln2_s + (size_t)l * H, ln2_b + (size_t)l * H, xb);
    }

    // pooling heads: fused transpose (4 matrices, one launch)
    {
        TTab tab;
        tab.n = 4;
        tab.d[0] = { key_w1, 0u,                               H,     2 * H, 0    };
        tab.d[1] = { val_w1, (unsigned)(1536 * 768),           H,     2 * E, 1152 };
        tab.d[2] = { key_w2, (unsigned)(2560 * 768),           2 * H, E,     1920 };
        tab.d[3] = { val_w2, (unsigned)(2560 * 768 + 512 * 1536), 2 * E, E,  2688 };
        tab.d[4] = { nullptr, 0u, 32, 32, 1 << 28 };
        tab.d[5] = { nullptr, 0u, 32, 32, 1 << 28 };
        hipLaunchKernelGGL(transpose_all, dim3(3200), dim3(256), 0, stream, tab, wt);
    }

    // fused key1|val1 GEMM: N=2560, split epilogue
    mfma_gemm<ACT_RELU, EPI_SPLIT2, 1><<<dim3(20, 36), 256, 0, stream>>>(
        xb, wt_kv1, key_b1, val_b1, nullptr, 1536, BIG,
        nullptr, nullptr, key1b, val1b, nullptr, 1024, Mrows, 2560, H);
    // key2: split-K, raw logits; sigmoid applied in pool
    mfma_gemm<ACT_NONE, EPI_F32, 2><<<dim3(4, 36, 2), 256, 0, stream>>>(
        key1b, wt_k2, key_b2, nullptr, nullptr, BIG, BIG,
        Bbuf, part1, nullptr, nullptr, nullptr, 0, Mrows, 512, 1536);
    // val2: unsplit, tanh epilogue
    mfma_gemm<ACT_TANH, EPI_F32, 1><<<dim3(4, 36), 256, 0, stream>>>(
        val1b, wt_v2, val_b2, nullptr, nullptr, BIG, BIG,
        valf, nullptr, nullptr, nullptr, nullptr, 0, Mrows, 512, 1024);
    hipLaunchKernelGGL(pool_kernel, dim3(B, E / 32), dim3(256), 0, stream,
                       Bbuf, part1, valf, ttarr, out);
}

// Round 7
// 580.577 us; speedup vs baseline: 13.0583x; 1.0080x over previous
//
#include <hip/hip_runtime.h>
#include <hip/hip_bf16.h>

#define B 8
#define S 512
#define MM 64
#define T 576          // S + MM
#define H 768
#define NH 12
#define DH 64
#define FF 3072
#define E 512
#define NL 2

typedef __attribute__((ext_vector_type(8))) short bf16x8;
typedef __attribute__((ext_vector_type(4))) float f32x4;

__device__ inline unsigned short bf16_rne(float f) {
    unsigned u = __builtin_bit_cast(unsigned, f);
    unsigned r = u + 0x7FFFu + ((u >> 16) & 1u);
    return (unsigned short)(r >> 16);
}

__device__ inline f32x4 mfma16(bf16x8 a, bf16x8 b, f32x4 c) {
    return __builtin_amdgcn_mfma_f32_16x16x32_bf16(a, b, c, 0, 0, 0);
}

__device__ inline void load_lds16(const void* g, void* l) {
    __builtin_amdgcn_global_load_lds((const __attribute__((address_space(1))) void*)g,
                                     (__attribute__((address_space(3))) void*)l, 16, 0, 0);
}

// ---------------- order / argsort ----------------
__global__ void order_kernel(const int* __restrict__ mask, int* __restrict__ ord,
                             int* __restrict__ Larr) {
    __shared__ int ps[S];
    int b = blockIdx.x;
    int t = threadIdx.x;
    int mv = (mask[b * S + t] != 0) ? 1 : 0;
    ps[t] = mv;
    __syncthreads();
    for (int off = 1; off < S; off <<= 1) {
        int v = ps[t];
        int add = (t >= off) ? ps[t - off] : 0;
        __syncthreads();
        ps[t] = v + add;
        __syncthreads();
    }
    int L = ps[S - 1];
    int rank = mv ? (ps[t] - 1) : (L + (t - ps[t]));
    ord[b * S + rank] = t;
    if (t == 0) Larr[b] = L;
}

// ---------------- embedding + LN (writes f32 x and bf16 xb) ----------------
__global__ void embed_kernel(const int* __restrict__ ids, const int* __restrict__ toktype,
                             const int* __restrict__ ord, const int* __restrict__ Larr,
                             const float* __restrict__ word_emb, const float* __restrict__ pos_emb,
                             const float* __restrict__ type_emb, const float* __restrict__ memory,
                             const float* __restrict__ lns, const float* __restrict__ lnb,
                             float* __restrict__ x, unsigned short* __restrict__ xb,
                             int* __restrict__ ttarr) {
    int t = blockIdx.x;
    int b = blockIdx.y;
    int Lb = Larr[b];
    int tid = threadIdx.x;
    int tt;
    const float* src;
    if (t < Lb) {
        int sp = ord[b * S + t];
        tt = toktype[b * S + sp];
        src = &word_emb[(size_t)ids[b * S + sp] * H];
    } else if (t < Lb + MM) {
        tt = 1;
        src = &memory[(size_t)(t - Lb) * H];
    } else {
        int spp = t - MM;
        if (spp < 0) spp = 0;
        if (spp > S - 1) spp = S - 1;
        int sp = ord[b * S + spp];
        tt = 1;
        src = &word_emb[(size_t)ids[b * S + sp] * H];
    }
    __shared__ float row[H];
    __shared__ float r1[256], r2[256];
    float lsum = 0.f, lsq = 0.f;
    for (int hh = tid; hh < H; hh += 256) {
        float v = src[hh] + pos_emb[(size_t)t * H + hh] + type_emb[(size_t)tt * H + hh];
        row[hh] = v;
        lsum += v;
        lsq += v * v;
    }
    r1[tid] = lsum; r2[tid] = lsq;
    __syncthreads();
    for (int s = 128; s > 0; s >>= 1) {
        if (tid < s) { r1[tid] += r1[tid + s]; r2[tid] += r2[tid + s]; }
        __syncthreads();
    }
    float mu = r1[0] / H;
    float var = r2[0] / H - mu * mu;
    float inv = rsqrtf(var + 1e-12f);
    for (int hh = tid; hh < H; hh += 256) {
        float v = (row[hh] - mu) * inv * lns[hh] + lnb[hh];
        x[((size_t)b * T + t) * H + hh] = v;
        xb[((size_t)b * T + t) * H + hh] = bf16_rne(v);
    }
    if (tid == 0) ttarr[b * T + t] = tt;
}

// ---------------- activations ----------------
#define ACT_NONE 0
#define ACT_RELU 1
#define ACT_GELU 2
#define ACT_SIGMOID 3
#define ACT_TANH 4

template <int ACT>
__device__ inline float apply_act(float v) {
    if constexpr (ACT == ACT_RELU) return fmaxf(v, 0.f);
    else if constexpr (ACT == ACT_GELU) {
        // exact-form GELU with A-S 7.1.26 erf (|err| <= 1.5e-7), exp2-based
        float y = v * 0.70710678118654752f;
        float a = fabsf(y);
        float t = 1.f / (1.f + 0.3275911f * a);
        float poly = t * (0.254829592f + t * (-0.284496736f + t * (1.421413741f +
                     t * (-1.453152027f + t * 1.061405429f))));
        float e = poly * exp2f(-a * a * 1.4426950408889634f);
        float erfv = 1.f - e;
        erfv = (y < 0.f) ? -erfv : erfv;
        return 0.5f * v * (1.f + erfv);
    }
    else if constexpr (ACT == ACT_SIGMOID) return 1.f / (1.f + expf(-v));
    else if constexpr (ACT == ACT_TANH) return tanhf(v);
    else return v;
}

// ---------------- fused weight transpose set: W[K][N] f32 -> Wt[N][K] bf16 ----------------
struct TDesc { const float* src; unsigned dstoff; int Kd; int Nd; int tile0; };
struct TTab { TDesc d[10]; int n; };

__global__ __launch_bounds__(256) void transpose_all(TTab tab, unsigned short* __restrict__ dstbase) {
    int tile = blockIdx.x;
    int mi = 0;
    #pragma unroll
    for (int i = 1; i < 10; ++i)
        if (i < tab.n && tab.d[i].tile0 <= tile) mi = i;
    TDesc d = tab.d[mi];
    int rel = tile - d.tile0;
    int tilesK = d.Kd >> 5;
    int kt = rel % tilesK, nt = rel / tilesK;
    __shared__ float ts[32][33];
    int k0 = kt * 32, n0 = nt * 32;
    int tx = threadIdx.x & 31, ty = threadIdx.x >> 5;  // 32 x 8
    #pragma unroll
    for (int r = 0; r < 4; ++r) {
        int kk = ty + r * 8;
        ts[kk][tx] = d.src[(size_t)(k0 + kk) * d.Nd + n0 + tx];
    }
    __syncthreads();
    unsigned short* Wt = dstbase + d.dstoff;
    #pragma unroll
    for (int r = 0; r < 4; ++r) {
        int nn = ty + r * 8;
        Wt[(size_t)(n0 + nn) * d.Kd + k0 + tx] = bf16_rne(ts[tx][nn]);
    }
}

// ---------------- MFMA GEMM ----------------
// C[M,N] = act(A[M,K] @ Wt[N,K]^T + bias).  128x128 tile, BK=32, 4 waves,
// 2-deep LDS dbuf (32KB -> ~5 blocks/CU) with counted vmcnt, XOR slot swizzle,
// bijective XCD swizzle, setprio around MFMA.  NSPLIT=2: blockIdx.z halves K;
// z0->Cf(+bias), z1->Cf2 (no bias, ACT must be NONE); consumer sums partials.
#define EPI_F32   0
#define EPI_BF16  1
#define EPI_QKV   2
#define EPI_SPLIT2 3

template <int ACT, int EPI, int NSPLIT>
__global__ __launch_bounds__(256) void mfma_gemm(
    const unsigned short* __restrict__ A, const unsigned short* __restrict__ Bt,
    const float* __restrict__ b0, const float* __restrict__ b1, const float* __restrict__ b2,
    int sp1, int sp2,
    float* __restrict__ Cf, float* __restrict__ Cf2,
    unsigned short* __restrict__ Cb, unsigned short* __restrict__ Cb2,
    unsigned short* __restrict__ Vt, int n2w,
    int Mdim, int Ndim, int Kdim) {
    __shared__ unsigned short As[2][128 * 32];
    __shared__ unsigned short Bs[2][128 * 32];

    // bijective XCD swizzle (m204) over the x-y grid
    const int gx = gridDim.x;
    const int nwg = gx * gridDim.y;
    int orig = blockIdx.y * gx + blockIdx.x;
    int q = nwg >> 3, r8 = nwg & 7;
    int xcd = orig & 7, idx = orig >> 3;
    int swz = (xcd < r8 ? xcd * (q + 1) : r8 * (q + 1) + (xcd - r8) * q) + idx;
    const int bn = (swz % gx) * 128, bm = (swz / gx) * 128;

    const int z = (NSPLIT > 1) ? blockIdx.z : 0;
    const int Klocal = Kdim / NSPLIT;
    const int koff = z * Klocal;

    const int tid = threadIdx.x;
    const int w = tid >> 6, lane = tid & 63;
    const int lr = lane & 15, g = lane >> 4;
    const int wr = w >> 1, wc = w & 1;
    f32x4 acc[4][4] = {};

    const int srow = w * 32 + (lane >> 2);
    const int kc = (((lane & 3) ^ ((lane >> 2) & 3)) * 8);
    const unsigned short* ga0 = A + (size_t)(bm + srow) * Kdim + kc;
    const unsigned short* ga1 = A + (size_t)(bm + srow + 16) * Kdim + kc;
    const unsigned short* gb0 = Bt + (size_t)(bn + srow) * Kdim + kc;
    const unsigned short* gb1 = Bt + (size_t)(bn + srow + 16) * Kdim + kc;
    const int d0 = (w * 32) * 32, d1 = (w * 32 + 16) * 32;

    const int sw = (g ^ (lr & 3)) * 8;  // swizzled read slot

    auto stage = [&](int pp, int k0) {
        load_lds16(ga0 + k0, &As[pp][d0]);
        load_lds16(ga1 + k0, &As[pp][d1]);
        load_lds16(gb0 + k0, &Bs[pp][d0]);
        load_lds16(gb1 + k0, &Bs[pp][d1]);
    };
    auto compute = [&](int pp) {
        bf16x8 af[4], bfr[4];
        #pragma unroll
        for (int i = 0; i < 4; ++i)
            af[i] = *(const bf16x8*)&As[pp][(wr * 64 + i * 16 + lr) * 32 + sw];
        #pragma unroll
        for (int j = 0; j < 4; ++j)
            bfr[j] = *(const bf16x8*)&Bs[pp][(wc * 64 + j * 16 + lr) * 32 + sw];
        __builtin_amdgcn_s_setprio(1);
        #pragma unroll
        for (int i = 0; i < 4; ++i)
            #pragma unroll
            for (int j = 0; j < 4; ++j)
                acc[i][j] = mfma16(af[i], bfr[j], acc[i][j]);
        __builtin_amdgcn_s_setprio(0);
    };

    const int nk = Klocal >> 5;
    stage(0, koff);
    int p = 0;
    for (int s = 0; s < nk; ++s) {
        if (s + 1 < nk) {
            stage(p ^ 1, koff + (s + 1) * 32);
            asm volatile("s_waitcnt vmcnt(4)" ::: "memory");
        } else {
            asm volatile("s_waitcnt vmcnt(0)" ::: "memory");
        }
        __builtin_amdgcn_s_barrier();
        __builtin_amdgcn_sched_barrier(0);
        compute(p);
        __builtin_amdgcn_sched_barrier(0);
        __builtin_amdgcn_s_barrier();
        __builtin_amdgcn_sched_barrier(0);
        p ^= 1;
    }

    float* Cdst = (NSPLIT > 1 && z == 1) ? Cf2 : Cf;
    #pragma unroll
    for (int i = 0; i < 4; ++i) {
        const int row0 = bm + wr * 64 + i * 16 + 4 * g;
        #pragma unroll
        for (int j = 0; j < 4; ++j) {
            const int col = bn + wc * 64 + j * 16 + lr;
            float bv = (NSPLIT > 1 && z == 1) ? 0.f
                     : ((col < sp1) ? b0[col] : (col < sp2 ? b1[col - sp1] : b2[col - sp2]));
            float vv[4];
            #pragma unroll
            for (int r = 0; r < 4; ++r) vv[r] = apply_act<ACT>(acc[i][j][r] + bv);
            if constexpr (EPI == EPI_F32) {
                #pragma unroll
                for (int r = 0; r < 4; ++r) Cdst[(size_t)(row0 + r) * Ndim + col] = vv[r];
            } else if constexpr (EPI == EPI_BF16) {
                #pragma unroll
                for (int r = 0; r < 4; ++r) Cb[(size_t)(row0 + r) * Ndim + col] = bf16_rne(vv[r]);
            } else if constexpr (EPI == EPI_QKV) {
                if (col < 1536) {
                    #pragma unroll
                    for (int r = 0; r < 4; ++r) Cb[(size_t)(row0 + r) * 1536 + col] = bf16_rne(vv[r]);
                } else {
                    int c2 = col - 1536;
                    int bb = row0 / T, t0 = row0 % T;
                    int hh2 = c2 >> 6, dd = c2 & 63;
                    unsigned lo = (unsigned)bf16_rne(vv[0]) | ((unsigned)bf16_rne(vv[1]) << 16);
                    unsigned hi = (unsigned)bf16_rne(vv[2]) | ((unsigned)bf16_rne(vv[3]) << 16);
                    size_t idxv = (((size_t)bb * NH + hh2) * DH + dd) * T + t0;
                    *(uint2*)&Vt[idxv] = make_uint2(lo, hi);
                }
            } else {  // EPI_SPLIT2
                if (col < sp1) {
                    #pragma unroll
                    for (int r = 0; r < 4; ++r) Cb[(size_t)(row0 + r) * sp1 + col] = bf16_rne(vv[r]);
                } else {
                    #pragma unroll
                    for (int r = 0; r < 4; ++r)
                        Cb2[(size_t)(row0 + r) * n2w + (col - sp1)] = bf16_rne(vv[r]);
                }
            }
        }
    }
}

// ---------------- MFMA flash attention ----------------
#define C2 0.180336880111116670f      // 0.125 * log2(e)
#define MB2 14426.950408889634f       // 10000 * log2(e)

__global__ __launch_bounds__(256) void attn_mfma(
    const unsigned short* __restrict__ QK, const unsigned short* __restrict__ Vt,
    const int* __restrict__ Larr, unsigned short* __restrict__ ctxb) {
    const int n = blockIdx.x;
    const int xcd = n & 7, k = n >> 3;
    const int p = xcd * 12 + k / 9, qt = k % 9;
    const int b = p / NH, h = p % NH;
    const int w = threadIdx.x >> 6, lane = threadIdx.x & 63;
    const int q0 = qt * 64 + w * 16;
    const int lr = lane & 15, g = lane >> 4;
    const int LbMM = Larr[b] + MM;
    const int ktend = min(T, (LbMM + 63) & ~63);
    __shared__ unsigned short P[4][16][72];
    const unsigned short* qrow = QK + (size_t)(b * T + q0 + lr) * 1536 + h * 64;
    bf16x8 qf0 = *(const bf16x8*)(qrow + 8 * g);
    bf16x8 qf1 = *(const bf16x8*)(qrow + 32 + 8 * g);
    f32x4 ctx[4] = {};
    float m_run = -1e30f, l_run = 0.f;
    const size_t vbase = ((size_t)b * NH + h) * DH;
    for (int kt = 0; kt < ktend; kt += 64) {
        f32x4 sf[4];
        #pragma unroll
        for (int i = 0; i < 4; ++i) {
            const unsigned short* krow =
                QK + (size_t)(b * T + kt + 16 * i + lr) * 1536 + 768 + h * 64;
            bf16x8 kf0 = *(const bf16x8*)(krow + 8 * g);
            bf16x8 kf1 = *(const bf16x8*)(krow + 32 + 8 * g);
            f32x4 s = {};
            s = mfma16(kf0, qf0, s);
            s = mfma16(kf1, qf1, s);
            sf[i] = s;
        }
        float tmax = -1e30f;
        #pragma unroll
        for (int i = 0; i < 4; ++i)
            #pragma unroll
            for (int r = 0; r < 4; ++r) {
                int key = kt + 16 * i + 4 * g + r;
                float v = sf[i][r] * C2 + (key < LbMM ? 0.f : -MB2);
                sf[i][r] = v;
                tmax = fmaxf(tmax, v);
            }
        tmax = fmaxf(tmax, __shfl_xor(tmax, 16));
        tmax = fmaxf(tmax, __shfl_xor(tmax, 32));
        float m_new = fmaxf(m_run, tmax);
        float scale = exp2f(m_run - m_new);
        m_run = m_new;
        float psum = 0.f;
        #pragma unroll
        for (int i = 0; i < 4; ++i)
            #pragma unroll
            for (int r = 0; r < 4; ++r) {
                float pv = exp2f(sf[i][r] - m_new);
                sf[i][r] = pv;
                psum += pv;
            }
        l_run = l_run * scale + psum;
        float f0 = __shfl(scale, 4 * g + 0);
        float f1 = __shfl(scale, 4 * g + 1);
        float f2 = __shfl(scale, 4 * g + 2);
        float f3 = __shfl(scale, 4 * g + 3);
        #pragma unroll
        for (int j = 0; j < 4; ++j) {
            ctx[j][0] *= f0; ctx[j][1] *= f1; ctx[j][2] *= f2; ctx[j][3] *= f3;
        }
        #pragma unroll
        for (int i = 0; i < 4; ++i) {
            unsigned lo = (unsigned)bf16_rne(sf[i][0]) | ((unsigned)bf16_rne(sf[i][1]) << 16);
            unsigned hi = (unsigned)bf16_rne(sf[i][2]) | ((unsigned)bf16_rne(sf[i][3]) << 16);
            *(unsigned*)&P[w][lr][16 * i + 4 * g] = lo;
            *(unsigned*)&P[w][lr][16 * i + 4 * g + 2] = hi;
        }
        asm volatile("s_waitcnt lgkmcnt(0)" ::: "memory");
        __builtin_amdgcn_sched_barrier(0);
        #pragma unroll
        for (int s2 = 0; s2 < 2; ++s2) {
            bf16x8 pa = *(const bf16x8*)&P[w][lr][32 * s2 + 8 * g];
            #pragma unroll
            for (int j = 0; j < 4; ++j) {
                const unsigned short* vrow =
                    Vt + (vbase + 16 * j + lr) * T + kt + 32 * s2 + 8 * g;
                bf16x8 vf = *(const bf16x8*)vrow;
                ctx[j] = mfma16(pa, vf, ctx[j]);
            }
        }
        asm volatile("s_waitcnt lgkmcnt(0)" ::: "memory");
        __builtin_amdgcn_sched_barrier(0);
    }
    l_run += __shfl_xor(l_run, 16);
    l_run += __shfl_xor(l_run, 32);
    float inv = 1.f / l_run;
    float i0 = __shfl(inv, 4 * g + 0);
    float i1 = __shfl(inv, 4 * g + 1);
    float i2 = __shfl(inv, 4 * g + 2);
    float i3 = __shfl(inv, 4 * g + 3);
    float sc[4] = {i0, i1, i2, i3};
    #pragma unroll
    for (int j = 0; j < 4; ++j)
        #pragma unroll
        for (int r = 0; r < 4; ++r)
            ctxb[(size_t)(b * T + q0 + 4 * g + r) * H + h * 64 + 16 * j + lr] =
                bf16_rne(ctx[j][r] * sc[r]);
}

// ---------------- residual + LN (delta = d1 + d2) ----------------
__global__ void lnres_kernel(float* __restrict__ x, const float* __restrict__ d1,
                             const float* __restrict__ d2,
                             const float* __restrict__ s, const float* __restrict__ bvec,
                             unsigned short* __restrict__ xb) {
    int r = blockIdx.x;
    int tid = threadIdx.x;
    __shared__ float row[H];
    __shared__ float r1[256], r2[256];
    float lsum = 0.f, lsq = 0.f;
    size_t off = (size_t)r * H;
    for (int hh = tid; hh < H; hh += 256) {
        float v = x[off + hh] + d1[off + hh] + d2[off + hh];
        row[hh] = v;
        lsum += v;
        lsq += v * v;
    }
    r1[tid] = lsum; r2[tid] = lsq;
    __syncthreads();
    for (int ss = 128; ss > 0; ss >>= 1) {
        if (tid < ss) { r1[tid] += r1[tid + ss]; r2[tid] += r2[tid + ss]; }
        __syncthreads();
    }
    float mu = r1[0] / H;
    float var = r2[0] / H - mu * mu;
    float inv = rsqrtf(var + 1e-12f);
    for (int hh = tid; hh < H; hh += 256) {
        float v = (row[hh] - mu) * inv * s[hh] + bvec[hh];
        x[off + hh] = v;
        xb[off + hh] = bf16_rne(v);
    }
}

// ---------------- masked softmax pooling (sigmoid applied here; w = sigma(w0+w1)) ----------------
__global__ __launch_bounds__(256) void pool_kernel(
    const float* __restrict__ w0, const float* __restrict__ w1,
    const float* __restrict__ value,
    const int* __restrict__ ttarr, float* __restrict__ out) {
    int b = blockIdx.x;
    int le = threadIdx.x & 31;
    int e = blockIdx.y * 32 + le;
    int tg = threadIdx.x >> 5;  // 0..7
    __shared__ int ttl[T];
    __shared__ float red[8][33];
    for (int t = threadIdx.x; t < T; t += 256) ttl[t] = ttarr[b * T + t];
    __syncthreads();
    float mx = -1e30f;
    for (int t = tg; t < T; t += 8) {
        if (ttl[t] == 1) continue;
        size_t idx = ((size_t)b * T + t) * E + e;
        float w = 1.f / (1.f + expf(-(w0[idx] + w1[idx])));
        mx = fmaxf(mx, w);
    }
    red[tg][le] = mx;
    __syncthreads();
    #pragma unroll
    for (int i = 0; i < 8; ++i) mx = fmaxf(mx, red[i][le]);
    float den = 0.f, num = 0.f;
    for (int t = tg; t < T; t += 8) {
        if (ttl[t] == 1) continue;
        size_t idx = ((size_t)b * T + t) * E + e;
        float w = 1.f / (1.f + expf(-(w0[idx] + w1[idx])));
        float ew = expf(w - mx);
        den += ew;
        num = fmaf(ew, value[idx], num);
    }
    __syncthreads();
    red[tg][le] = den;
    __syncthreads();
    float dtot = 0.f;
    #pragma unroll
    for (int i = 0; i < 8; ++i) dtot += red[i][le];
    __syncthreads();
    red[tg][le] = num;
    __syncthreads();
    float ntot = 0.f;
    #pragma unroll
    for (int i = 0; i < 8; ++i) ntot += red[i][le];
    if (tg == 0) out[(size_t)b * E + e] = fmaxf(ntot / dtot, 0.f);
}

// ---------------- host-side launch ----------------
extern "C" void kernel_launch(void* const* d_in, const int* in_sizes, int n_in,
                              void* d_out, int out_size, void* d_ws, size_t ws_size,
                              hipStream_t stream) {
    const int*   input_ids  = (const int*)d_in[0];
    const int*   token_type = (const int*)d_in[1];
    const int*   attn_mask  = (const int*)d_in[2];
    const float* word_emb   = (const float*)d_in[3];
    const float* pos_emb    = (const float*)d_in[4];
    const float* type_emb   = (const float*)d_in[5];
    const float* emb_ln_s   = (const float*)d_in[6];
    const float* emb_ln_b   = (const float*)d_in[7];
    const float* memory     = (const float*)d_in[8];
    const float* q_w  = (const float*)d_in[9];
    const float* q_b  = (const float*)d_in[10];
    const float* k_w  = (const float*)d_in[11];
    const float* k_b  = (const float*)d_in[12];
    const float* v_w  = (const float*)d_in[13];
    const float* v_b  = (const float*)d_in[14];
    const float* o_w  = (const float*)d_in[15];
    const float* o_b  = (const float*)d_in[16];
    const float* ln1_s = (const float*)d_in[17];
    const float* ln1_b = (const float*)d_in[18];
    const float* f_w1  = (const float*)d_in[19];
    const float* f_b1  = (const float*)d_in[20];
    const float* f_w2  = (const float*)d_in[21];
    const float* f_b2  = (const float*)d_in[22];
    const float* ln2_s = (const float*)d_in[23];
    const float* ln2_b = (const float*)d_in[24];
    const float* key_w1 = (const float*)d_in[25];
    const float* key_b1 = (const float*)d_in[26];
    const float* key_w2 = (const float*)d_in[27];
    const float* key_b2 = (const float*)d_in[28];
    const float* val_w1 = (const float*)d_in[29];
    const float* val_b1 = (const float*)d_in[30];
    const float* val_w2 = (const float*)d_in[31];
    const float* val_b2 = (const float*)d_in[32];
    float* out = (float*)d_out;

    char* ws = (char*)d_ws;
    size_t off = 0;
    auto alloc = [&](size_t bytes) {
        void* p = ws + off;
        off += (bytes + 255) & ~(size_t)255;
        return p;
    };
    const size_t BT  = (size_t)B * T;      // 4608
    const size_t BTH = BT * H;             // 3538944

    int*   ord   = (int*)alloc((size_t)B * S * 4);
    int*   Larr  = (int*)alloc(64);
    int*   ttarr = (int*)alloc(BT * 4);
    float* x     = (float*)alloc(BTH * 4);
    unsigned short* xb   = (unsigned short*)alloc(BTH * 2);
    unsigned short* reg1 = (unsigned short*)alloc(BT * FF * 2);
    float* Bbuf  = (float*)alloc(BTH * 4);     // split-K partial z0
    float* part1 = (float*)alloc(BTH * 4);     // split-K partial z1
    // wt: per-layer region (7,077,888) + head region (3,276,800)
    unsigned short* wt = (unsigned short*)alloc((size_t)10354688 * 2);

    unsigned short* qkb  = reg1;                       // [BT][1536]
    unsigned short* Vtb  = reg1 + BT * 1536;           // [B][NH][DH][T]
    unsigned short* ctxb = reg1 + BT * 1536 + BTH;     // [BT][H]
    unsigned short* hb   = reg1;                       // [BT][FF] (FFN phase)
    unsigned short* key1b = reg1;                      // [BT][1536] (head phase)
    unsigned short* val1b = reg1 + BT * 1536;          // [BT][1024]
    float* valf = x;                                   // [BT][512] f32 (x dead by then)

    unsigned short* wt_qkv = wt;                       // [2304][768] (q|k|v)
    unsigned short* wt_o  = wt + (size_t)2304 * 768;   // [768][768]
    unsigned short* wt_f1 = wt_o + (size_t)768 * 768;  // [3072][768]
    unsigned short* wt_f2 = wt_f1 + (size_t)3072 * 768;// [768][3072]
    unsigned short* wt_head = wt + (size_t)7077888;    // head region
    unsigned short* wt_kv1 = wt_head;                  // [2560][768] (key1|val1)
    unsigned short* wt_k2 = wt_head + (size_t)2560 * 768;   // [512][1536]
    unsigned short* wt_v2 = wt_k2 + (size_t)512 * 1536;     // [512][1024]

    const int Mrows = (int)BT;  // 4608
    const size_t HH = (size_t)H * H;
    const int BIG = 1 << 30;

    hipLaunchKernelGGL(order_kernel, dim3(B), dim3(S), 0, stream, attn_mask, ord, Larr);
    hipLaunchKernelGGL(embed_kernel, dim3(T, B), dim3(256), 0, stream,
                       input_ids, token_type, ord, Larr, word_emb, pos_emb, type_emb,
                       memory, emb_ln_s, emb_ln_b, x, xb, ttarr);

    for (int l = 0; l < NL; ++l) {
        TTab tab;
        tab.d[0] = { q_w + l * HH,              0u,                              H,  H,  0    };
        tab.d[1] = { k_w + l * HH,              (unsigned)(768 * 768),           H,  H,  576  };
        tab.d[2] = { v_w + l * HH,              (unsigned)(1536 * 768),          H,  H,  1152 };
        tab.d[3] = { o_w + l * HH,              (unsigned)(2304 * 768),          H,  H,  1728 };
        tab.d[4] = { f_w1 + (size_t)l * H * FF, (unsigned)(3072 * 768),          H,  FF, 2304 };
        tab.d[5] = { f_w2 + (size_t)l * FF * H, (unsigned)(6144 * 768),          FF, H,  4608 };
        int ntiles = 6912;
        if (l == NL - 1) {
            // append head-weight transposes to the last layer's launch
            tab.d[6] = { key_w1, 7077888u,                     H,     2 * H, 6912 };
            tab.d[7] = { val_w1, 7077888u + 1536u * 768u,      H,     2 * E, 8064 };
            tab.d[8] = { key_w2, 9043968u,                     2 * H, E,     8832 };
            tab.d[9] = { val_w2, 9830400u,                     2 * E, E,     9600 };
            tab.n = 10;
            ntiles = 10112;
        } else {
            tab.n = 6;
        }
        hipLaunchKernelGGL(transpose_all, dim3(ntiles), dim3(256), 0, stream, tab, wt);

        mfma_gemm<ACT_NONE, EPI_QKV, 1><<<dim3(18, 36), 256, 0, stream>>>(
            xb, wt_qkv, q_b + (size_t)l * H, k_b + (size_t)l * H, v_b + (size_t)l * H,
            768, 1536, nullptr, nullptr, qkb, nullptr, Vtb, 0, Mrows, 2304, H);
        hipLaunchKernelGGL(attn_mfma, dim3(864), dim3(256), 0, stream,
                           qkb, Vtb, Larr, ctxb);
        mfma_gemm<ACT_NONE, EPI_F32, 2><<<dim3(6, 36, 2), 256, 0, stream>>>(
            ctxb, wt_o, o_b + (size_t)l * H, nullptr, nullptr, BIG, BIG,
            Bbuf, part1, nullptr, nullptr, nullptr, 0, Mrows, H, H);
        hipLaunchKernelGGL(lnres_kernel, dim3((int)BT), dim3(256), 0, stream,
                           x, Bbuf, part1, ln1_s + (size_t)l * H, ln1_b + (size_t)l * H, xb);
        mfma_gemm<ACT_GELU, EPI_BF16, 1><<<dim3(24, 36), 256, 0, stream>>>(
            xb, wt_f1, f_b1 + (size_t)l * FF, nullptr, nullptr, BIG, BIG,
            nullptr, nullptr, hb, nullptr, nullptr, 0, Mrows, FF, H);
        mfma_gemm<ACT_NONE, EPI_F32, 2><<<dim3(6, 36, 2), 256, 0, stream>>>(
            hb, wt_f2, f_b2 + (size_t)l * H, nullptr, nullptr, BIG, BIG,
            Bbuf, part1, nullptr, nullptr, nullptr, 0, Mrows, H, FF);
        hipLaunchKernelGGL(lnres_kernel, dim3((int)BT), dim3(256), 0, stream,
                           x, Bbuf, part1, ln2_s + (size_t)l * H, ln2_b + (size_t)l * H, xb);
    }

    // fused key1|val1 GEMM: N=2560, split epilogue
    mfma_gemm<ACT_RELU, EPI_SPLIT2, 1><<<dim3(20, 36), 256, 0, stream>>>(
        xb, wt_kv1, key_b1, val_b1, nullptr, 1536, BIG,
        nullptr, nullptr, key1b, val1b, nullptr, 1024, Mrows, 2560, H);
    // key2: split-K, raw logits; sigmoid applied in pool
    mfma_gemm<ACT_NONE, EPI_F32, 2><<<dim3(4, 36, 2), 256, 0, stream>>>(
        key1b, wt_k2, key_b2, nullptr, nullptr, BIG, BIG,
        Bbuf, part1, nullptr, nullptr, nullptr, 0, Mrows, 512, 1536);
    // val2: unsplit, tanh epilogue
    mfma_gemm<ACT_TANH, EPI_F32, 1><<<dim3(4, 36), 256, 0, stream>>>(
        val1b, wt_v2, val_b2, nullptr, nullptr, BIG, BIG,
        valf, nullptr, nullptr, nullptr, nullptr, 0, Mrows, 512, 1024);
    hipLaunchKernelGGL(pool_kernel, dim3(B, E / 32), dim3(256), 0, stream,
                       Bbuf, part1, valf, ttarr, out);
}

// Round 8
// 569.955 us; speedup vs baseline: 13.3016x; 1.0186x over previous
//
#include <hip/hip_runtime.h>
#include <hip/hip_bf16.h>

#define B 8
#define S 512
#define MM 64
#define T 576          // S + MM
#define H 768
#define NH 12
#define DH 64
#define FF 3072
#define E 512
#define NL 2

typedef __attribute__((ext_vector_type(8))) short bf16x8;
typedef __attribute__((ext_vector_type(4))) float f32x4;

__device__ inline unsigned short bf16_rne(float f) {
    unsigned u = __builtin_bit_cast(unsigned, f);
    unsigned r = u + 0x7FFFu + ((u >> 16) & 1u);
    return (unsigned short)(r >> 16);
}

__device__ inline f32x4 mfma16(bf16x8 a, bf16x8 b, f32x4 c) {
    return __builtin_amdgcn_mfma_f32_16x16x32_bf16(a, b, c, 0, 0, 0);
}

__device__ inline void load_lds16(const void* g, void* l) {
    __builtin_amdgcn_global_load_lds((const __attribute__((address_space(1))) void*)g,
                                     (__attribute__((address_space(3))) void*)l, 16, 0, 0);
}

// ---------------- order / argsort ----------------
__global__ void order_kernel(const int* __restrict__ mask, int* __restrict__ ord,
                             int* __restrict__ Larr) {
    __shared__ int ps[S];
    int b = blockIdx.x;
    int t = threadIdx.x;
    int mv = (mask[b * S + t] != 0) ? 1 : 0;
    ps[t] = mv;
    __syncthreads();
    for (int off = 1; off < S; off <<= 1) {
        int v = ps[t];
        int add = (t >= off) ? ps[t - off] : 0;
        __syncthreads();
        ps[t] = v + add;
        __syncthreads();
    }
    int L = ps[S - 1];
    int rank = mv ? (ps[t] - 1) : (L + (t - ps[t]));
    ord[b * S + rank] = t;
    if (t == 0) Larr[b] = L;
}

// ---------------- embedding + LN (writes f32 x and bf16 xb) ----------------
__global__ void embed_kernel(const int* __restrict__ ids, const int* __restrict__ toktype,
                             const int* __restrict__ ord, const int* __restrict__ Larr,
                             const float* __restrict__ word_emb, const float* __restrict__ pos_emb,
                             const float* __restrict__ type_emb, const float* __restrict__ memory,
                             const float* __restrict__ lns, const float* __restrict__ lnb,
                             float* __restrict__ x, unsigned short* __restrict__ xb,
                             int* __restrict__ ttarr) {
    int t = blockIdx.x;
    int b = blockIdx.y;
    int Lb = Larr[b];
    int tid = threadIdx.x;
    int tt;
    const float* src;
    if (t < Lb) {
        int sp = ord[b * S + t];
        tt = toktype[b * S + sp];
        src = &word_emb[(size_t)ids[b * S + sp] * H];
    } else if (t < Lb + MM) {
        tt = 1;
        src = &memory[(size_t)(t - Lb) * H];
    } else {
        int spp = t - MM;
        if (spp < 0) spp = 0;
        if (spp > S - 1) spp = S - 1;
        int sp = ord[b * S + spp];
        tt = 1;
        src = &word_emb[(size_t)ids[b * S + sp] * H];
    }
    __shared__ float row[H];
    __shared__ float r1[256], r2[256];
    float lsum = 0.f, lsq = 0.f;
    for (int hh = tid; hh < H; hh += 256) {
        float v = src[hh] + pos_emb[(size_t)t * H + hh] + type_emb[(size_t)tt * H + hh];
        row[hh] = v;
        lsum += v;
        lsq += v * v;
    }
    r1[tid] = lsum; r2[tid] = lsq;
    __syncthreads();
    for (int s = 128; s > 0; s >>= 1) {
        if (tid < s) { r1[tid] += r1[tid + s]; r2[tid] += r2[tid + s]; }
        __syncthreads();
    }
    float mu = r1[0] / H;
    float var = r2[0] / H - mu * mu;
    float inv = rsqrtf(var + 1e-12f);
    for (int hh = tid; hh < H; hh += 256) {
        float v = (row[hh] - mu) * inv * lns[hh] + lnb[hh];
        x[((size_t)b * T + t) * H + hh] = v;
        xb[((size_t)b * T + t) * H + hh] = bf16_rne(v);
    }
    if (tid == 0) ttarr[b * T + t] = tt;
}

// ---------------- activations ----------------
#define ACT_NONE 0
#define ACT_RELU 1
#define ACT_GELU 2
#define ACT_SIGMOID 3
#define ACT_TANH 4

template <int ACT>
__device__ inline float apply_act(float v) {
    if constexpr (ACT == ACT_RELU) return fmaxf(v, 0.f);
    else if constexpr (ACT == ACT_GELU) {
        // exact-form GELU with A-S 7.1.26 erf (|err| <= 1.5e-7), exp2-based
        float y = v * 0.70710678118654752f;
        float a = fabsf(y);
        float t = 1.f / (1.f + 0.3275911f * a);
        float poly = t * (0.254829592f + t * (-0.284496736f + t * (1.421413741f +
                     t * (-1.453152027f + t * 1.061405429f))));
        float e = poly * exp2f(-a * a * 1.4426950408889634f);
        float erfv = 1.f - e;
        erfv = (y < 0.f) ? -erfv : erfv;
        return 0.5f * v * (1.f + erfv);
    }
    else if constexpr (ACT == ACT_SIGMOID) return 1.f / (1.f + expf(-v));
    else if constexpr (ACT == ACT_TANH) return tanhf(v);
    else return v;
}

// ---------------- fused weight transpose set: W[K][N] f32 -> Wt[N][K] bf16 ----------------
struct TDesc { const float* src; unsigned dstoff; int Kd; int Nd; int tile0; };
struct TTab { TDesc d[10]; int n; };

__global__ __launch_bounds__(256) void transpose_all(TTab tab, unsigned short* __restrict__ dstbase) {
    int tile = blockIdx.x;
    int mi = 0;
    #pragma unroll
    for (int i = 1; i < 10; ++i)
        if (i < tab.n && tab.d[i].tile0 <= tile) mi = i;
    TDesc d = tab.d[mi];
    int rel = tile - d.tile0;
    int tilesK = d.Kd >> 5;
    int kt = rel % tilesK, nt = rel / tilesK;
    __shared__ float ts[32][33];
    int k0 = kt * 32, n0 = nt * 32;
    int tx = threadIdx.x & 31, ty = threadIdx.x >> 5;  // 32 x 8
    #pragma unroll
    for (int r = 0; r < 4; ++r) {
        int kk = ty + r * 8;
        ts[kk][tx] = d.src[(size_t)(k0 + kk) * d.Nd + n0 + tx];
    }
    __syncthreads();
    unsigned short* Wt = dstbase + d.dstoff;
    #pragma unroll
    for (int r = 0; r < 4; ++r) {
        int nn = ty + r * 8;
        Wt[(size_t)(n0 + nn) * d.Kd + k0 + tx] = bf16_rne(ts[tx][nn]);
    }
}

// ---------------- MFMA GEMM ----------------
// C[M,N] = act(A[M,K] @ Wt[N,K]^T + bias).  128x128 tile, BK=32, 4 waves,
// 2-deep LDS dbuf with counted vmcnt, row>>2 XOR slot swizzle (bank-exact),
// bijective XCD swizzle, setprio around MFMA.  NSPLIT=2: blockIdx.z halves K.
#define EPI_F32   0
#define EPI_BF16  1
#define EPI_QKV   2
#define EPI_SPLIT2 3

template <int ACT, int EPI, int NSPLIT>
__global__ __launch_bounds__(256) void mfma_gemm(
    const unsigned short* __restrict__ A, const unsigned short* __restrict__ Bt,
    const float* __restrict__ b0, const float* __restrict__ b1, const float* __restrict__ b2,
    int sp1, int sp2,
    float* __restrict__ Cf, float* __restrict__ Cf2,
    unsigned short* __restrict__ Cb, unsigned short* __restrict__ Cb2,
    unsigned short* __restrict__ Vt, int n2w,
    int Mdim, int Ndim, int Kdim) {
    __shared__ unsigned short As[2][128 * 32];
    __shared__ unsigned short Bs[2][128 * 32];

    // bijective XCD swizzle (m204) over the x-y grid
    const int gx = gridDim.x;
    const int nwg = gx * gridDim.y;
    int orig = blockIdx.y * gx + blockIdx.x;
    int q = nwg >> 3, r8 = nwg & 7;
    int xcd = orig & 7, idx = orig >> 3;
    int swz = (xcd < r8 ? xcd * (q + 1) : r8 * (q + 1) + (xcd - r8) * q) + idx;
    const int bn = (swz % gx) * 128, bm = (swz / gx) * 128;

    const int z = (NSPLIT > 1) ? blockIdx.z : 0;
    const int Klocal = Kdim / NSPLIT;
    const int koff = z * Klocal;

    const int tid = threadIdx.x;
    const int w = tid >> 6, lane = tid & 63;
    const int lr = lane & 15, g = lane >> 4;
    const int wr = w >> 1, wc = w & 1;
    f32x4 acc[4][4] = {};

    // staging: lane L writes LDS row (L>>2), 16B slot (L&3) of its 16-row chunk.
    // Bank-exact swizzle key = (row>>2)&3 = (L>>4)&3 (same for rows 16..31 chunk).
    const int srow = w * 32 + (lane >> 2);
    const int kc = (((lane & 3) ^ ((lane >> 4) & 3)) * 8);
    const unsigned short* ga0 = A + (size_t)(bm + srow) * Kdim + kc;
    const unsigned short* ga1 = A + (size_t)(bm + srow + 16) * Kdim + kc;
    const unsigned short* gb0 = Bt + (size_t)(bn + srow) * Kdim + kc;
    const unsigned short* gb1 = Bt + (size_t)(bn + srow + 16) * Kdim + kc;
    const int d0 = (w * 32) * 32, d1 = (w * 32 + 16) * 32;

    // read: fragment row R = wr*64+i*16+lr -> key (R>>2)&3 = (lr>>2)&3
    const int sw = ((g ^ ((lr >> 2) & 3)) & 3) * 8;

    auto stage = [&](int pp, int k0) {
        load_lds16(ga0 + k0, &As[pp][d0]);
        load_lds16(ga1 + k0, &As[pp][d1]);
        load_lds16(gb0 + k0, &Bs[pp][d0]);
        load_lds16(gb1 + k0, &Bs[pp][d1]);
    };
    auto compute = [&](int pp) {
        bf16x8 af[4], bfr[4];
        #pragma unroll
        for (int i = 0; i < 4; ++i)
            af[i] = *(const bf16x8*)&As[pp][(wr * 64 + i * 16 + lr) * 32 + sw];
        #pragma unroll
        for (int j = 0; j < 4; ++j)
            bfr[j] = *(const bf16x8*)&Bs[pp][(wc * 64 + j * 16 + lr) * 32 + sw];
        __builtin_amdgcn_s_setprio(1);
        #pragma unroll
        for (int i = 0; i < 4; ++i)
            #pragma unroll
            for (int j = 0; j < 4; ++j)
                acc[i][j] = mfma16(af[i], bfr[j], acc[i][j]);
        __builtin_amdgcn_s_setprio(0);
    };

    const int nk = Klocal >> 5;
    stage(0, koff);
    int p = 0;
    for (int s = 0; s < nk; ++s) {
        if (s + 1 < nk) {
            stage(p ^ 1, koff + (s + 1) * 32);
            asm volatile("s_waitcnt vmcnt(4)" ::: "memory");
        } else {
            asm volatile("s_waitcnt vmcnt(0)" ::: "memory");
        }
        __builtin_amdgcn_s_barrier();
        __builtin_amdgcn_sched_barrier(0);
        compute(p);
        __builtin_amdgcn_sched_barrier(0);
        __builtin_amdgcn_s_barrier();
        __builtin_amdgcn_sched_barrier(0);
        p ^= 1;
    }

    float* Cdst = (NSPLIT > 1 && z == 1) ? Cf2 : Cf;
    #pragma unroll
    for (int i = 0; i < 4; ++i) {
        const int row0 = bm + wr * 64 + i * 16 + 4 * g;
        #pragma unroll
        for (int j = 0; j < 4; ++j) {
            const int col = bn + wc * 64 + j * 16 + lr;
            float bv = (NSPLIT > 1 && z == 1) ? 0.f
                     : ((col < sp1) ? b0[col] : (col < sp2 ? b1[col - sp1] : b2[col - sp2]));
            float vv[4];
            #pragma unroll
            for (int r = 0; r < 4; ++r) vv[r] = apply_act<ACT>(acc[i][j][r] + bv);
            if constexpr (EPI == EPI_F32) {
                #pragma unroll
                for (int r = 0; r < 4; ++r) Cdst[(size_t)(row0 + r) * Ndim + col] = vv[r];
            } else if constexpr (EPI == EPI_BF16) {
                #pragma unroll
                for (int r = 0; r < 4; ++r) Cb[(size_t)(row0 + r) * Ndim + col] = bf16_rne(vv[r]);
            } else if constexpr (EPI == EPI_QKV) {
                if (col < 1536) {
                    #pragma unroll
                    for (int r = 0; r < 4; ++r) Cb[(size_t)(row0 + r) * 1536 + col] = bf16_rne(vv[r]);
                } else {
                    int c2 = col - 1536;
                    int bb = row0 / T, t0 = row0 % T;
                    int hh2 = c2 >> 6, dd = c2 & 63;
                    unsigned lo = (unsigned)bf16_rne(vv[0]) | ((unsigned)bf16_rne(vv[1]) << 16);
                    unsigned hi = (unsigned)bf16_rne(vv[2]) | ((unsigned)bf16_rne(vv[3]) << 16);
                    size_t idxv = (((size_t)bb * NH + hh2) * DH + dd) * T + t0;
                    *(uint2*)&Vt[idxv] = make_uint2(lo, hi);
                }
            } else {  // EPI_SPLIT2
                if (col < sp1) {
                    #pragma unroll
                    for (int r = 0; r < 4; ++r) Cb[(size_t)(row0 + r) * sp1 + col] = bf16_rne(vv[r]);
                } else {
                    #pragma unroll
                    for (int r = 0; r < 4; ++r)
                        Cb2[(size_t)(row0 + r) * n2w + (col - sp1)] = bf16_rne(vv[r]);
                }
            }
        }
    }
}

// ---------------- MFMA flash attention ----------------
#define C2 0.180336880111116670f      // 0.125 * log2(e)
#define MB2 14426.950408889634f       // 10000 * log2(e)

__global__ __launch_bounds__(256) void attn_mfma(
    const unsigned short* __restrict__ QK, const unsigned short* __restrict__ Vt,
    const int* __restrict__ Larr, unsigned short* __restrict__ ctxb) {
    const int n = blockIdx.x;
    const int xcd = n & 7, k = n >> 3;
    const int p = xcd * 12 + k / 9, qt = k % 9;
    const int b = p / NH, h = p % NH;
    const int w = threadIdx.x >> 6, lane = threadIdx.x & 63;
    const int q0 = qt * 64 + w * 16;
    const int lr = lane & 15, g = lane >> 4;
    const int LbMM = Larr[b] + MM;
    const int ktend = min(T, (LbMM + 63) & ~63);
    __shared__ unsigned short P[4][16][72];
    const unsigned short* qrow = QK + (size_t)(b * T + q0 + lr) * 1536 + h * 64;
    bf16x8 qf0 = *(const bf16x8*)(qrow + 8 * g);
    bf16x8 qf1 = *(const bf16x8*)(qrow + 32 + 8 * g);
    f32x4 ctx[4] = {};
    float m_run = -1e30f, l_run = 0.f;
    const size_t vbase = ((size_t)b * NH + h) * DH;
    for (int kt = 0; kt < ktend; kt += 64) {
        f32x4 sf[4];
        #pragma unroll
        for (int i = 0; i < 4; ++i) {
            const unsigned short* krow =
                QK + (size_t)(b * T + kt + 16 * i + lr) * 1536 + 768 + h * 64;
            bf16x8 kf0 = *(const bf16x8*)(krow + 8 * g);
            bf16x8 kf1 = *(const bf16x8*)(krow + 32 + 8 * g);
            f32x4 s = {};
            s = mfma16(kf0, qf0, s);
            s = mfma16(kf1, qf1, s);
            sf[i] = s;
        }
        float tmax = -1e30f;
        #pragma unroll
        for (int i = 0; i < 4; ++i)
            #pragma unroll
            for (int r = 0; r < 4; ++r) {
                int key = kt + 16 * i + 4 * g + r;
                float v = sf[i][r] * C2 + (key < LbMM ? 0.f : -MB2);
                sf[i][r] = v;
                tmax = fmaxf(tmax, v);
            }
        tmax = fmaxf(tmax, __shfl_xor(tmax, 16));
        tmax = fmaxf(tmax, __shfl_xor(tmax, 32));
        float m_new = fmaxf(m_run, tmax);
        float scale = exp2f(m_run - m_new);
        m_run = m_new;
        float psum = 0.f;
        #pragma unroll
        for (int i = 0; i < 4; ++i)
            #pragma unroll
            for (int r = 0; r < 4; ++r) {
                float pv = exp2f(sf[i][r] - m_new);
                sf[i][r] = pv;
                psum += pv;
            }
        l_run = l_run * scale + psum;
        float f0 = __shfl(scale, 4 * g + 0);
        float f1 = __shfl(scale, 4 * g + 1);
        float f2 = __shfl(scale, 4 * g + 2);
        float f3 = __shfl(scale, 4 * g + 3);
        #pragma unroll
        for (int j = 0; j < 4; ++j) {
            ctx[j][0] *= f0; ctx[j][1] *= f1; ctx[j][2] *= f2; ctx[j][3] *= f3;
        }
        #pragma unroll
        for (int i = 0; i < 4; ++i) {
            unsigned lo = (unsigned)bf16_rne(sf[i][0]) | ((unsigned)bf16_rne(sf[i][1]) << 16);
            unsigned hi = (unsigned)bf16_rne(sf[i][2]) | ((unsigned)bf16_rne(sf[i][3]) << 16);
            *(unsigned*)&P[w][lr][16 * i + 4 * g] = lo;
            *(unsigned*)&P[w][lr][16 * i + 4 * g + 2] = hi;
        }
        asm volatile("s_waitcnt lgkmcnt(0)" ::: "memory");
        __builtin_amdgcn_sched_barrier(0);
        #pragma unroll
        for (int s2 = 0; s2 < 2; ++s2) {
            bf16x8 pa = *(const bf16x8*)&P[w][lr][32 * s2 + 8 * g];
            #pragma unroll
            for (int j = 0; j < 4; ++j) {
                const unsigned short* vrow =
                    Vt + (vbase + 16 * j + lr) * T + kt + 32 * s2 + 8 * g;
                bf16x8 vf = *(const bf16x8*)vrow;
                ctx[j] = mfma16(pa, vf, ctx[j]);
            }
        }
        asm volatile("s_waitcnt lgkmcnt(0)" ::: "memory");
        __builtin_amdgcn_sched_barrier(0);
    }
    l_run += __shfl_xor(l_run, 16);
    l_run += __shfl_xor(l_run, 32);
    float inv = 1.f / l_run;
    float i0 = __shfl(inv, 4 * g + 0);
    float i1 = __shfl(inv, 4 * g + 1);
    float i2 = __shfl(inv, 4 * g + 2);
    float i3 = __shfl(inv, 4 * g + 3);
    float sc[4] = {i0, i1, i2, i3};
    #pragma unroll
    for (int j = 0; j < 4; ++j)
        #pragma unroll
        for (int r = 0; r < 4; ++r)
            ctxb[(size_t)(b * T + q0 + 4 * g + r) * H + h * 64 + 16 * j + lr] =
                bf16_rne(ctx[j][r] * sc[r]);
}

// ---------------- residual + LN (delta = d1 + d2), float4-vectorized ----------------
__global__ void lnres_kernel(float* __restrict__ x, const float* __restrict__ d1,
                             const float* __restrict__ d2,
                             const float* __restrict__ s, const float* __restrict__ bvec,
                             unsigned short* __restrict__ xb) {
    int r = blockIdx.x;
    int tid = threadIdx.x;
    __shared__ float4 row[H / 4];
    __shared__ float r1[256], r2[256];
    float lsum = 0.f, lsq = 0.f;
    size_t off4 = (size_t)r * (H / 4);
    const float4* x4 = (const float4*)x;
    const float4* d14 = (const float4*)d1;
    const float4* d24 = (const float4*)d2;
    if (tid < H / 4) {
        float4 a = x4[off4 + tid], bb = d14[off4 + tid], cc = d24[off4 + tid];
        float4 v = make_float4(a.x + bb.x + cc.x, a.y + bb.y + cc.y,
                               a.z + bb.z + cc.z, a.w + bb.w + cc.w);
        row[tid] = v;
        lsum = v.x + v.y + v.z + v.w;
        lsq = v.x * v.x + v.y * v.y + v.z * v.z + v.w * v.w;
    }
    r1[tid] = lsum; r2[tid] = lsq;
    __syncthreads();
    for (int ss = 128; ss > 0; ss >>= 1) {
        if (tid < ss) { r1[tid] += r1[tid + ss]; r2[tid] += r2[tid + ss]; }
        __syncthreads();
    }
    float mu = r1[0] / H;
    float var = r2[0] / H - mu * mu;
    float inv = rsqrtf(var + 1e-12f);
    if (tid < H / 4) {
        float4 v = row[tid];
        const float4 sv = ((const float4*)s)[tid];
        const float4 bv = ((const float4*)bvec)[tid];
        float4 o = make_float4((v.x - mu) * inv * sv.x + bv.x,
                               (v.y - mu) * inv * sv.y + bv.y,
                               (v.z - mu) * inv * sv.z + bv.z,
                               (v.w - mu) * inv * sv.w + bv.w);
        ((float4*)x)[off4 + tid] = o;
        ushort4 ob = make_ushort4(bf16_rne(o.x), bf16_rne(o.y), bf16_rne(o.z), bf16_rne(o.w));
        *(ushort4*)&xb[(size_t)r * H + tid * 4] = ob;
    }
}

// ---------------- masked softmax pooling (sigmoid applied here; w = sigma(w0+w1)) ----------------
__global__ __launch_bounds__(256) void pool_kernel(
    const float* __restrict__ w0, const float* __restrict__ w1,
    const float* __restrict__ value,
    const int* __restrict__ ttarr, float* __restrict__ out) {
    int b = blockIdx.x;
    int le = threadIdx.x & 31;
    int e = blockIdx.y * 32 + le;
    int tg = threadIdx.x >> 5;  // 0..7
    __shared__ int ttl[T];
    __shared__ float red[8][33];
    for (int t = threadIdx.x; t < T; t += 256) ttl[t] = ttarr[b * T + t];
    __syncthreads();
    float mx = -1e30f;
    for (int t = tg; t < T; t += 8) {
        if (ttl[t] == 1) continue;
        size_t idx = ((size_t)b * T + t) * E + e;
        float w = 1.f / (1.f + expf(-(w0[idx] + w1[idx])));
        mx = fmaxf(mx, w);
    }
    red[tg][le] = mx;
    __syncthreads();
    #pragma unroll
    for (int i = 0; i < 8; ++i) mx = fmaxf(mx, red[i][le]);
    float den = 0.f, num = 0.f;
    for (int t = tg; t < T; t += 8) {
        if (ttl[t] == 1) continue;
        size_t idx = ((size_t)b * T + t) * E + e;
        float w = 1.f / (1.f + expf(-(w0[idx] + w1[idx])));
        float ew = expf(w - mx);
        den += ew;
        num = fmaf(ew, value[idx], num);
    }
    __syncthreads();
    red[tg][le] = den;
    __syncthreads();
    float dtot = 0.f;
    #pragma unroll
    for (int i = 0; i < 8; ++i) dtot += red[i][le];
    __syncthreads();
    red[tg][le] = num;
    __syncthreads();
    float ntot = 0.f;
    #pragma unroll
    for (int i = 0; i < 8; ++i) ntot += red[i][le];
    if (tg == 0) out[(size_t)b * E + e] = fmaxf(ntot / dtot, 0.f);
}

// ---------------- host-side launch ----------------
extern "C" void kernel_launch(void* const* d_in, const int* in_sizes, int n_in,
                              void* d_out, int out_size, void* d_ws, size_t ws_size,
                              hipStream_t stream) {
    const int*   input_ids  = (const int*)d_in[0];
    const int*   token_type = (const int*)d_in[1];
    const int*   attn_mask  = (const int*)d_in[2];
    const float* word_emb   = (const float*)d_in[3];
    const float* pos_emb    = (const float*)d_in[4];
    const float* type_emb   = (const float*)d_in[5];
    const float* emb_ln_s   = (const float*)d_in[6];
    const float* emb_ln_b   = (const float*)d_in[7];
    const float* memory     = (const float*)d_in[8];
    const float* q_w  = (const float*)d_in[9];
    const float* q_b  = (const float*)d_in[10];
    const float* k_w  = (const float*)d_in[11];
    const float* k_b  = (const float*)d_in[12];
    const float* v_w  = (const float*)d_in[13];
    const float* v_b  = (const float*)d_in[14];
    const float* o_w  = (const float*)d_in[15];
    const float* o_b  = (const float*)d_in[16];
    const float* ln1_s = (const float*)d_in[17];
    const float* ln1_b = (const float*)d_in[18];
    const float* f_w1  = (const float*)d_in[19];
    const float* f_b1  = (const float*)d_in[20];
    const float* f_w2  = (const float*)d_in[21];
    const float* f_b2  = (const float*)d_in[22];
    const float* ln2_s = (const float*)d_in[23];
    const float* ln2_b = (const float*)d_in[24];
    const float* key_w1 = (const float*)d_in[25];
    const float* key_b1 = (const float*)d_in[26];
    const float* key_w2 = (const float*)d_in[27];
    const float* key_b2 = (const float*)d_in[28];
    const float* val_w1 = (const float*)d_in[29];
    const float* val_b1 = (const float*)d_in[30];
    const float* val_w2 = (const float*)d_in[31];
    const float* val_b2 = (const float*)d_in[32];
    float* out = (float*)d_out;

    char* ws = (char*)d_ws;
    size_t off = 0;
    auto alloc = [&](size_t bytes) {
        void* p = ws + off;
        off += (bytes + 255) & ~(size_t)255;
        return p;
    };
    const size_t BT  = (size_t)B * T;      // 4608
    const size_t BTH = BT * H;             // 3538944

    int*   ord   = (int*)alloc((size_t)B * S * 4);
    int*   Larr  = (int*)alloc(64);
    int*   ttarr = (int*)alloc(BT * 4);
    float* x     = (float*)alloc(BTH * 4);
    unsigned short* xb   = (unsigned short*)alloc(BTH * 2);
    unsigned short* reg1 = (unsigned short*)alloc(BT * FF * 2);
    float* Bbuf  = (float*)alloc(BTH * 4);     // split-K partial z0
    float* part1 = (float*)alloc(BTH * 4);     // split-K partial z1
    // wt: per-layer region (7,077,888) + head region (3,276,800)
    unsigned short* wt = (unsigned short*)alloc((size_t)10354688 * 2);

    unsigned short* qkb  = reg1;                       // [BT][1536]
    unsigned short* Vtb  = reg1 + BT * 1536;           // [B][NH][DH][T]
    unsigned short* ctxb = reg1 + BT * 1536 + BTH;     // [BT][H]
    unsigned short* hb   = reg1;                       // [BT][FF] (FFN phase)
    unsigned short* key1b = reg1;                      // [BT][1536] (head phase)
    unsigned short* val1b = reg1 + BT * 1536;          // [BT][1024]
    float* valf = x;                                   // [BT][512] f32 (x dead by then)

    unsigned short* wt_qkv = wt;                       // [2304][768] (q|k|v)
    unsigned short* wt_o  = wt + (size_t)2304 * 768;   // [768][768]
    unsigned short* wt_f1 = wt_o + (size_t)768 * 768;  // [3072][768]
    unsigned short* wt_f2 = wt_f1 + (size_t)3072 * 768;// [768][3072]
    unsigned short* wt_head = wt + (size_t)7077888;    // head region
    unsigned short* wt_kv1 = wt_head;                  // [2560][768] (key1|val1)
    unsigned short* wt_k2 = wt_head + (size_t)2560 * 768;   // [512][1536]
    unsigned short* wt_v2 = wt_k2 + (size_t)512 * 1536;     // [512][1024]

    const int Mrows = (int)BT;  // 4608
    const size_t HH = (size_t)H * H;
    const int BIG = 1 << 30;

    hipLaunchKernelGGL(order_kernel, dim3(B), dim3(S), 0, stream, attn_mask, ord, Larr);
    hipLaunchKernelGGL(embed_kernel, dim3(T, B), dim3(256), 0, stream,
                       input_ids, token_type, ord, Larr, word_emb, pos_emb, type_emb,
                       memory, emb_ln_s, emb_ln_b, x, xb, ttarr);

    for (int l = 0; l < NL; ++l) {
        TTab tab;
        tab.d[0] = { q_w + l * HH,              0u,                              H,  H,  0    };
        tab.d[1] = { k_w + l * HH,              (unsigned)(768 * 768),           H,  H,  576  };
        tab.d[2] = { v_w + l * HH,              (unsigned)(1536 * 768),          H,  H,  1152 };
        tab.d[3] = { o_w + l * HH,              (unsigned)(2304 * 768),          H,  H,  1728 };
        tab.d[4] = { f_w1 + (size_t)l * H * FF, (unsigned)(3072 * 768),          H,  FF, 2304 };
        tab.d[5] = { f_w2 + (size_t)l * FF * H, (unsigned)(6144 * 768),          FF, H,  4608 };
        int ntiles = 6912;
        if (l == NL - 1) {
            tab.d[6] = { key_w1, 7077888u,                     H,     2 * H, 6912 };
            tab.d[7] = { val_w1, 7077888u + 1536u * 768u,      H,     2 * E, 8064 };
            tab.d[8] = { key_w2, 9043968u,                     2 * H, E,     8832 };
            tab.d[9] = { val_w2, 9830400u,                     2 * E, E,     9600 };
            tab.n = 10;
            ntiles = 10112;
        } else {
            tab.n = 6;
        }
        hipLaunchKernelGGL(transpose_all, dim3(ntiles), dim3(256), 0, stream, tab, wt);

        mfma_gemm<ACT_NONE, EPI_QKV, 1><<<dim3(18, 36), 256, 0, stream>>>(
            xb, wt_qkv, q_b + (size_t)l * H, k_b + (size_t)l * H, v_b + (size_t)l * H,
            768, 1536, nullptr, nullptr, qkb, nullptr, Vtb, 0, Mrows, 2304, H);
        hipLaunchKernelGGL(attn_mfma, dim3(864), dim3(256), 0, stream,
                           qkb, Vtb, Larr, ctxb);
        mfma_gemm<ACT_NONE, EPI_F32, 2><<<dim3(6, 36, 2), 256, 0, stream>>>(
            ctxb, wt_o, o_b + (size_t)l * H, nullptr, nullptr, BIG, BIG,
            Bbuf, part1, nullptr, nullptr, nullptr, 0, Mrows, H, H);
        hipLaunchKernelGGL(lnres_kernel, dim3((int)BT), dim3(256), 0, stream,
                           x, Bbuf, part1, ln1_s + (size_t)l * H, ln1_b + (size_t)l * H, xb);
        mfma_gemm<ACT_GELU, EPI_BF16, 1><<<dim3(24, 36), 256, 0, stream>>>(
            xb, wt_f1, f_b1 + (size_t)l * FF, nullptr, nullptr, BIG, BIG,
            nullptr, nullptr, hb, nullptr, nullptr, 0, Mrows, FF, H);
        mfma_gemm<ACT_NONE, EPI_F32, 2><<<dim3(6, 36, 2), 256, 0, stream>>>(
            hb, wt_f2, f_b2 + (size_t)l * H, nullptr, nullptr, BIG, BIG,
            Bbuf, part1, nullptr, nullptr, nullptr, 0, Mrows, H, FF);
        hipLaunchKernelGGL(lnres_kernel, dim3((int)BT), dim3(256), 0, stream,
                           x, Bbuf, part1, ln2_s + (size_t)l * H, ln2_b + (size_t)l * H, xb);
    }

    // fused key1|val1 GEMM: N=2560, split epilogue
    mfma_gemm<ACT_RELU, EPI_SPLIT2, 1><<<dim3(20, 36), 256, 0, stream>>>(
        xb, wt_kv1, key_b1, val_b1, nullptr, 1536, BIG,
        nullptr, nullptr, key1b, val1b, nullptr, 1024, Mrows, 2560, H);
    // key2: split-K, raw logits; sigmoid applied in pool
    mfma_gemm<ACT_NONE, EPI_F32, 2><<<dim3(4, 36, 2), 256, 0, stream>>>(
        key1b, wt_k2, key_b2, nullptr, nullptr, BIG, BIG,
        Bbuf, part1, nullptr, nullptr, nullptr, 0, Mrows, 512, 1536);
    // val2: unsplit, tanh epilogue
    mfma_gemm<ACT_TANH, EPI_F32, 1><<<dim3(4, 36), 256, 0, stream>>>(
        val1b, wt_v2, val_b2, nullptr, nullptr, BIG, BIG,
        valf, nullptr, nullptr, nullptr, nullptr, 0, Mrows, 512, 1024);
    hipLaunchKernelGGL(pool_kernel, dim3(B, E / 32), dim3(256), 0, stream,
                       Bbuf, part1, valf, ttarr, out);
}